// Round 6
// baseline (618.167 us; speedup 1.0000x reference)
//
#include <hip/hip_runtime.h>
#include <hip/hip_fp16.h>
#include <math.h>

#define N_NODES 50000
#define N_EDGES 1000000
#define F_IN 128
#define HID 16
#define N_CLS 40
#define HEADS 8
#define ET (N_EDGES + N_NODES)
#define XB ((N_NODES + 63) / 64)   // 782 xform blocks
#define HB ((ET + 255) / 256)      // 4103 hist/scatter blocks
#define NSCB ((N_NODES + 255) / 256)  // 196 scan blocks

__device__ __forceinline__ void fma4(float4& acc, float s, const float4& v) {
  acc.x += s * v.x;
  acc.y += s * v.y;
  acc.z += s * v.z;
  acc.w += s * v.w;
}

__device__ __forceinline__ float dot4(float4 a, float4 b) {
  return a.x * b.x + a.y * b.y + a.z * b.z + a.w * b.w;
}

// monotone float<->uint encoding for atomicMax on floats (0 is a safe bottom)
__device__ __forceinline__ unsigned encf(float f) {
  unsigned b = __float_as_uint(f);
  return (b & 0x80000000u) ? ~b : (b | 0x80000000u);
}
__device__ __forceinline__ float decf(unsigned k) {
  unsigned b = (k & 0x80000000u) ? (k ^ 0x80000000u) : ~k;
  return __uint_as_float(b);
}

// ---------------- conv1 transform (+ fused hist blocks, + fused as1-max) ----

__global__ __launch_bounds__(256) void k_xform1(
    const float* __restrict__ x, const float* __restrict__ W1,
    const float* __restrict__ att_s, const float* __restrict__ att_d,
    const int* __restrict__ ei, int* __restrict__ deg,
    __half* __restrict__ h1, float* __restrict__ as1, float* __restrict__ ad1,
    unsigned* __restrict__ enc1) {
  if (blockIdx.x >= XB) {  // histogram blocks
    int i = (blockIdx.x - XB) * 256 + threadIdx.x;
    if (i < ET) {
      int dd = (i < N_EDGES) ? ei[N_EDGES + i] : (i - N_EDGES);
      atomicAdd(&deg[dd], 1);
    }
    return;
  }
  __shared__ float4 xlds[64 * 32];  // [node][k/4]
  __shared__ float4 wlds[64 * 32];  // [k_local][c/4]
  __shared__ unsigned encl[8];
  int t = threadIdx.x;
  if (t < 8) encl[t] = 0u;
  int tx = t & 15, ty = t >> 4;
  int base = blockIdx.x * 64;
  const float4* x4 = (const float4*)x;
  const float4* W4 = (const float4*)W1;

  for (int i = t; i < 64 * 32; i += 256) {
    int n = i >> 5;
    int gn = base + n;
    float4 v = {0.f, 0.f, 0.f, 0.f};
    if (gn < N_NODES) v = x4[(size_t)gn * 32 + (i & 31)];
    xlds[i] = v;
  }

  float4 accA[4], accB[4];
#pragma unroll
  for (int n = 0; n < 4; n++) {
    accA[n] = {0.f, 0.f, 0.f, 0.f};
    accB[n] = {0.f, 0.f, 0.f, 0.f};
  }
  int n0 = ty * 4;

  for (int half = 0; half < 2; half++) {
    __syncthreads();
    for (int i = t; i < 64 * 32; i += 256)
      wlds[i] = W4[(size_t)(half * 64 + (i >> 5)) * 32 + (i & 31)];
    __syncthreads();
#pragma unroll
    for (int kk = 0; kk < 64; kk += 4) {
      int kq = half * 16 + (kk >> 2);
      float4 xv0 = xlds[(n0 + 0) * 32 + kq];
      float4 xv1 = xlds[(n0 + 1) * 32 + kq];
      float4 xv2 = xlds[(n0 + 2) * 32 + kq];
      float4 xv3 = xlds[(n0 + 3) * 32 + kq];
#pragma unroll
      for (int j = 0; j < 4; j++) {
        float4 wA = wlds[(kk + j) * 32 + tx * 2];
        float4 wB = wlds[(kk + j) * 32 + tx * 2 + 1];
        float s0 = (j == 0) ? xv0.x : (j == 1) ? xv0.y : (j == 2) ? xv0.z : xv0.w;
        float s1 = (j == 0) ? xv1.x : (j == 1) ? xv1.y : (j == 2) ? xv1.z : xv1.w;
        float s2 = (j == 0) ? xv2.x : (j == 1) ? xv2.y : (j == 2) ? xv2.z : xv2.w;
        float s3 = (j == 0) ? xv3.x : (j == 1) ? xv3.y : (j == 2) ? xv3.z : xv3.w;
        fma4(accA[0], s0, wA); fma4(accB[0], s0, wB);
        fma4(accA[1], s1, wA); fma4(accB[1], s1, wB);
        fma4(accA[2], s2, wA); fma4(accB[2], s2, wB);
        fma4(accA[3], s3, wA); fma4(accB[3], s3, wB);
      }
    }
  }

  int c0 = tx * 8;
  float4 asA = *(const float4*)(att_s + c0);
  float4 asB = *(const float4*)(att_s + c0 + 4);
  float4 adA = *(const float4*)(att_d + c0);
  float4 adB = *(const float4*)(att_d + c0 + 4);
  float psmax = -1e30f;
#pragma unroll
  for (int n = 0; n < 4; n++) {
    int gn = base + n0 + n;
    float ps = dot4(accA[n], asA) + dot4(accB[n], asB);
    float pd = dot4(accA[n], adA) + dot4(accB[n], adB);
    ps += __shfl_xor(ps, 1);
    pd += __shfl_xor(pd, 1);
    if (gn < N_NODES) {
      uint4 pk;
      __half2* ph = (__half2*)&pk;
      ph[0] = __floats2half2_rn(accA[n].x, accA[n].y);
      ph[1] = __floats2half2_rn(accA[n].z, accA[n].w);
      ph[2] = __floats2half2_rn(accB[n].x, accB[n].y);
      ph[3] = __floats2half2_rn(accB[n].z, accB[n].w);
      *(uint4*)(h1 + (size_t)gn * 128 + tx * 8) = pk;
      psmax = fmaxf(psmax, ps);
      if ((tx & 1) == 0) {
        as1[gn * 8 + (tx >> 1)] = ps;
        ad1[gn * 8 + (tx >> 1)] = pd;
      }
    }
  }
  if ((tx & 1) == 0) atomicMax(&encl[tx >> 1], encf(psmax));
  __syncthreads();
  if (t < 8) atomicMax(&enc1[t], encl[t]);
}

// ---------------- 3-kernel coalesced exclusive scan of deg -> start ----------

__global__ __launch_bounds__(256) void k_scanA(const int* __restrict__ deg,
                                               int* __restrict__ bsum) {
  int i = blockIdx.x * 256 + threadIdx.x;
  int v = (i < N_NODES) ? deg[i] : 0;
#pragma unroll
  for (int off = 32; off; off >>= 1) v += __shfl_xor(v, off);
  __shared__ int ws[4];
  if ((threadIdx.x & 63) == 0) ws[threadIdx.x >> 6] = v;
  __syncthreads();
  if (threadIdx.x == 0) bsum[blockIdx.x] = ws[0] + ws[1] + ws[2] + ws[3];
}

__global__ __launch_bounds__(256) void k_scanB(const int* __restrict__ bsum,
                                               int* __restrict__ boff,
                                               int* __restrict__ start) {
  __shared__ int s[256];
  int t = threadIdx.x;
  int v0 = (t < NSCB) ? bsum[t] : 0;
  s[t] = v0;
  __syncthreads();
  for (int off = 1; off < 256; off <<= 1) {
    int v = (t >= off) ? s[t - off] : 0;
    __syncthreads();
    s[t] += v;
    __syncthreads();
  }
  boff[t] = s[t] - v0;  // exclusive
  if (t == 0) start[N_NODES] = ET;
}

__global__ __launch_bounds__(256) void k_scanC(const int* __restrict__ deg,
                                               const int* __restrict__ boff,
                                               int* __restrict__ start) {
  __shared__ int s[256];
  int t = threadIdx.x;
  int i = blockIdx.x * 256 + t;
  int v0 = (i < N_NODES) ? deg[i] : 0;
  s[t] = v0;
  __syncthreads();
  for (int off = 1; off < 256; off <<= 1) {
    int v = (t >= off) ? s[t - off] : 0;
    __syncthreads();
    s[t] += v;
    __syncthreads();
  }
  if (i < N_NODES) start[i] = boff[blockIdx.x] + s[t] - v0;
}

__global__ void k_scatter(const int* __restrict__ ei, const int* __restrict__ start,
                          int* __restrict__ cursor, int* __restrict__ esrc) {
  int i = blockIdx.x * blockDim.x + threadIdx.x;
  if (i >= ET) return;
  int s, d;
  if (i < N_EDGES) { s = ei[i]; d = ei[N_EDGES + i]; }
  else { s = i - N_EDGES; d = s; }
  int pos = atomicAdd(&cursor[d], 1);
  esrc[start[d] + pos] = s;
}

// ---------------- conv1 aggregation + fused conv2 transform (+ as2 max) -----
// One wave per dst. Exp phase parallel over (edge x head); transposed p in LDS;
// serial gather with b128 LDS reads, fma_mix, den accumulated in serial phase.

__global__ __launch_bounds__(256) void k_agg1(
    const __half* __restrict__ h1, const float* __restrict__ as1,
    const float* __restrict__ ad1, const int* __restrict__ start,
    const int* __restrict__ esrc, const float* __restrict__ b1,
    const float* __restrict__ W2, const float* __restrict__ att_s2,
    const float* __restrict__ att_d2, const unsigned* __restrict__ enc1,
    __half* __restrict__ h2, float* __restrict__ as2, float* __restrict__ ad2,
    unsigned* __restrict__ enc2) {
  __shared__ __align__(16) float p_t[4][8][68];  // [wave][head][edge], padded
  __shared__ __align__(16) int s_lds[4][64];
  __shared__ unsigned encl;
  int wave = threadIdx.x >> 6, lane = threadIdx.x & 63;
  if (threadIdx.x == 0) encl = 0u;
  __syncthreads();

  int d = blockIdx.x * 4 + wave;
  bool valid = d < N_NODES;
  int dd = valid ? d : (N_NODES - 1);
  int s0 = start[dd];
  int deg = valid ? (start[dd + 1] - s0) : 0;

  int hE = lane & 7;   // head in exp phase
  int hS = lane >> 3;  // head owning this lane's channel pair in serial phase
  float adh = ad1[dd * 8 + hE];
  float cE = decf(enc1[hE]) + adh;
  cE = cE > 0.f ? cE : 0.2f * cE;

  const __half* h1l = h1 + lane * 2;
  float a0x = 0.f, a0y = 0.f, a1x = 0.f, a1y = 0.f, den = 0.f;

  for (int be = 0; be < deg; be += 64) {
    int cnt = min(64, deg - be);
    if (lane < cnt) s_lds[wave][lane] = esrc[s0 + be + lane];
    for (int r = 0; r < cnt; r += 8) {
      int e = r + hS;
      if (e < cnt) {
        int s = s_lds[wave][e];
        float ev = as1[s * 8 + hE] + adh;
        ev = ev > 0.f ? ev : 0.2f * ev;
        p_t[wave][hE][e] = __expf(ev - cE);
      }
    }
    int i = 0;
    for (; i + 7 < cnt; i += 8) {
      int4 sA = *(const int4*)&s_lds[wave][i];
      int4 sB = *(const int4*)&s_lds[wave][i + 4];
      float4 pA = *(const float4*)&p_t[wave][hS][i];
      float4 pB = *(const float4*)&p_t[wave][hS][i + 4];
      __half2 hA = *(const __half2*)(h1l + (size_t)sA.x * 128);
      __half2 hBv = *(const __half2*)(h1l + (size_t)sA.y * 128);
      __half2 hC = *(const __half2*)(h1l + (size_t)sA.z * 128);
      __half2 hD = *(const __half2*)(h1l + (size_t)sA.w * 128);
      __half2 hEv = *(const __half2*)(h1l + (size_t)sB.x * 128);
      __half2 hF = *(const __half2*)(h1l + (size_t)sB.y * 128);
      __half2 hG = *(const __half2*)(h1l + (size_t)sB.z * 128);
      __half2 hH = *(const __half2*)(h1l + (size_t)sB.w * 128);
      a0x = fmaf(__half2float(hA.x), pA.x, a0x);  a0y = fmaf(__half2float(hA.y), pA.x, a0y);
      a1x = fmaf(__half2float(hBv.x), pA.y, a1x); a1y = fmaf(__half2float(hBv.y), pA.y, a1y);
      a0x = fmaf(__half2float(hC.x), pA.z, a0x);  a0y = fmaf(__half2float(hC.y), pA.z, a0y);
      a1x = fmaf(__half2float(hD.x), pA.w, a1x);  a1y = fmaf(__half2float(hD.y), pA.w, a1y);
      a0x = fmaf(__half2float(hEv.x), pB.x, a0x); a0y = fmaf(__half2float(hEv.y), pB.x, a0y);
      a1x = fmaf(__half2float(hF.x), pB.y, a1x);  a1y = fmaf(__half2float(hF.y), pB.y, a1y);
      a0x = fmaf(__half2float(hG.x), pB.z, a0x);  a0y = fmaf(__half2float(hG.y), pB.z, a0y);
      a1x = fmaf(__half2float(hH.x), pB.w, a1x);  a1y = fmaf(__half2float(hH.y), pB.w, a1y);
      den += (pA.x + pA.y) + (pA.z + pA.w) + (pB.x + pB.y) + (pB.z + pB.w);
    }
    for (; i + 3 < cnt; i += 4) {
      int4 sA = *(const int4*)&s_lds[wave][i];
      float4 pA = *(const float4*)&p_t[wave][hS][i];
      __half2 hA = *(const __half2*)(h1l + (size_t)sA.x * 128);
      __half2 hBv = *(const __half2*)(h1l + (size_t)sA.y * 128);
      __half2 hC = *(const __half2*)(h1l + (size_t)sA.z * 128);
      __half2 hD = *(const __half2*)(h1l + (size_t)sA.w * 128);
      a0x = fmaf(__half2float(hA.x), pA.x, a0x);  a0y = fmaf(__half2float(hA.y), pA.x, a0y);
      a1x = fmaf(__half2float(hBv.x), pA.y, a1x); a1y = fmaf(__half2float(hBv.y), pA.y, a1y);
      a0x = fmaf(__half2float(hC.x), pA.z, a0x);  a0y = fmaf(__half2float(hC.y), pA.z, a0y);
      a1x = fmaf(__half2float(hD.x), pA.w, a1x);  a1y = fmaf(__half2float(hD.y), pA.w, a1y);
      den += (pA.x + pA.y) + (pA.z + pA.w);
    }
    for (; i < cnt; i++) {
      int s = s_lds[wave][i];
      float p = p_t[wave][hS][i];
      __half2 hv = *(const __half2*)(h1l + (size_t)s * 128);
      a0x = fmaf(__half2float(hv.x), p, a0x);
      a0y = fmaf(__half2float(hv.y), p, a0y);
      den += p;
    }
  }

  if (valid) {
    float invd = 1.f / den;
    float r0 = (a0x + a1x) * invd;
    float r1 = (a0y + a1y) * invd;
    // sum over 8 heads (lanes sharing lane&7)
    r0 += __shfl_xor(r0, 8);  r1 += __shfl_xor(r1, 8);
    r0 += __shfl_xor(r0, 16); r1 += __shfl_xor(r1, 16);
    r0 += __shfl_xor(r0, 32); r1 += __shfl_xor(r1, 32);
    int ch = (lane & 7) * 2;
    r0 = r0 * 0.125f + b1[ch];
    r1 = r1 * 0.125f + b1[ch + 1];
    r0 = r0 > 0.f ? r0 : __expf(r0) - 1.f;
    r1 = r1 > 0.f ? r1 : __expf(r1) - 1.f;

    float acc2 = 0.f;
#pragma unroll
    for (int k = 0; k < 16; k++) {
      float rs = (k & 1) ? r1 : r0;
      float rk = __shfl(rs, k >> 1);
      if (lane < N_CLS) acc2 = fmaf(rk, W2[k * N_CLS + lane], acc2);
    }
    float sv = 0.f, dv = 0.f;
    if (lane < N_CLS) {
      h2[d * N_CLS + lane] = __float2half(acc2);
      sv = acc2 * att_s2[lane];
      dv = acc2 * att_d2[lane];
    }
#pragma unroll
    for (int off = 32; off; off >>= 1) {
      sv += __shfl_xor(sv, off);
      dv += __shfl_xor(dv, off);
    }
    if (lane == 0) {
      as2[d] = sv;
      ad2[d] = dv;
      atomicMax(&encl, encf(sv));
    }
  }
  __syncthreads();
  if (threadIdx.x == 0) atomicMax(enc2, encl);
}

// ---------------- conv2 aggregation + bias + log_softmax ----------------

__global__ __launch_bounds__(256) void k_agg2(
    const __half* __restrict__ h2, const float* __restrict__ as2,
    const float* __restrict__ ad2, const int* __restrict__ start,
    const int* __restrict__ esrc, const float* __restrict__ b2,
    const unsigned* __restrict__ enc2, float* __restrict__ out) {
  __shared__ __align__(16) float p_l[4][64];
  __shared__ __align__(16) int s_l[4][64];
  int wave = threadIdx.x >> 6, lane = threadIdx.x & 63;
  int d = blockIdx.x * 4 + wave;
  if (d >= N_NODES) return;
  int s0 = start[d];
  int deg = start[d + 1] - s0;
  float adv = ad2[d];
  float cm = decf(enc2[0]) + adv;
  cm = cm > 0.f ? cm : 0.2f * cm;

  float den = 0.f, acc0 = 0.f, acc1 = 0.f;
  const __half* h2l = h2 + lane;
  for (int be = 0; be < deg; be += 64) {
    int cnt = min(64, deg - be);
    if (lane < cnt) {
      int s = esrc[s0 + be + lane];
      s_l[wave][lane] = s;
      float e = as2[s] + adv;
      e = e > 0.f ? e : 0.2f * e;
      p_l[wave][lane] = __expf(e - cm);
    }
    int i = 0;
    for (; i + 3 < cnt; i += 4) {
      int4 s4 = *(const int4*)&s_l[wave][i];
      float4 p4 = *(const float4*)&p_l[wave][i];
      den += (p4.x + p4.y) + (p4.z + p4.w);
      if (lane < N_CLS) {
        __half v0 = h2l[(size_t)s4.x * 40];
        __half v1 = h2l[(size_t)s4.y * 40];
        __half v2 = h2l[(size_t)s4.z * 40];
        __half v3 = h2l[(size_t)s4.w * 40];
        acc0 = fmaf(__half2float(v0), p4.x, acc0);
        acc1 = fmaf(__half2float(v1), p4.y, acc1);
        acc0 = fmaf(__half2float(v2), p4.z, acc0);
        acc1 = fmaf(__half2float(v3), p4.w, acc1);
      }
    }
    for (; i < cnt; i++) {
      int s = s_l[wave][i];
      float p = p_l[wave][i];
      den += p;
      if (lane < N_CLS) acc0 = fmaf(__half2float(h2l[(size_t)s * 40]), p, acc0);
    }
  }
  float iv = 1.f / den;
  float v = (lane < N_CLS) ? (acc0 + acc1) * iv + b2[lane] : -1e30f;
  float mx = v;
#pragma unroll
  for (int off = 32; off; off >>= 1) mx = fmaxf(mx, __shfl_xor(mx, off));
  float ex = (lane < N_CLS) ? __expf(v - mx) : 0.f;
  float sm = ex;
#pragma unroll
  for (int off = 32; off; off >>= 1) sm += __shfl_xor(sm, off);
  float lse = logf(sm);
  if (lane < N_CLS) out[d * N_CLS + lane] = (v - mx) - lse;
}

// ---------------- host launcher ----------------

extern "C" void kernel_launch(void* const* d_in, const int* in_sizes, int n_in,
                              void* d_out, int out_size, void* d_ws, size_t ws_size,
                              hipStream_t stream) {
  const float* x    = (const float*)d_in[0];
  const int*   ei   = (const int*)d_in[1];
  const float* W1   = (const float*)d_in[2];
  const float* as1w = (const float*)d_in[3];
  const float* ad1w = (const float*)d_in[4];
  const float* b1   = (const float*)d_in[5];
  const float* W2   = (const float*)d_in[6];
  const float* as2w = (const float*)d_in[7];
  const float* ad2w = (const float*)d_in[8];
  const float* b2   = (const float*)d_in[9];
  float* out = (float*)d_out;

  char* ws = (char*)d_ws;
  size_t off = 0;
  auto alloc = [&](size_t bytes) -> void* {
    void* p = ws + off;
    off += (bytes + 255) & ~(size_t)255;
    return p;
  };
  __half* h1   = (__half*)alloc((size_t)N_NODES * 128 * 2);
  float* as1   = (float*)alloc((size_t)N_NODES * 8 * 4);
  float* ad1   = (float*)alloc((size_t)N_NODES * 8 * 4);
  __half* h2   = (__half*)alloc((size_t)N_NODES * 40 * 2);
  float* as2   = (float*)alloc((size_t)N_NODES * 4);
  float* ad2   = (float*)alloc((size_t)N_NODES * 4);
  // contiguous zero region: deg | cursor | maxenc(16)
  size_t zbytes = (size_t)2 * N_NODES * 4 + 256;
  int* deg     = (int*)alloc(zbytes);
  int* cursor  = deg + N_NODES;
  unsigned* maxenc = (unsigned*)(cursor + N_NODES);  // [0..7]=as1 heads, [8]=as2
  int* start   = (int*)alloc((size_t)(N_NODES + 1) * 4);
  int* esrc    = (int*)alloc((size_t)ET * 4);
  int* bsum    = (int*)alloc((size_t)NSCB * 4);
  int* boff    = (int*)alloc(256 * 4);

  (void)hipMemsetAsync(deg, 0, zbytes, stream);

  k_xform1<<<XB + HB, 256, 0, stream>>>(x, W1, as1w, ad1w, ei, deg,
                                        h1, as1, ad1, maxenc);
  k_scanA<<<NSCB, 256, 0, stream>>>(deg, bsum);
  k_scanB<<<1, 256, 0, stream>>>(bsum, boff, start);
  k_scanC<<<NSCB, 256, 0, stream>>>(deg, boff, start);
  k_scatter<<<HB, 256, 0, stream>>>(ei, start, cursor, esrc);

  k_agg1<<<(N_NODES + 3) / 4, 256, 0, stream>>>(h1, as1, ad1, start, esrc, b1,
                                                W2, as2w, ad2w, maxenc,
                                                h2, as2, ad2, maxenc + 8);
  k_agg2<<<(N_NODES + 3) / 4, 256, 0, stream>>>(h2, as2, ad2, start, esrc, b2,
                                                maxenc + 8, out);
}

// Round 7
// 267.443 us; speedup vs baseline: 2.3114x; 2.3114x over previous
//
#include <hip/hip_runtime.h>
#include <hip/hip_fp16.h>
#include <math.h>

#define N_NODES 50000
#define N_EDGES 1000000
#define F_IN 128
#define HID 16
#define N_CLS 40
#define HEADS 8
#define ET (N_EDGES + N_NODES)
#define XB ((N_NODES + 63) / 64)      // 782 xform blocks
#define HB ((ET + 255) / 256)         // 4103 hist blocks
#define NSCB ((N_NODES + 255) / 256)  // 196 scan blocks

__device__ __forceinline__ void fma4(float4& acc, float s, const float4& v) {
  acc.x += s * v.x;
  acc.y += s * v.y;
  acc.z += s * v.z;
  acc.w += s * v.w;
}

__device__ __forceinline__ float dot4(float4 a, float4 b) {
  return a.x * b.x + a.y * b.y + a.z * b.z + a.w * b.w;
}

// monotone float<->uint encoding for atomicMax on floats
__device__ __forceinline__ unsigned encf(float f) {
  unsigned b = __float_as_uint(f);
  return (b & 0x80000000u) ? ~b : (b | 0x80000000u);
}
__device__ __forceinline__ float decf(unsigned k) {
  unsigned b = (k & 0x80000000u) ? (k ^ 0x80000000u) : ~k;
  return __uint_as_float(b);
}

// ---------------- conv1 transform (+ fused hist blocks, + fused as1-max) ----

__global__ __launch_bounds__(256) void k_xform1(
    const float* __restrict__ x, const float* __restrict__ W1,
    const float* __restrict__ att_s, const float* __restrict__ att_d,
    const int* __restrict__ ei, int* __restrict__ deg,
    __half* __restrict__ h1, float* __restrict__ as1, float* __restrict__ ad1,
    unsigned* __restrict__ enc1) {
  if (blockIdx.x >= XB) {  // histogram blocks
    int i = (blockIdx.x - XB) * 256 + threadIdx.x;
    if (i < ET) {
      int dd = (i < N_EDGES) ? ei[N_EDGES + i] : (i - N_EDGES);
      atomicAdd(&deg[dd], 1);
    }
    return;
  }
  __shared__ float4 xlds[64 * 32];  // [node][k/4]
  __shared__ float4 wlds[64 * 32];  // [k_local][c/4]
  __shared__ unsigned encl[8];
  int t = threadIdx.x;
  if (t < 8) encl[t] = 0u;
  int tx = t & 15, ty = t >> 4;
  int base = blockIdx.x * 64;
  const float4* x4 = (const float4*)x;
  const float4* W4 = (const float4*)W1;

  for (int i = t; i < 64 * 32; i += 256) {
    int n = i >> 5;
    int gn = base + n;
    float4 v = {0.f, 0.f, 0.f, 0.f};
    if (gn < N_NODES) v = x4[(size_t)gn * 32 + (i & 31)];
    xlds[i] = v;
  }

  float4 accA[4], accB[4];
#pragma unroll
  for (int n = 0; n < 4; n++) {
    accA[n] = {0.f, 0.f, 0.f, 0.f};
    accB[n] = {0.f, 0.f, 0.f, 0.f};
  }
  int n0 = ty * 4;

  for (int half = 0; half < 2; half++) {
    __syncthreads();
    for (int i = t; i < 64 * 32; i += 256)
      wlds[i] = W4[(size_t)(half * 64 + (i >> 5)) * 32 + (i & 31)];
    __syncthreads();
#pragma unroll
    for (int kk = 0; kk < 64; kk += 4) {
      int kq = half * 16 + (kk >> 2);
      float4 xv0 = xlds[(n0 + 0) * 32 + kq];
      float4 xv1 = xlds[(n0 + 1) * 32 + kq];
      float4 xv2 = xlds[(n0 + 2) * 32 + kq];
      float4 xv3 = xlds[(n0 + 3) * 32 + kq];
#pragma unroll
      for (int j = 0; j < 4; j++) {
        float4 wA = wlds[(kk + j) * 32 + tx * 2];
        float4 wB = wlds[(kk + j) * 32 + tx * 2 + 1];
        float s0 = (j == 0) ? xv0.x : (j == 1) ? xv0.y : (j == 2) ? xv0.z : xv0.w;
        float s1 = (j == 0) ? xv1.x : (j == 1) ? xv1.y : (j == 2) ? xv1.z : xv1.w;
        float s2 = (j == 0) ? xv2.x : (j == 1) ? xv2.y : (j == 2) ? xv2.z : xv2.w;
        float s3 = (j == 0) ? xv3.x : (j == 1) ? xv3.y : (j == 2) ? xv3.z : xv3.w;
        fma4(accA[0], s0, wA); fma4(accB[0], s0, wB);
        fma4(accA[1], s1, wA); fma4(accB[1], s1, wB);
        fma4(accA[2], s2, wA); fma4(accB[2], s2, wB);
        fma4(accA[3], s3, wA); fma4(accB[3], s3, wB);
      }
    }
  }

  int c0 = tx * 8;
  float4 asA = *(const float4*)(att_s + c0);
  float4 asB = *(const float4*)(att_s + c0 + 4);
  float4 adA = *(const float4*)(att_d + c0);
  float4 adB = *(const float4*)(att_d + c0 + 4);
  float psmax = -1e30f;
#pragma unroll
  for (int n = 0; n < 4; n++) {
    int gn = base + n0 + n;
    float ps = dot4(accA[n], asA) + dot4(accB[n], asB);
    float pd = dot4(accA[n], adA) + dot4(accB[n], adB);
    ps += __shfl_xor(ps, 1);
    pd += __shfl_xor(pd, 1);
    if (gn < N_NODES) {
      uint4 pk;
      __half2* ph = (__half2*)&pk;
      ph[0] = __floats2half2_rn(accA[n].x, accA[n].y);
      ph[1] = __floats2half2_rn(accA[n].z, accA[n].w);
      ph[2] = __floats2half2_rn(accB[n].x, accB[n].y);
      ph[3] = __floats2half2_rn(accB[n].z, accB[n].w);
      *(uint4*)(h1 + (size_t)gn * 128 + tx * 8) = pk;
      psmax = fmaxf(psmax, ps);
      if ((tx & 1) == 0) {
        as1[gn * 8 + (tx >> 1)] = ps;
        ad1[gn * 8 + (tx >> 1)] = pd;
      }
    }
  }
  if ((tx & 1) == 0) atomicMax(&encl[tx >> 1], encf(psmax));
  __syncthreads();
  if (t < 8) atomicMax(&enc1[t], encl[t]);
}

// ---------------- 3-kernel coalesced exclusive scan of deg -> start ----------

__global__ __launch_bounds__(256) void k_scanA(const int* __restrict__ deg,
                                               int* __restrict__ bsum) {
  int i = blockIdx.x * 256 + threadIdx.x;
  int v = (i < N_NODES) ? deg[i] : 0;
#pragma unroll
  for (int off = 32; off; off >>= 1) v += __shfl_xor(v, off);
  __shared__ int ws[4];
  if ((threadIdx.x & 63) == 0) ws[threadIdx.x >> 6] = v;
  __syncthreads();
  if (threadIdx.x == 0) bsum[blockIdx.x] = ws[0] + ws[1] + ws[2] + ws[3];
}

__global__ __launch_bounds__(256) void k_scanB(const int* __restrict__ bsum,
                                               int* __restrict__ boff,
                                               int* __restrict__ start) {
  __shared__ int s[256];
  int t = threadIdx.x;
  int v0 = (t < NSCB) ? bsum[t] : 0;
  s[t] = v0;
  __syncthreads();
  for (int off = 1; off < 256; off <<= 1) {
    int v = (t >= off) ? s[t - off] : 0;
    __syncthreads();
    s[t] += v;
    __syncthreads();
  }
  boff[t] = s[t] - v0;  // exclusive
  if (t == 0) start[N_NODES] = ET;
}

__global__ __launch_bounds__(256) void k_scanC(const int* __restrict__ deg,
                                               const int* __restrict__ boff,
                                               int* __restrict__ start) {
  __shared__ int s[256];
  int t = threadIdx.x;
  int i = blockIdx.x * 256 + t;
  int v0 = (i < N_NODES) ? deg[i] : 0;
  s[t] = v0;
  __syncthreads();
  for (int off = 1; off < 256; off <<= 1) {
    int v = (t >= off) ? s[t - off] : 0;
    __syncthreads();
    s[t] += v;
    __syncthreads();
  }
  if (i < N_NODES) start[i] = boff[blockIdx.x] + s[t] - v0;
}

__global__ void k_scatter(const int* __restrict__ ei, const int* __restrict__ start,
                          int* __restrict__ cursor, int* __restrict__ esrc) {
  int i = blockIdx.x * blockDim.x + threadIdx.x;
  if (i >= ET) return;
  int s, d;
  if (i < N_EDGES) { s = ei[i]; d = ei[N_EDGES + i]; }
  else { s = i - N_EDGES; d = s; }
  int pos = atomicAdd(&cursor[d], 1);
  esrc[start[d] + pos] = s;
}

// ---------------- conv1 aggregation + fused conv2 transform ----------------
// ROUND-5 STRUCTURE (measured 80 us): lane-parallel exp phase -> LDS ->
// fixed-unroll serial gather with 4 loads in flight; unnormalized accumulate.

__global__ __launch_bounds__(256) void k_agg1(
    const __half* __restrict__ h1, const float* __restrict__ as1,
    const float* __restrict__ ad1, const int* __restrict__ start,
    const int* __restrict__ esrc, const float* __restrict__ b1,
    const float* __restrict__ W2, const float* __restrict__ att_s2,
    const float* __restrict__ att_d2, const unsigned* __restrict__ as1maxEnc,
    __half* __restrict__ h2, float* __restrict__ as2, float* __restrict__ ad2) {
  __shared__ float p_lds[4][64][8];
  __shared__ int s_lds[4][64];
  int wave = threadIdx.x >> 6, lane = threadIdx.x & 63;
  int d = blockIdx.x * 4 + wave;
  if (d >= N_NODES) return;
  int s0 = start[d];
  int deg = start[d + 1] - s0;

  float4 av0 = *(const float4*)(ad1 + d * 8);
  float4 av1 = *(const float4*)(ad1 + d * 8 + 4);
  float ad[8] = {av0.x, av0.y, av0.z, av0.w, av1.x, av1.y, av1.z, av1.w};
  float c[8], den[8];
#pragma unroll
  for (int h = 0; h < 8; h++) {
    float e = decf(as1maxEnc[h]) + ad[h];
    c[h] = e > 0.f ? e : 0.2f * e;   // upper bound on leaky(as+ad) over segment
    den[h] = 0.f;
  }

  int hsel = lane >> 3;  // head for this lane's channel pair (2*lane, 2*lane+1)
  float accx = 0.f, accy = 0.f;
  const __half* h1l = h1 + lane * 2;

  for (int be = 0; be < deg; be += 64) {
    int cnt = min(64, deg - be);
    if (lane < cnt) {
      int s = esrc[s0 + be + lane];
      s_lds[wave][lane] = s;
      float4 p0 = *(const float4*)(as1 + s * 8);
      float4 p1 = *(const float4*)(as1 + s * 8 + 4);
      float e[8] = {p0.x, p0.y, p0.z, p0.w, p1.x, p1.y, p1.z, p1.w};
      float pv[8];
#pragma unroll
      for (int h = 0; h < 8; h++) {
        float v = e[h] + ad[h];
        v = v > 0.f ? v : 0.2f * v;
        pv[h] = __expf(v - c[h]);
        den[h] += pv[h];
      }
      *(float4*)&p_lds[wave][lane][0] = make_float4(pv[0], pv[1], pv[2], pv[3]);
      *(float4*)&p_lds[wave][lane][4] = make_float4(pv[4], pv[5], pv[6], pv[7]);
    }
    asm volatile("s_waitcnt lgkmcnt(0)" ::: "memory");
    int i = 0;
    for (; i + 3 < cnt; i += 4) {
      int sA = s_lds[wave][i + 0], sB = s_lds[wave][i + 1];
      int sC = s_lds[wave][i + 2], sD = s_lds[wave][i + 3];
      float pA = p_lds[wave][i + 0][hsel], pB = p_lds[wave][i + 1][hsel];
      float pC = p_lds[wave][i + 2][hsel], pD = p_lds[wave][i + 3][hsel];
      float2 fA = __half22float2(*(const __half2*)(h1l + (size_t)sA * 128));
      float2 fB = __half22float2(*(const __half2*)(h1l + (size_t)sB * 128));
      float2 fC = __half22float2(*(const __half2*)(h1l + (size_t)sC * 128));
      float2 fD = __half22float2(*(const __half2*)(h1l + (size_t)sD * 128));
      accx += fA.x * pA; accy += fA.y * pA;
      accx += fB.x * pB; accy += fB.y * pB;
      accx += fC.x * pC; accy += fC.y * pC;
      accx += fD.x * pD; accy += fD.y * pD;
    }
    for (; i < cnt; i++) {
      int s = s_lds[wave][i];
      float p = p_lds[wave][i][hsel];
      float2 f = __half22float2(*(const __half2*)(h1l + (size_t)s * 128));
      accx += f.x * p; accy += f.y * p;
    }
    asm volatile("s_waitcnt lgkmcnt(0)" ::: "memory");
  }

  // reduce den across lanes
#pragma unroll
  for (int h = 0; h < 8; h++) {
#pragma unroll
    for (int off = 32; off; off >>= 1) den[h] += __shfl_xor(den[h], off);
  }
  int hl = hsel & 3;
  float dA = (hl == 0) ? den[0] : (hl == 1) ? den[1] : (hl == 2) ? den[2] : den[3];
  float dB = (hl == 0) ? den[4] : (hl == 1) ? den[5] : (hl == 2) ? den[6] : den[7];
  float invd = 1.f / ((hsel & 4) ? dB : dA);
  float r0 = accx * invd, r1 = accy * invd;
  // sum over 8 heads (lanes sharing lane&7)
#pragma unroll
  for (int off = 8; off < 64; off <<= 1) {
    r0 += __shfl_xor(r0, off);
    r1 += __shfl_xor(r1, off);
  }
  int ch = (lane & 7) * 2;
  r0 = r0 * 0.125f + b1[ch];
  r1 = r1 * 0.125f + b1[ch + 1];
  r0 = r0 > 0.f ? r0 : __expf(r0) - 1.f;
  r1 = r1 > 0.f ? r1 : __expf(r1) - 1.f;

  // fused conv2 transform: h2[d][j] = sum_k r_k W2[k][j]
  float acc2 = 0.f;
#pragma unroll
  for (int k = 0; k < 16; k++) {
    float rs = (k & 1) ? r1 : r0;
    float rk = __shfl(rs, k >> 1);
    if (lane < N_CLS) acc2 += rk * W2[k * N_CLS + lane];
  }
  float sv = 0.f, dv = 0.f;
  if (lane < N_CLS) {
    h2[d * N_CLS + lane] = __float2half(acc2);
    sv = acc2 * att_s2[lane];
    dv = acc2 * att_d2[lane];
  }
#pragma unroll
  for (int off = 32; off; off >>= 1) {
    sv += __shfl_xor(sv, off);
    dv += __shfl_xor(dv, off);
  }
  if (lane == 0) { as2[d] = sv; ad2[d] = dv; }
}

// ---------------- global max of as2 ----------------

__global__ __launch_bounds__(256) void k_maxas2(const float* __restrict__ as2,
                                                unsigned* __restrict__ enc) {
  int t = blockIdx.x * 256 + threadIdx.x;  // 64 blocks -> 16384 threads
  float mx = -1e30f;
  for (int r = t; r < N_NODES; r += 16384) mx = fmaxf(mx, as2[r]);
#pragma unroll
  for (int off = 32; off; off >>= 1) mx = fmaxf(mx, __shfl_xor(mx, off));
  if ((threadIdx.x & 63) == 0) atomicMax(enc, encf(mx));
}

// ---------------- conv2 aggregation + bias + log_softmax ----------------
// ROUND-5 STRUCTURE (measured-good).

__global__ __launch_bounds__(256) void k_agg2(
    const __half* __restrict__ h2, const float* __restrict__ as2,
    const float* __restrict__ ad2, const int* __restrict__ start,
    const int* __restrict__ esrc, const float* __restrict__ b2,
    const unsigned* __restrict__ as2maxEnc, float* __restrict__ out) {
  __shared__ float p_lds[4][64];
  __shared__ int s_lds[4][64];
  int wave = threadIdx.x >> 6, lane = threadIdx.x & 63;
  int d = blockIdx.x * 4 + wave;
  if (d >= N_NODES) return;
  int s0 = start[d];
  int deg = start[d + 1] - s0;
  float adv = ad2[d];
  float cm = decf(as2maxEnc[0]) + adv;
  cm = cm > 0.f ? cm : 0.2f * cm;

  float den = 0.f, acc = 0.f;
  for (int be = 0; be < deg; be += 64) {
    int cnt = min(64, deg - be);
    if (lane < cnt) {
      int s = esrc[s0 + be + lane];
      s_lds[wave][lane] = s;
      float e = as2[s] + adv;
      e = e > 0.f ? e : 0.2f * e;
      float p = __expf(e - cm);
      den += p;
      p_lds[wave][lane] = p;
    }
    asm volatile("s_waitcnt lgkmcnt(0)" ::: "memory");
    int i = 0;
    for (; i + 1 < cnt; i += 2) {
      int sA = s_lds[wave][i], sB = s_lds[wave][i + 1];
      float pA = p_lds[wave][i], pB = p_lds[wave][i + 1];
      if (lane < N_CLS) {
        float fA = __half2float(h2[(size_t)sA * N_CLS + lane]);
        float fB = __half2float(h2[(size_t)sB * N_CLS + lane]);
        acc += fA * pA;
        acc += fB * pB;
      }
    }
    if (i < cnt) {
      int s = s_lds[wave][i];
      float p = p_lds[wave][i];
      if (lane < N_CLS) acc += __half2float(h2[(size_t)s * N_CLS + lane]) * p;
    }
    asm volatile("s_waitcnt lgkmcnt(0)" ::: "memory");
  }
#pragma unroll
  for (int off = 32; off; off >>= 1) den += __shfl_xor(den, off);
  float iv = 1.f / den;

  float v = (lane < N_CLS) ? acc * iv + b2[lane] : -1e30f;
  float mx = v;
#pragma unroll
  for (int off = 32; off; off >>= 1) mx = fmaxf(mx, __shfl_xor(mx, off));
  float ex = (lane < N_CLS) ? __expf(v - mx) : 0.f;
  float sm = ex;
#pragma unroll
  for (int off = 32; off; off >>= 1) sm += __shfl_xor(sm, off);
  float lse = logf(sm);
  if (lane < N_CLS) out[d * N_CLS + lane] = (v - mx) - lse;
}

// ---------------- host launcher ----------------

extern "C" void kernel_launch(void* const* d_in, const int* in_sizes, int n_in,
                              void* d_out, int out_size, void* d_ws, size_t ws_size,
                              hipStream_t stream) {
  const float* x    = (const float*)d_in[0];
  const int*   ei   = (const int*)d_in[1];
  const float* W1   = (const float*)d_in[2];
  const float* as1w = (const float*)d_in[3];
  const float* ad1w = (const float*)d_in[4];
  const float* b1   = (const float*)d_in[5];
  const float* W2   = (const float*)d_in[6];
  const float* as2w = (const float*)d_in[7];
  const float* ad2w = (const float*)d_in[8];
  const float* b2   = (const float*)d_in[9];
  float* out = (float*)d_out;

  char* ws = (char*)d_ws;
  size_t off = 0;
  auto alloc = [&](size_t bytes) -> void* {
    void* p = ws + off;
    off += (bytes + 255) & ~(size_t)255;
    return p;
  };
  __half* h1   = (__half*)alloc((size_t)N_NODES * 128 * 2);
  float* as1   = (float*)alloc((size_t)N_NODES * 8 * 4);
  float* ad1   = (float*)alloc((size_t)N_NODES * 8 * 4);
  __half* h2   = (__half*)alloc((size_t)N_NODES * 40 * 2);
  float* as2   = (float*)alloc((size_t)N_NODES * 4);
  float* ad2   = (float*)alloc((size_t)N_NODES * 4);
  // contiguous zero region: deg | cursor | maxenc(16)
  size_t zbytes = (size_t)2 * N_NODES * 4 + 256;
  int* deg     = (int*)alloc(zbytes);
  int* cursor  = deg + N_NODES;
  unsigned* maxenc = (unsigned*)(cursor + N_NODES);  // [0..7]=as1 heads, [8]=as2
  int* start   = (int*)alloc((size_t)(N_NODES + 1) * 4);
  int* esrc    = (int*)alloc((size_t)ET * 4);
  int* bsum    = (int*)alloc((size_t)NSCB * 4);
  int* boff    = (int*)alloc(256 * 4);

  (void)hipMemsetAsync(deg, 0, zbytes, stream);

  k_xform1<<<XB + HB, 256, 0, stream>>>(x, W1, as1w, ad1w, ei, deg,
                                        h1, as1, ad1, maxenc);
  k_scanA<<<NSCB, 256, 0, stream>>>(deg, bsum);
  k_scanB<<<1, 256, 0, stream>>>(bsum, boff, start);
  k_scanC<<<NSCB, 256, 0, stream>>>(deg, boff, start);
  k_scatter<<<HB, 256, 0, stream>>>(ei, start, cursor, esrc);

  k_agg1<<<(N_NODES + 3) / 4, 256, 0, stream>>>(h1, as1, ad1, start, esrc, b1,
                                                W2, as2w, ad2w, maxenc,
                                                h2, as2, ad2);
  k_maxas2<<<64, 256, 0, stream>>>(as2, maxenc + 8);
  k_agg2<<<(N_NODES + 3) / 4, 256, 0, stream>>>(h2, as2, ad2, start, esrc, b2,
                                                maxenc + 8, out);
}

// Round 8
// 259.088 us; speedup vs baseline: 2.3859x; 1.0322x over previous
//
#include <hip/hip_runtime.h>
#include <hip/hip_fp16.h>
#include <math.h>

#define N_NODES 50000
#define N_EDGES 1000000
#define F_IN 128
#define HID 16
#define N_CLS 40
#define HEADS 8
#define ET (N_EDGES + N_NODES)
#define XB ((N_NODES + 63) / 64)      // 782 xform blocks
#define HB ((ET + 255) / 256)         // 4103 hist blocks
#define NSCB ((N_NODES + 255) / 256)  // 196 scan blocks

__device__ __forceinline__ void fma4(float4& acc, float s, const float4& v) {
  acc.x += s * v.x;
  acc.y += s * v.y;
  acc.z += s * v.z;
  acc.w += s * v.w;
}

__device__ __forceinline__ float dot4(float4 a, float4 b) {
  return a.x * b.x + a.y * b.y + a.z * b.z + a.w * b.w;
}

// monotone float<->uint encoding for atomicMax on floats
__device__ __forceinline__ unsigned encf(float f) {
  unsigned b = __float_as_uint(f);
  return (b & 0x80000000u) ? ~b : (b | 0x80000000u);
}
__device__ __forceinline__ float decf(unsigned k) {
  unsigned b = (k & 0x80000000u) ? (k ^ 0x80000000u) : ~k;
  return __uint_as_float(b);
}

// ---------------- conv1 transform (+ fused hist blocks, + fused as1-max) ----

__global__ __launch_bounds__(256) void k_xform1(
    const float* __restrict__ x, const float* __restrict__ W1,
    const float* __restrict__ att_s, const float* __restrict__ att_d,
    const int* __restrict__ ei, int* __restrict__ deg,
    __half* __restrict__ h1, float* __restrict__ as1, float* __restrict__ ad1,
    unsigned* __restrict__ enc1) {
  if (blockIdx.x >= XB) {  // histogram blocks
    int i = (blockIdx.x - XB) * 256 + threadIdx.x;
    if (i < ET) {
      int dd = (i < N_EDGES) ? ei[N_EDGES + i] : (i - N_EDGES);
      atomicAdd(&deg[dd], 1);
    }
    return;
  }
  __shared__ float4 xlds[64 * 32];  // [node][k/4]
  __shared__ float4 wlds[64 * 32];  // [k_local][c/4]
  __shared__ unsigned encl[8];
  int t = threadIdx.x;
  if (t < 8) encl[t] = 0u;
  int tx = t & 15, ty = t >> 4;
  int base = blockIdx.x * 64;
  const float4* x4 = (const float4*)x;
  const float4* W4 = (const float4*)W1;

  for (int i = t; i < 64 * 32; i += 256) {
    int n = i >> 5;
    int gn = base + n;
    float4 v = {0.f, 0.f, 0.f, 0.f};
    if (gn < N_NODES) v = x4[(size_t)gn * 32 + (i & 31)];
    xlds[i] = v;
  }

  float4 accA[4], accB[4];
#pragma unroll
  for (int n = 0; n < 4; n++) {
    accA[n] = {0.f, 0.f, 0.f, 0.f};
    accB[n] = {0.f, 0.f, 0.f, 0.f};
  }
  int n0 = ty * 4;

  for (int half = 0; half < 2; half++) {
    __syncthreads();
    for (int i = t; i < 64 * 32; i += 256)
      wlds[i] = W4[(size_t)(half * 64 + (i >> 5)) * 32 + (i & 31)];
    __syncthreads();
#pragma unroll
    for (int kk = 0; kk < 64; kk += 4) {
      int kq = half * 16 + (kk >> 2);
      float4 xv0 = xlds[(n0 + 0) * 32 + kq];
      float4 xv1 = xlds[(n0 + 1) * 32 + kq];
      float4 xv2 = xlds[(n0 + 2) * 32 + kq];
      float4 xv3 = xlds[(n0 + 3) * 32 + kq];
#pragma unroll
      for (int j = 0; j < 4; j++) {
        float4 wA = wlds[(kk + j) * 32 + tx * 2];
        float4 wB = wlds[(kk + j) * 32 + tx * 2 + 1];
        float s0 = (j == 0) ? xv0.x : (j == 1) ? xv0.y : (j == 2) ? xv0.z : xv0.w;
        float s1 = (j == 0) ? xv1.x : (j == 1) ? xv1.y : (j == 2) ? xv1.z : xv1.w;
        float s2 = (j == 0) ? xv2.x : (j == 1) ? xv2.y : (j == 2) ? xv2.z : xv2.w;
        float s3 = (j == 0) ? xv3.x : (j == 1) ? xv3.y : (j == 2) ? xv3.z : xv3.w;
        fma4(accA[0], s0, wA); fma4(accB[0], s0, wB);
        fma4(accA[1], s1, wA); fma4(accB[1], s1, wB);
        fma4(accA[2], s2, wA); fma4(accB[2], s2, wB);
        fma4(accA[3], s3, wA); fma4(accB[3], s3, wB);
      }
    }
  }

  int c0 = tx * 8;
  float4 asA = *(const float4*)(att_s + c0);
  float4 asB = *(const float4*)(att_s + c0 + 4);
  float4 adA = *(const float4*)(att_d + c0);
  float4 adB = *(const float4*)(att_d + c0 + 4);
  float psmax = -1e30f;
#pragma unroll
  for (int n = 0; n < 4; n++) {
    int gn = base + n0 + n;
    float ps = dot4(accA[n], asA) + dot4(accB[n], asB);
    float pd = dot4(accA[n], adA) + dot4(accB[n], adB);
    ps += __shfl_xor(ps, 1);
    pd += __shfl_xor(pd, 1);
    if (gn < N_NODES) {
      uint4 pk;
      __half2* ph = (__half2*)&pk;
      ph[0] = __floats2half2_rn(accA[n].x, accA[n].y);
      ph[1] = __floats2half2_rn(accA[n].z, accA[n].w);
      ph[2] = __floats2half2_rn(accB[n].x, accB[n].y);
      ph[3] = __floats2half2_rn(accB[n].z, accB[n].w);
      *(uint4*)(h1 + (size_t)gn * 128 + tx * 8) = pk;
      psmax = fmaxf(psmax, ps);
      if ((tx & 1) == 0) {
        as1[gn * 8 + (tx >> 1)] = ps;
        ad1[gn * 8 + (tx >> 1)] = pd;
      }
    }
  }
  if ((tx & 1) == 0) atomicMax(&encl[tx >> 1], encf(psmax));
  __syncthreads();
  if (t < 8) atomicMax(&enc1[t], encl[t]);
}

// ---------------- 3-kernel coalesced exclusive scan of deg -> start ----------

__global__ __launch_bounds__(256) void k_scanA(const int* __restrict__ deg,
                                               int* __restrict__ bsum) {
  int i = blockIdx.x * 256 + threadIdx.x;
  int v = (i < N_NODES) ? deg[i] : 0;
#pragma unroll
  for (int off = 32; off; off >>= 1) v += __shfl_xor(v, off);
  __shared__ int ws[4];
  if ((threadIdx.x & 63) == 0) ws[threadIdx.x >> 6] = v;
  __syncthreads();
  if (threadIdx.x == 0) bsum[blockIdx.x] = ws[0] + ws[1] + ws[2] + ws[3];
}

__global__ __launch_bounds__(256) void k_scanB(const int* __restrict__ bsum,
                                               int* __restrict__ boff,
                                               int* __restrict__ start) {
  __shared__ int s[256];
  int t = threadIdx.x;
  int v0 = (t < NSCB) ? bsum[t] : 0;
  s[t] = v0;
  __syncthreads();
  for (int off = 1; off < 256; off <<= 1) {
    int v = (t >= off) ? s[t - off] : 0;
    __syncthreads();
    s[t] += v;
    __syncthreads();
  }
  boff[t] = s[t] - v0;  // exclusive
  if (t == 0) start[N_NODES] = ET;
}

__global__ __launch_bounds__(256) void k_scanC(const int* __restrict__ deg,
                                               const int* __restrict__ boff,
                                               int* __restrict__ start) {
  __shared__ int s[256];
  int t = threadIdx.x;
  int i = blockIdx.x * 256 + t;
  int v0 = (i < N_NODES) ? deg[i] : 0;
  s[t] = v0;
  __syncthreads();
  for (int off = 1; off < 256; off <<= 1) {
    int v = (t >= off) ? s[t - off] : 0;
    __syncthreads();
    s[t] += v;
    __syncthreads();
  }
  if (i < N_NODES) start[i] = boff[blockIdx.x] + s[t] - v0;
}

__global__ void k_scatter(const int* __restrict__ ei, const int* __restrict__ start,
                          int* __restrict__ cursor, int* __restrict__ esrc) {
  int i = blockIdx.x * blockDim.x + threadIdx.x;
  if (i >= ET) return;
  int s, d;
  if (i < N_EDGES) { s = ei[i]; d = ei[N_EDGES + i]; }
  else { s = i - N_EDGES; d = s; }
  int pos = atomicAdd(&cursor[d], 1);
  esrc[start[d] + pos] = s;
}

// ---------------- conv1 aggregation + fused conv2 transform ----------------
// Round-5 skeleton; serial phase: transposed half2-splat p (b128 reads) +
// v_pk_fma_f16 with per-chunk fp32 promotion; pre-shifted byte offsets.

__global__ __launch_bounds__(256) void k_agg1(
    const __half* __restrict__ h1, const float* __restrict__ as1,
    const float* __restrict__ ad1, const int* __restrict__ start,
    const int* __restrict__ esrc, const float* __restrict__ b1,
    const float* __restrict__ W2, const float* __restrict__ att_s2,
    const float* __restrict__ att_d2, const unsigned* __restrict__ as1maxEnc,
    __half* __restrict__ h2, float* __restrict__ as2, float* __restrict__ ad2) {
  __shared__ __align__(16) __half2 p_t[4][8][68];  // [wave][head][edge] splat
  __shared__ __align__(16) int s_lds[4][64];       // byte offsets (s<<8)
  int wave = threadIdx.x >> 6, lane = threadIdx.x & 63;
  int d = blockIdx.x * 4 + wave;
  if (d >= N_NODES) return;
  int s0 = start[d];
  int deg = start[d + 1] - s0;

  float4 av0 = *(const float4*)(ad1 + d * 8);
  float4 av1 = *(const float4*)(ad1 + d * 8 + 4);
  float ad[8] = {av0.x, av0.y, av0.z, av0.w, av1.x, av1.y, av1.z, av1.w};
  float c[8], den[8];
#pragma unroll
  for (int h = 0; h < 8; h++) {
    float e = decf(as1maxEnc[h]) + ad[h];
    c[h] = e > 0.f ? e : 0.2f * e;   // upper bound on leaky(as+ad) over segment
    den[h] = 0.f;
  }

  int hsel = lane >> 3;  // head for this lane's channel pair
  float accx = 0.f, accy = 0.f;
  const __half* h1l = h1 + lane * 2;

  for (int be = 0; be < deg; be += 64) {
    int cnt = min(64, deg - be);
    if (lane < cnt) {
      int s = esrc[s0 + be + lane];
      s_lds[wave][lane] = s << 8;  // byte offset into h1 (128 halves = 256B)
      float4 p0 = *(const float4*)(as1 + s * 8);
      float4 p1 = *(const float4*)(as1 + s * 8 + 4);
      float e[8] = {p0.x, p0.y, p0.z, p0.w, p1.x, p1.y, p1.z, p1.w};
#pragma unroll
      for (int h = 0; h < 8; h++) {
        float v = e[h] + ad[h];
        v = v > 0.f ? v : 0.2f * v;
        float pv = __expf(v - c[h]);
        den[h] += pv;
        __half hp = __float2half(pv);
        p_t[wave][h][lane] = __half2{hp, hp};
      }
    }
    asm volatile("s_waitcnt lgkmcnt(0)" ::: "memory");
    __half2 acch0 = __floats2half2_rn(0.f, 0.f);
    __half2 acch1 = __floats2half2_rn(0.f, 0.f);
    int i = 0;
    for (; i + 3 < cnt; i += 4) {
      int4 sA = *(const int4*)&s_lds[wave][i];
      uint4 pw = *(const uint4*)&p_t[wave][hsel][i];
      const __half2* pp = (const __half2*)&pw;
      __half2 hA = *(const __half2*)((const char*)h1l + (unsigned)sA.x);
      __half2 hB = *(const __half2*)((const char*)h1l + (unsigned)sA.y);
      __half2 hC = *(const __half2*)((const char*)h1l + (unsigned)sA.z);
      __half2 hD = *(const __half2*)((const char*)h1l + (unsigned)sA.w);
      acch0 = __hfma2(hA, pp[0], acch0);
      acch1 = __hfma2(hB, pp[1], acch1);
      acch0 = __hfma2(hC, pp[2], acch0);
      acch1 = __hfma2(hD, pp[3], acch1);
    }
    for (; i < cnt; i++) {
      int sb = s_lds[wave][i];
      __half2 pv = p_t[wave][hsel][i];
      __half2 hv = *(const __half2*)((const char*)h1l + (unsigned)sb);
      acch0 = __hfma2(hv, pv, acch0);
    }
    // promote chunk accumulators to fp32
    float2 t0 = __half22float2(acch0);
    float2 t1 = __half22float2(acch1);
    accx += t0.x + t1.x;
    accy += t0.y + t1.y;
    asm volatile("s_waitcnt lgkmcnt(0)" ::: "memory");
  }

  // reduce den across lanes
#pragma unroll
  for (int h = 0; h < 8; h++) {
#pragma unroll
    for (int off = 32; off; off >>= 1) den[h] += __shfl_xor(den[h], off);
  }
  int hl = hsel & 3;
  float dA = (hl == 0) ? den[0] : (hl == 1) ? den[1] : (hl == 2) ? den[2] : den[3];
  float dB = (hl == 0) ? den[4] : (hl == 1) ? den[5] : (hl == 2) ? den[6] : den[7];
  float invd = 1.f / ((hsel & 4) ? dB : dA);
  float r0 = accx * invd, r1 = accy * invd;
  // sum over 8 heads (lanes sharing lane&7)
#pragma unroll
  for (int off = 8; off < 64; off <<= 1) {
    r0 += __shfl_xor(r0, off);
    r1 += __shfl_xor(r1, off);
  }
  int ch = (lane & 7) * 2;
  r0 = r0 * 0.125f + b1[ch];
  r1 = r1 * 0.125f + b1[ch + 1];
  r0 = r0 > 0.f ? r0 : __expf(r0) - 1.f;
  r1 = r1 > 0.f ? r1 : __expf(r1) - 1.f;

  // fused conv2 transform: h2[d][j] = sum_k r_k W2[k][j]
  float acc2 = 0.f;
#pragma unroll
  for (int k = 0; k < 16; k++) {
    float rs = (k & 1) ? r1 : r0;
    float rk = __shfl(rs, k >> 1);
    if (lane < N_CLS) acc2 += rk * W2[k * N_CLS + lane];
  }
  float sv = 0.f, dv = 0.f;
  if (lane < N_CLS) {
    h2[d * N_CLS + lane] = __float2half(acc2);
    sv = acc2 * att_s2[lane];
    dv = acc2 * att_d2[lane];
  }
#pragma unroll
  for (int off = 32; off; off >>= 1) {
    sv += __shfl_xor(sv, off);
    dv += __shfl_xor(dv, off);
  }
  if (lane == 0) { as2[d] = sv; ad2[d] = dv; }
}

// ---------------- global max of as2 ----------------

__global__ __launch_bounds__(256) void k_maxas2(const float* __restrict__ as2,
                                                unsigned* __restrict__ enc) {
  int t = blockIdx.x * 256 + threadIdx.x;  // 64 blocks -> 16384 threads
  float mx = -1e30f;
  for (int r = t; r < N_NODES; r += 16384) mx = fmaxf(mx, as2[r]);
#pragma unroll
  for (int off = 32; off; off >>= 1) mx = fmaxf(mx, __shfl_xor(mx, off));
  if ((threadIdx.x & 63) == 0) atomicMax(enc, encf(mx));
}

// ---------------- conv2 aggregation + bias + log_softmax ----------------
// 60 lanes = 20 channel-pairs x 3 edge-slots; den in exp phase; fp32 accum.

__global__ __launch_bounds__(256) void k_agg2(
    const __half* __restrict__ h2, const float* __restrict__ as2,
    const float* __restrict__ ad2, const int* __restrict__ start,
    const int* __restrict__ esrc, const float* __restrict__ b2,
    const unsigned* __restrict__ as2maxEnc, float* __restrict__ out) {
  __shared__ __align__(16) float p_l[4][64];
  __shared__ __align__(16) int s_l[4][64];  // byte offsets (s*80)
  int wave = threadIdx.x >> 6, lane = threadIdx.x & 63;
  int d = blockIdx.x * 4 + wave;
  if (d >= N_NODES) return;
  int s0 = start[d];
  int deg = start[d + 1] - s0;
  float adv = ad2[d];
  float cm = decf(as2maxEnc[0]) + adv;
  cm = cm > 0.f ? cm : 0.2f * cm;

  int cp = lane % 20;        // channel pair (ch 2cp, 2cp+1)
  int es = lane / 20;        // edge slot 0..2 (lanes >= 60 idle in serial)
  const char* h2b = (const char*)h2 + cp * 4;

  float den = 0.f, acc0 = 0.f, acc1 = 0.f;
  for (int be = 0; be < deg; be += 64) {
    int cnt = min(64, deg - be);
    if (lane < cnt) {
      int s = esrc[s0 + be + lane];
      s_l[wave][lane] = s * 80;  // byte offset into h2 (40 halves)
      float e = as2[s] + adv;
      e = e > 0.f ? e : 0.2f * e;
      float p = __expf(e - cm);
      den += p;
      p_l[wave][lane] = p;
    }
    asm volatile("s_waitcnt lgkmcnt(0)" ::: "memory");
    if (es < 3) {
      for (int i = 0; i < cnt; i += 3) {
        int e = i + es;
        if (e < cnt) {
          int sb = s_l[wave][e];
          float p = p_l[wave][e];
          __half2 hv = *(const __half2*)(h2b + (unsigned)sb);
          acc0 = fmaf(__half2float(hv.x), p, acc0);
          acc1 = fmaf(__half2float(hv.y), p, acc1);
        }
      }
    }
    asm volatile("s_waitcnt lgkmcnt(0)" ::: "memory");
  }
#pragma unroll
  for (int off = 32; off; off >>= 1) den += __shfl_xor(den, off);
  float iv = 1.f / den;

  // combine 3 edge-slots: lanes 0..19 gather from +20, +40
  acc0 += __shfl(acc0, lane + 20) + __shfl(acc0, lane + 40);
  acc1 += __shfl(acc1, lane + 20) + __shfl(acc1, lane + 40);
  // distribute pairs to 40-lane layout: channel j from lane j>>1, comp j&1
  float va = __shfl(acc0, lane >> 1);
  float vb = __shfl(acc1, lane >> 1);
  float v = (lane & 1) ? vb : va;
  v = (lane < N_CLS) ? v * iv + b2[lane] : -1e30f;

  float mx = v;
#pragma unroll
  for (int off = 32; off; off >>= 1) mx = fmaxf(mx, __shfl_xor(mx, off));
  float ex = (lane < N_CLS) ? __expf(v - mx) : 0.f;
  float sm = ex;
#pragma unroll
  for (int off = 32; off; off >>= 1) sm += __shfl_xor(sm, off);
  float lse = logf(sm);
  if (lane < N_CLS) out[d * N_CLS + lane] = (v - mx) - lse;
}

// ---------------- host launcher ----------------

extern "C" void kernel_launch(void* const* d_in, const int* in_sizes, int n_in,
                              void* d_out, int out_size, void* d_ws, size_t ws_size,
                              hipStream_t stream) {
  const float* x    = (const float*)d_in[0];
  const int*   ei   = (const int*)d_in[1];
  const float* W1   = (const float*)d_in[2];
  const float* as1w = (const float*)d_in[3];
  const float* ad1w = (const float*)d_in[4];
  const float* b1   = (const float*)d_in[5];
  const float* W2   = (const float*)d_in[6];
  const float* as2w = (const float*)d_in[7];
  const float* ad2w = (const float*)d_in[8];
  const float* b2   = (const float*)d_in[9];
  float* out = (float*)d_out;

  char* ws = (char*)d_ws;
  size_t off = 0;
  auto alloc = [&](size_t bytes) -> void* {
    void* p = ws + off;
    off += (bytes + 255) & ~(size_t)255;
    return p;
  };
  __half* h1   = (__half*)alloc((size_t)N_NODES * 128 * 2);
  float* as1   = (float*)alloc((size_t)N_NODES * 8 * 4);
  float* ad1   = (float*)alloc((size_t)N_NODES * 8 * 4);
  __half* h2   = (__half*)alloc((size_t)N_NODES * 40 * 2);
  float* as2   = (float*)alloc((size_t)N_NODES * 4);
  float* ad2   = (float*)alloc((size_t)N_NODES * 4);
  // contiguous zero region: deg | cursor | maxenc(16)
  size_t zbytes = (size_t)2 * N_NODES * 4 + 256;
  int* deg     = (int*)alloc(zbytes);
  int* cursor  = deg + N_NODES;
  unsigned* maxenc = (unsigned*)(cursor + N_NODES);  // [0..7]=as1 heads, [8]=as2
  int* start   = (int*)alloc((size_t)(N_NODES + 1) * 4);
  int* esrc    = (int*)alloc((size_t)ET * 4);
  int* bsum    = (int*)alloc((size_t)NSCB * 4);
  int* boff    = (int*)alloc(256 * 4);

  (void)hipMemsetAsync(deg, 0, zbytes, stream);

  k_xform1<<<XB + HB, 256, 0, stream>>>(x, W1, as1w, ad1w, ei, deg,
                                        h1, as1, ad1, maxenc);
  k_scanA<<<NSCB, 256, 0, stream>>>(deg, bsum);
  k_scanB<<<1, 256, 0, stream>>>(bsum, boff, start);
  k_scanC<<<NSCB, 256, 0, stream>>>(deg, boff, start);
  k_scatter<<<HB, 256, 0, stream>>>(ei, start, cursor, esrc);

  k_agg1<<<(N_NODES + 3) / 4, 256, 0, stream>>>(h1, as1, ad1, start, esrc, b1,
                                                W2, as2w, ad2w, maxenc,
                                                h2, as2, ad2);
  k_maxas2<<<64, 256, 0, stream>>>(as2, maxenc + 8);
  k_agg2<<<(N_NODES + 3) / 4, 256, 0, stream>>>(h2, as2, ad2, start, esrc, b2,
                                                maxenc + 8, out);
}

// Round 9
// 245.187 us; speedup vs baseline: 2.5212x; 1.0567x over previous
//
#include <hip/hip_runtime.h>
#include <hip/hip_fp16.h>
#include <math.h>

#define N_NODES 50000
#define N_EDGES 1000000
#define F_IN 128
#define HID 16
#define N_CLS 40
#define HEADS 8
#define ET (N_EDGES + N_NODES)
#define XB ((N_NODES + 63) / 64)      // 782 xform blocks
#define HB ((ET + 255) / 256)         // 4103 hist blocks
#define NSCB ((N_NODES + 255) / 256)  // 196 scan blocks

__device__ __forceinline__ void fma4(float4& acc, float s, const float4& v) {
  acc.x += s * v.x;
  acc.y += s * v.y;
  acc.z += s * v.z;
  acc.w += s * v.w;
}

__device__ __forceinline__ float dot4(float4 a, float4 b) {
  return a.x * b.x + a.y * b.y + a.z * b.z + a.w * b.w;
}

// monotone float<->uint encoding for atomicMax on floats
__device__ __forceinline__ unsigned encf(float f) {
  unsigned b = __float_as_uint(f);
  return (b & 0x80000000u) ? ~b : (b | 0x80000000u);
}
__device__ __forceinline__ float decf(unsigned k) {
  unsigned b = (k & 0x80000000u) ? (k ^ 0x80000000u) : ~k;
  return __uint_as_float(b);
}

// ---------------- conv1 transform (+ fused hist blocks, + fused as1-max) ----

__global__ __launch_bounds__(256) void k_xform1(
    const float* __restrict__ x, const float* __restrict__ W1,
    const float* __restrict__ att_s, const float* __restrict__ att_d,
    const int* __restrict__ ei, int* __restrict__ deg,
    __half* __restrict__ h1, float* __restrict__ as1, float* __restrict__ ad1,
    unsigned* __restrict__ enc1) {
  if (blockIdx.x >= XB) {  // histogram blocks
    int i = (blockIdx.x - XB) * 256 + threadIdx.x;
    if (i < ET) {
      int dd = (i < N_EDGES) ? ei[N_EDGES + i] : (i - N_EDGES);
      atomicAdd(&deg[dd], 1);
    }
    return;
  }
  __shared__ float4 xlds[64 * 32];  // [node][k/4]
  __shared__ float4 wlds[64 * 32];  // [k_local][c/4]
  __shared__ unsigned encl[8];
  int t = threadIdx.x;
  if (t < 8) encl[t] = 0u;
  int tx = t & 15, ty = t >> 4;
  int base = blockIdx.x * 64;
  const float4* x4 = (const float4*)x;
  const float4* W4 = (const float4*)W1;

  for (int i = t; i < 64 * 32; i += 256) {
    int n = i >> 5;
    int gn = base + n;
    float4 v = {0.f, 0.f, 0.f, 0.f};
    if (gn < N_NODES) v = x4[(size_t)gn * 32 + (i & 31)];
    xlds[i] = v;
  }

  float4 accA[4], accB[4];
#pragma unroll
  for (int n = 0; n < 4; n++) {
    accA[n] = {0.f, 0.f, 0.f, 0.f};
    accB[n] = {0.f, 0.f, 0.f, 0.f};
  }
  int n0 = ty * 4;

  for (int half = 0; half < 2; half++) {
    __syncthreads();
    for (int i = t; i < 64 * 32; i += 256)
      wlds[i] = W4[(size_t)(half * 64 + (i >> 5)) * 32 + (i & 31)];
    __syncthreads();
#pragma unroll
    for (int kk = 0; kk < 64; kk += 4) {
      int kq = half * 16 + (kk >> 2);
      float4 xv0 = xlds[(n0 + 0) * 32 + kq];
      float4 xv1 = xlds[(n0 + 1) * 32 + kq];
      float4 xv2 = xlds[(n0 + 2) * 32 + kq];
      float4 xv3 = xlds[(n0 + 3) * 32 + kq];
#pragma unroll
      for (int j = 0; j < 4; j++) {
        float4 wA = wlds[(kk + j) * 32 + tx * 2];
        float4 wB = wlds[(kk + j) * 32 + tx * 2 + 1];
        float s0 = (j == 0) ? xv0.x : (j == 1) ? xv0.y : (j == 2) ? xv0.z : xv0.w;
        float s1 = (j == 0) ? xv1.x : (j == 1) ? xv1.y : (j == 2) ? xv1.z : xv1.w;
        float s2 = (j == 0) ? xv2.x : (j == 1) ? xv2.y : (j == 2) ? xv2.z : xv2.w;
        float s3 = (j == 0) ? xv3.x : (j == 1) ? xv3.y : (j == 2) ? xv3.z : xv3.w;
        fma4(accA[0], s0, wA); fma4(accB[0], s0, wB);
        fma4(accA[1], s1, wA); fma4(accB[1], s1, wB);
        fma4(accA[2], s2, wA); fma4(accB[2], s2, wB);
        fma4(accA[3], s3, wA); fma4(accB[3], s3, wB);
      }
    }
  }

  int c0 = tx * 8;
  float4 asA = *(const float4*)(att_s + c0);
  float4 asB = *(const float4*)(att_s + c0 + 4);
  float4 adA = *(const float4*)(att_d + c0);
  float4 adB = *(const float4*)(att_d + c0 + 4);
  float psmax = -1e30f;
#pragma unroll
  for (int n = 0; n < 4; n++) {
    int gn = base + n0 + n;
    float ps = dot4(accA[n], asA) + dot4(accB[n], asB);
    float pd = dot4(accA[n], adA) + dot4(accB[n], adB);
    ps += __shfl_xor(ps, 1);
    pd += __shfl_xor(pd, 1);
    if (gn < N_NODES) {
      uint4 pk;
      __half2* ph = (__half2*)&pk;
      ph[0] = __floats2half2_rn(accA[n].x, accA[n].y);
      ph[1] = __floats2half2_rn(accA[n].z, accA[n].w);
      ph[2] = __floats2half2_rn(accB[n].x, accB[n].y);
      ph[3] = __floats2half2_rn(accB[n].z, accB[n].w);
      *(uint4*)(h1 + (size_t)gn * 128 + tx * 8) = pk;
      psmax = fmaxf(psmax, ps);
      if ((tx & 1) == 0) {
        as1[gn * 8 + (tx >> 1)] = ps;
        ad1[gn * 8 + (tx >> 1)] = pd;
      }
    }
  }
  if ((tx & 1) == 0) atomicMax(&encl[tx >> 1], encf(psmax));
  __syncthreads();
  if (t < 8) atomicMax(&enc1[t], encl[t]);
}

// ---------------- 3-kernel coalesced exclusive scan of deg -> start ----------

__global__ __launch_bounds__(256) void k_scanA(const int* __restrict__ deg,
                                               int* __restrict__ bsum) {
  int i = blockIdx.x * 256 + threadIdx.x;
  int v = (i < N_NODES) ? deg[i] : 0;
#pragma unroll
  for (int off = 32; off; off >>= 1) v += __shfl_xor(v, off);
  __shared__ int ws[4];
  if ((threadIdx.x & 63) == 0) ws[threadIdx.x >> 6] = v;
  __syncthreads();
  if (threadIdx.x == 0) bsum[blockIdx.x] = ws[0] + ws[1] + ws[2] + ws[3];
}

__global__ __launch_bounds__(256) void k_scanB(const int* __restrict__ bsum,
                                               int* __restrict__ boff,
                                               int* __restrict__ start) {
  __shared__ int s[256];
  int t = threadIdx.x;
  int v0 = (t < NSCB) ? bsum[t] : 0;
  s[t] = v0;
  __syncthreads();
  for (int off = 1; off < 256; off <<= 1) {
    int v = (t >= off) ? s[t - off] : 0;
    __syncthreads();
    s[t] += v;
    __syncthreads();
  }
  boff[t] = s[t] - v0;  // exclusive
  if (t == 0) start[N_NODES] = ET;
}

__global__ __launch_bounds__(256) void k_scanC(const int* __restrict__ deg,
                                               const int* __restrict__ boff,
                                               int* __restrict__ start) {
  __shared__ int s[256];
  int t = threadIdx.x;
  int i = blockIdx.x * 256 + t;
  int v0 = (i < N_NODES) ? deg[i] : 0;
  s[t] = v0;
  __syncthreads();
  for (int off = 1; off < 256; off <<= 1) {
    int v = (t >= off) ? s[t - off] : 0;
    __syncthreads();
    s[t] += v;
    __syncthreads();
  }
  if (i < N_NODES) start[i] = boff[blockIdx.x] + s[t] - v0;
}

__global__ void k_scatter(const int* __restrict__ ei, const int* __restrict__ start,
                          int* __restrict__ cursor, int* __restrict__ esrc) {
  int i = blockIdx.x * blockDim.x + threadIdx.x;
  if (i >= ET) return;
  int s, d;
  if (i < N_EDGES) { s = ei[i]; d = ei[N_EDGES + i]; }
  else { s = i - N_EDGES; d = s; }
  int pos = atomicAdd(&cursor[d], 1);
  esrc[start[d] + pos] = s;
}

// ---------------- conv1 aggregation + fused conv2 transform ----------------
// Round-8 skeleton; serial gather unrolled x8 (8 loads in flight per lane).

__global__ __launch_bounds__(256) void k_agg1(
    const __half* __restrict__ h1, const float* __restrict__ as1,
    const float* __restrict__ ad1, const int* __restrict__ start,
    const int* __restrict__ esrc, const float* __restrict__ b1,
    const float* __restrict__ W2, const float* __restrict__ att_s2,
    const float* __restrict__ att_d2, const unsigned* __restrict__ as1maxEnc,
    __half* __restrict__ h2, float* __restrict__ as2, float* __restrict__ ad2) {
  __shared__ __align__(16) __half2 p_t[4][8][68];  // [wave][head][edge] splat
  __shared__ __align__(16) int s_lds[4][64];       // byte offsets (s<<8)
  int wave = threadIdx.x >> 6, lane = threadIdx.x & 63;
  int d = blockIdx.x * 4 + wave;
  if (d >= N_NODES) return;
  int s0 = start[d];
  int deg = start[d + 1] - s0;

  float4 av0 = *(const float4*)(ad1 + d * 8);
  float4 av1 = *(const float4*)(ad1 + d * 8 + 4);
  float ad[8] = {av0.x, av0.y, av0.z, av0.w, av1.x, av1.y, av1.z, av1.w};
  float c[8], den[8];
#pragma unroll
  for (int h = 0; h < 8; h++) {
    float e = decf(as1maxEnc[h]) + ad[h];
    c[h] = e > 0.f ? e : 0.2f * e;   // upper bound on leaky(as+ad) over segment
    den[h] = 0.f;
  }

  int hsel = lane >> 3;  // head for this lane's channel pair
  float accx = 0.f, accy = 0.f;
  const __half* h1l = h1 + lane * 2;

  for (int be = 0; be < deg; be += 64) {
    int cnt = min(64, deg - be);
    if (lane < cnt) {
      int s = esrc[s0 + be + lane];
      s_lds[wave][lane] = s << 8;  // byte offset into h1 (128 halves = 256B)
      float4 p0 = *(const float4*)(as1 + s * 8);
      float4 p1 = *(const float4*)(as1 + s * 8 + 4);
      float e[8] = {p0.x, p0.y, p0.z, p0.w, p1.x, p1.y, p1.z, p1.w};
#pragma unroll
      for (int h = 0; h < 8; h++) {
        float v = e[h] + ad[h];
        v = v > 0.f ? v : 0.2f * v;
        float pv = __expf(v - c[h]);
        den[h] += pv;
        __half hp = __float2half(pv);
        p_t[wave][h][lane] = __half2{hp, hp};
      }
    }
    asm volatile("s_waitcnt lgkmcnt(0)" ::: "memory");
    __half2 acch0 = __floats2half2_rn(0.f, 0.f);
    __half2 acch1 = __floats2half2_rn(0.f, 0.f);
    __half2 acch2 = __floats2half2_rn(0.f, 0.f);
    __half2 acch3 = __floats2half2_rn(0.f, 0.f);
    int i = 0;
    for (; i + 7 < cnt; i += 8) {
      int4 sA = *(const int4*)&s_lds[wave][i];
      int4 sB = *(const int4*)&s_lds[wave][i + 4];
      uint4 pwA = *(const uint4*)&p_t[wave][hsel][i];
      uint4 pwB = *(const uint4*)&p_t[wave][hsel][i + 4];
      const __half2* ppA = (const __half2*)&pwA;
      const __half2* ppB = (const __half2*)&pwB;
      __half2 hA = *(const __half2*)((const char*)h1l + (unsigned)sA.x);
      __half2 hB = *(const __half2*)((const char*)h1l + (unsigned)sA.y);
      __half2 hC = *(const __half2*)((const char*)h1l + (unsigned)sA.z);
      __half2 hD = *(const __half2*)((const char*)h1l + (unsigned)sA.w);
      __half2 hE = *(const __half2*)((const char*)h1l + (unsigned)sB.x);
      __half2 hF = *(const __half2*)((const char*)h1l + (unsigned)sB.y);
      __half2 hG = *(const __half2*)((const char*)h1l + (unsigned)sB.z);
      __half2 hH = *(const __half2*)((const char*)h1l + (unsigned)sB.w);
      acch0 = __hfma2(hA, ppA[0], acch0);
      acch1 = __hfma2(hB, ppA[1], acch1);
      acch2 = __hfma2(hC, ppA[2], acch2);
      acch3 = __hfma2(hD, ppA[3], acch3);
      acch0 = __hfma2(hE, ppB[0], acch0);
      acch1 = __hfma2(hF, ppB[1], acch1);
      acch2 = __hfma2(hG, ppB[2], acch2);
      acch3 = __hfma2(hH, ppB[3], acch3);
    }
    for (; i + 3 < cnt; i += 4) {
      int4 sA = *(const int4*)&s_lds[wave][i];
      uint4 pwA = *(const uint4*)&p_t[wave][hsel][i];
      const __half2* ppA = (const __half2*)&pwA;
      __half2 hA = *(const __half2*)((const char*)h1l + (unsigned)sA.x);
      __half2 hB = *(const __half2*)((const char*)h1l + (unsigned)sA.y);
      __half2 hC = *(const __half2*)((const char*)h1l + (unsigned)sA.z);
      __half2 hD = *(const __half2*)((const char*)h1l + (unsigned)sA.w);
      acch0 = __hfma2(hA, ppA[0], acch0);
      acch1 = __hfma2(hB, ppA[1], acch1);
      acch2 = __hfma2(hC, ppA[2], acch2);
      acch3 = __hfma2(hD, ppA[3], acch3);
    }
    for (; i < cnt; i++) {
      int sb = s_lds[wave][i];
      __half2 pv = p_t[wave][hsel][i];
      __half2 hv = *(const __half2*)((const char*)h1l + (unsigned)sb);
      acch0 = __hfma2(hv, pv, acch0);
    }
    // promote chunk accumulators to fp32
    float2 t0 = __half22float2(acch0);
    float2 t1 = __half22float2(acch1);
    float2 t2 = __half22float2(acch2);
    float2 t3 = __half22float2(acch3);
    accx += (t0.x + t1.x) + (t2.x + t3.x);
    accy += (t0.y + t1.y) + (t2.y + t3.y);
    asm volatile("s_waitcnt lgkmcnt(0)" ::: "memory");
  }

  // reduce den across lanes
#pragma unroll
  for (int h = 0; h < 8; h++) {
#pragma unroll
    for (int off = 32; off; off >>= 1) den[h] += __shfl_xor(den[h], off);
  }
  int hl = hsel & 3;
  float dA = (hl == 0) ? den[0] : (hl == 1) ? den[1] : (hl == 2) ? den[2] : den[3];
  float dB = (hl == 0) ? den[4] : (hl == 1) ? den[5] : (hl == 2) ? den[6] : den[7];
  float invd = 1.f / ((hsel & 4) ? dB : dA);
  float r0 = accx * invd, r1 = accy * invd;
  // sum over 8 heads (lanes sharing lane&7)
#pragma unroll
  for (int off = 8; off < 64; off <<= 1) {
    r0 += __shfl_xor(r0, off);
    r1 += __shfl_xor(r1, off);
  }
  int ch = (lane & 7) * 2;
  r0 = r0 * 0.125f + b1[ch];
  r1 = r1 * 0.125f + b1[ch + 1];
  r0 = r0 > 0.f ? r0 : __expf(r0) - 1.f;
  r1 = r1 > 0.f ? r1 : __expf(r1) - 1.f;

  // fused conv2 transform: h2[d][j] = sum_k r_k W2[k][j]
  float acc2 = 0.f;
#pragma unroll
  for (int k = 0; k < 16; k++) {
    float rs = (k & 1) ? r1 : r0;
    float rk = __shfl(rs, k >> 1);
    if (lane < N_CLS) acc2 += rk * W2[k * N_CLS + lane];
  }
  float sv = 0.f, dv = 0.f;
  if (lane < N_CLS) {
    h2[d * N_CLS + lane] = __float2half(acc2);
    sv = acc2 * att_s2[lane];
    dv = acc2 * att_d2[lane];
  }
#pragma unroll
  for (int off = 32; off; off >>= 1) {
    sv += __shfl_xor(sv, off);
    dv += __shfl_xor(dv, off);
  }
  if (lane == 0) { as2[d] = sv; ad2[d] = dv; }
}

// ---------------- global max of as2 ----------------

__global__ __launch_bounds__(256) void k_maxas2(const float* __restrict__ as2,
                                                unsigned* __restrict__ enc) {
  int t = blockIdx.x * 256 + threadIdx.x;  // 64 blocks -> 16384 threads
  float mx = -1e30f;
  for (int r = t; r < N_NODES; r += 16384) mx = fmaxf(mx, as2[r]);
#pragma unroll
  for (int off = 32; off; off >>= 1) mx = fmaxf(mx, __shfl_xor(mx, off));
  if ((threadIdx.x & 63) == 0) atomicMax(enc, encf(mx));
}

// ---------------- conv2 aggregation + bias + log_softmax ----------------
// 60 lanes = 20 channel-pairs x 3 edge-slots; 2 slot-groups in flight.

__global__ __launch_bounds__(256) void k_agg2(
    const __half* __restrict__ h2, const float* __restrict__ as2,
    const float* __restrict__ ad2, const int* __restrict__ start,
    const int* __restrict__ esrc, const float* __restrict__ b2,
    const unsigned* __restrict__ as2maxEnc, float* __restrict__ out) {
  __shared__ __align__(16) float p_l[4][64];
  __shared__ __align__(16) int s_l[4][64];  // byte offsets (s*80)
  int wave = threadIdx.x >> 6, lane = threadIdx.x & 63;
  int d = blockIdx.x * 4 + wave;
  if (d >= N_NODES) return;
  int s0 = start[d];
  int deg = start[d + 1] - s0;
  float adv = ad2[d];
  float cm = decf(as2maxEnc[0]) + adv;
  cm = cm > 0.f ? cm : 0.2f * cm;

  int cp = lane % 20;        // channel pair (ch 2cp, 2cp+1)
  int es = lane / 20;        // edge slot 0..2 (lanes >= 60 idle in serial)
  const char* h2b = (const char*)h2 + cp * 4;

  float den = 0.f, acc0 = 0.f, acc1 = 0.f;
  for (int be = 0; be < deg; be += 64) {
    int cnt = min(64, deg - be);
    if (lane < cnt) {
      int s = esrc[s0 + be + lane];
      s_l[wave][lane] = s * 80;  // byte offset into h2 (40 halves)
      float e = as2[s] + adv;
      e = e > 0.f ? e : 0.2f * e;
      float p = __expf(e - cm);
      den += p;
      p_l[wave][lane] = p;
    }
    asm volatile("s_waitcnt lgkmcnt(0)" ::: "memory");
    if (es < 3) {
      int i = 0;
      for (; i + 5 < cnt; i += 6) {
        int eA = i + es, eB = i + 3 + es;
        int sbA = s_l[wave][eA], sbB = s_l[wave][eB];
        float pA = p_l[wave][eA], pB = p_l[wave][eB];
        __half2 hvA = *(const __half2*)(h2b + (unsigned)sbA);
        __half2 hvB = *(const __half2*)(h2b + (unsigned)sbB);
        acc0 = fmaf(__half2float(hvA.x), pA, acc0);
        acc1 = fmaf(__half2float(hvA.y), pA, acc1);
        acc0 = fmaf(__half2float(hvB.x), pB, acc0);
        acc1 = fmaf(__half2float(hvB.y), pB, acc1);
      }
      for (; i < cnt; i += 3) {
        int e = i + es;
        if (e < cnt) {
          int sb = s_l[wave][e];
          float p = p_l[wave][e];
          __half2 hv = *(const __half2*)(h2b + (unsigned)sb);
          acc0 = fmaf(__half2float(hv.x), p, acc0);
          acc1 = fmaf(__half2float(hv.y), p, acc1);
        }
      }
    }
    asm volatile("s_waitcnt lgkmcnt(0)" ::: "memory");
  }
#pragma unroll
  for (int off = 32; off; off >>= 1) den += __shfl_xor(den, off);
  float iv = 1.f / den;

  // combine 3 edge-slots: lanes 0..19 gather from +20, +40
  acc0 += __shfl(acc0, lane + 20) + __shfl(acc0, lane + 40);
  acc1 += __shfl(acc1, lane + 20) + __shfl(acc1, lane + 40);
  // distribute pairs to 40-lane layout: channel j from lane j>>1, comp j&1
  float va = __shfl(acc0, lane >> 1);
  float vb = __shfl(acc1, lane >> 1);
  float v = (lane & 1) ? vb : va;
  v = (lane < N_CLS) ? v * iv + b2[lane] : -1e30f;

  float mx = v;
#pragma unroll
  for (int off = 32; off; off >>= 1) mx = fmaxf(mx, __shfl_xor(mx, off));
  float ex = (lane < N_CLS) ? __expf(v - mx) : 0.f;
  float sm = ex;
#pragma unroll
  for (int off = 32; off; off >>= 1) sm += __shfl_xor(sm, off);
  float lse = logf(sm);
  if (lane < N_CLS) out[d * N_CLS + lane] = (v - mx) - lse;
}

// ---------------- host launcher ----------------

extern "C" void kernel_launch(void* const* d_in, const int* in_sizes, int n_in,
                              void* d_out, int out_size, void* d_ws, size_t ws_size,
                              hipStream_t stream) {
  const float* x    = (const float*)d_in[0];
  const int*   ei   = (const int*)d_in[1];
  const float* W1   = (const float*)d_in[2];
  const float* as1w = (const float*)d_in[3];
  const float* ad1w = (const float*)d_in[4];
  const float* b1   = (const float*)d_in[5];
  const float* W2   = (const float*)d_in[6];
  const float* as2w = (const float*)d_in[7];
  const float* ad2w = (const float*)d_in[8];
  const float* b2   = (const float*)d_in[9];
  float* out = (float*)d_out;

  char* ws = (char*)d_ws;
  size_t off = 0;
  auto alloc = [&](size_t bytes) -> void* {
    void* p = ws + off;
    off += (bytes + 255) & ~(size_t)255;
    return p;
  };
  __half* h1   = (__half*)alloc((size_t)N_NODES * 128 * 2);
  float* as1   = (float*)alloc((size_t)N_NODES * 8 * 4);
  float* ad1   = (float*)alloc((size_t)N_NODES * 8 * 4);
  __half* h2   = (__half*)alloc((size_t)N_NODES * 40 * 2);
  float* as2   = (float*)alloc((size_t)N_NODES * 4);
  float* ad2   = (float*)alloc((size_t)N_NODES * 4);
  // contiguous zero region: deg | cursor | maxenc(16)
  size_t zbytes = (size_t)2 * N_NODES * 4 + 256;
  int* deg     = (int*)alloc(zbytes);
  int* cursor  = deg + N_NODES;
  unsigned* maxenc = (unsigned*)(cursor + N_NODES);  // [0..7]=as1 heads, [8]=as2
  int* start   = (int*)alloc((size_t)(N_NODES + 1) * 4);
  int* esrc    = (int*)alloc((size_t)ET * 4);
  int* bsum    = (int*)alloc((size_t)NSCB * 4);
  int* boff    = (int*)alloc(256 * 4);

  (void)hipMemsetAsync(deg, 0, zbytes, stream);

  k_xform1<<<XB + HB, 256, 0, stream>>>(x, W1, as1w, ad1w, ei, deg,
                                        h1, as1, ad1, maxenc);
  k_scanA<<<NSCB, 256, 0, stream>>>(deg, bsum);
  k_scanB<<<1, 256, 0, stream>>>(bsum, boff, start);
  k_scanC<<<NSCB, 256, 0, stream>>>(deg, boff, start);
  k_scatter<<<HB, 256, 0, stream>>>(ei, start, cursor, esrc);

  k_agg1<<<(N_NODES + 3) / 4, 256, 0, stream>>>(h1, as1, ad1, start, esrc, b1,
                                                W2, as2w, ad2w, maxenc,
                                                h2, as2, ad2);
  k_maxas2<<<64, 256, 0, stream>>>(as2, maxenc + 8);
  k_agg2<<<(N_NODES + 3) / 4, 256, 0, stream>>>(h2, as2, ad2, start, esrc, b2,
                                                maxenc + 8, out);
}

// Round 10
// 218.087 us; speedup vs baseline: 2.8345x; 1.1243x over previous
//
#include <hip/hip_runtime.h>
#include <hip/hip_fp16.h>
#include <math.h>

#define N_NODES 50000
#define N_EDGES 1000000
#define F_IN 128
#define HID 16
#define N_CLS 40
#define HEADS 8
#define ET (N_EDGES + N_NODES)
#define XB ((N_NODES + 63) / 64)      // 782 xform blocks
#define HB ((ET + 255) / 256)         // 4103 hist blocks
#define NSCB ((N_NODES + 255) / 256)  // 196 scan blocks

__device__ __forceinline__ void fma4(float4& acc, float s, const float4& v) {
  acc.x += s * v.x;
  acc.y += s * v.y;
  acc.z += s * v.z;
  acc.w += s * v.w;
}

__device__ __forceinline__ float dot4(float4 a, float4 b) {
  return a.x * b.x + a.y * b.y + a.z * b.z + a.w * b.w;
}

// monotone float<->uint encoding for atomicMax on floats
__device__ __forceinline__ unsigned encf(float f) {
  unsigned b = __float_as_uint(f);
  return (b & 0x80000000u) ? ~b : (b | 0x80000000u);
}
__device__ __forceinline__ float decf(unsigned k) {
  unsigned b = (k & 0x80000000u) ? (k ^ 0x80000000u) : ~k;
  return __uint_as_float(b);
}

// ---------------- conv1 transform (+ fused hist blocks, + fused as1-max) ----

__global__ __launch_bounds__(256) void k_xform1(
    const float* __restrict__ x, const float* __restrict__ W1,
    const float* __restrict__ att_s, const float* __restrict__ att_d,
    const int* __restrict__ ei, int* __restrict__ deg,
    __half* __restrict__ h1, float* __restrict__ as1, float* __restrict__ ad1,
    unsigned* __restrict__ enc1) {
  if (blockIdx.x >= XB) {  // histogram blocks
    int i = (blockIdx.x - XB) * 256 + threadIdx.x;
    if (i < ET) {
      int dd = (i < N_EDGES) ? ei[N_EDGES + i] : (i - N_EDGES);
      atomicAdd(&deg[dd], 1);
    }
    return;
  }
  __shared__ float4 xlds[64 * 32];  // [node][k/4]
  __shared__ float4 wlds[64 * 32];  // [k_local][c/4]
  __shared__ unsigned encl[8];
  int t = threadIdx.x;
  if (t < 8) encl[t] = 0u;
  int tx = t & 15, ty = t >> 4;
  int base = blockIdx.x * 64;
  const float4* x4 = (const float4*)x;
  const float4* W4 = (const float4*)W1;

  for (int i = t; i < 64 * 32; i += 256) {
    int n = i >> 5;
    int gn = base + n;
    float4 v = {0.f, 0.f, 0.f, 0.f};
    if (gn < N_NODES) v = x4[(size_t)gn * 32 + (i & 31)];
    xlds[i] = v;
  }

  float4 accA[4], accB[4];
#pragma unroll
  for (int n = 0; n < 4; n++) {
    accA[n] = {0.f, 0.f, 0.f, 0.f};
    accB[n] = {0.f, 0.f, 0.f, 0.f};
  }
  int n0 = ty * 4;

  for (int half = 0; half < 2; half++) {
    __syncthreads();
    for (int i = t; i < 64 * 32; i += 256)
      wlds[i] = W4[(size_t)(half * 64 + (i >> 5)) * 32 + (i & 31)];
    __syncthreads();
#pragma unroll
    for (int kk = 0; kk < 64; kk += 4) {
      int kq = half * 16 + (kk >> 2);
      float4 xv0 = xlds[(n0 + 0) * 32 + kq];
      float4 xv1 = xlds[(n0 + 1) * 32 + kq];
      float4 xv2 = xlds[(n0 + 2) * 32 + kq];
      float4 xv3 = xlds[(n0 + 3) * 32 + kq];
#pragma unroll
      for (int j = 0; j < 4; j++) {
        float4 wA = wlds[(kk + j) * 32 + tx * 2];
        float4 wB = wlds[(kk + j) * 32 + tx * 2 + 1];
        float s0 = (j == 0) ? xv0.x : (j == 1) ? xv0.y : (j == 2) ? xv0.z : xv0.w;
        float s1 = (j == 0) ? xv1.x : (j == 1) ? xv1.y : (j == 2) ? xv1.z : xv1.w;
        float s2 = (j == 0) ? xv2.x : (j == 1) ? xv2.y : (j == 2) ? xv2.z : xv2.w;
        float s3 = (j == 0) ? xv3.x : (j == 1) ? xv3.y : (j == 2) ? xv3.z : xv3.w;
        fma4(accA[0], s0, wA); fma4(accB[0], s0, wB);
        fma4(accA[1], s1, wA); fma4(accB[1], s1, wB);
        fma4(accA[2], s2, wA); fma4(accB[2], s2, wB);
        fma4(accA[3], s3, wA); fma4(accB[3], s3, wB);
      }
    }
  }

  int c0 = tx * 8;
  float4 asA = *(const float4*)(att_s + c0);
  float4 asB = *(const float4*)(att_s + c0 + 4);
  float4 adA = *(const float4*)(att_d + c0);
  float4 adB = *(const float4*)(att_d + c0 + 4);
  float psmax = -1e30f;
#pragma unroll
  for (int n = 0; n < 4; n++) {
    int gn = base + n0 + n;
    float ps = dot4(accA[n], asA) + dot4(accB[n], asB);
    float pd = dot4(accA[n], adA) + dot4(accB[n], adB);
    ps += __shfl_xor(ps, 1);
    pd += __shfl_xor(pd, 1);
    if (gn < N_NODES) {
      uint4 pk;
      __half2* ph = (__half2*)&pk;
      ph[0] = __floats2half2_rn(accA[n].x, accA[n].y);
      ph[1] = __floats2half2_rn(accA[n].z, accA[n].w);
      ph[2] = __floats2half2_rn(accB[n].x, accB[n].y);
      ph[3] = __floats2half2_rn(accB[n].z, accB[n].w);
      *(uint4*)(h1 + (size_t)gn * 128 + tx * 8) = pk;
      psmax = fmaxf(psmax, ps);
      if ((tx & 1) == 0) {
        as1[gn * 8 + (tx >> 1)] = ps;
        ad1[gn * 8 + (tx >> 1)] = pd;
      }
    }
  }
  if ((tx & 1) == 0) atomicMax(&encl[tx >> 1], encf(psmax));
  __syncthreads();
  if (t < 8) atomicMax(&enc1[t], encl[t]);
}

// ---------------- 3-kernel coalesced exclusive scan of deg -> start ----------

__global__ __launch_bounds__(256) void k_scanA(const int* __restrict__ deg,
                                               int* __restrict__ bsum) {
  int i = blockIdx.x * 256 + threadIdx.x;
  int v = (i < N_NODES) ? deg[i] : 0;
#pragma unroll
  for (int off = 32; off; off >>= 1) v += __shfl_xor(v, off);
  __shared__ int ws[4];
  if ((threadIdx.x & 63) == 0) ws[threadIdx.x >> 6] = v;
  __syncthreads();
  if (threadIdx.x == 0) bsum[blockIdx.x] = ws[0] + ws[1] + ws[2] + ws[3];
}

__global__ __launch_bounds__(256) void k_scanB(const int* __restrict__ bsum,
                                               int* __restrict__ boff,
                                               int* __restrict__ start,
                                               const unsigned* __restrict__ enc1,
                                               float* __restrict__ fmax1) {
  __shared__ int s[256];
  int t = threadIdx.x;
  int v0 = (t < NSCB) ? bsum[t] : 0;
  s[t] = v0;
  __syncthreads();
  for (int off = 1; off < 256; off <<= 1) {
    int v = (t >= off) ? s[t - off] : 0;
    __syncthreads();
    s[t] += v;
    __syncthreads();
  }
  boff[t] = s[t] - v0;  // exclusive
  if (t == 0) start[N_NODES] = ET;
  if (t < 8) fmax1[t] = decf(enc1[t]);  // pre-decode as1 per-head max
}

__global__ __launch_bounds__(256) void k_scanC(const int* __restrict__ deg,
                                               const int* __restrict__ boff,
                                               int* __restrict__ start) {
  __shared__ int s[256];
  int t = threadIdx.x;
  int i = blockIdx.x * 256 + t;
  int v0 = (i < N_NODES) ? deg[i] : 0;
  s[t] = v0;
  __syncthreads();
  for (int off = 1; off < 256; off <<= 1) {
    int v = (t >= off) ? s[t - off] : 0;
    __syncthreads();
    s[t] += v;
    __syncthreads();
  }
  if (i < N_NODES) start[i] = boff[blockIdx.x] + s[t] - v0;
}

__global__ void k_scatter(const int* __restrict__ ei, const int* __restrict__ start,
                          int* __restrict__ cursor, int* __restrict__ esrc) {
  int i = blockIdx.x * blockDim.x + threadIdx.x;
  if (i >= ET) return;
  int s, d;
  if (i < N_EDGES) { s = ei[i]; d = ei[N_EDGES + i]; }
  else { s = i - N_EDGES; d = s; }
  int pos = atomicAdd(&cursor[d], 1);
  esrc[start[d] + pos] = s;
}

// ---------------- conv1 aggregation + fused conv2 transform ----------------
// 16-lane groups: wave = 4 dst; lane = 8 channels (16B dwordx4 gathers).
// One gather instr covers 4 edges -> 4x less address processing per byte.
// den accumulates fully per-lane (no cross-lane den reduce).

__global__ __launch_bounds__(256) void k_agg1(
    const __half* __restrict__ h1, const float* __restrict__ as1,
    const float* __restrict__ ad1, const int* __restrict__ start,
    const int* __restrict__ esrc, const float* __restrict__ b1,
    const float* __restrict__ W2, const float* __restrict__ att_s2,
    const float* __restrict__ att_d2, const float* __restrict__ fmax1,
    __half* __restrict__ h2, float* __restrict__ as2, float* __restrict__ ad2) {
  __shared__ __align__(16) __half2 p_t[4][4][8][20];  // [wave][g][head][16e+pad]
  __shared__ __align__(16) int s_off[4][4][20];       // [wave][g][16e+pad]
  __shared__ float w2s[16 * 40];
  int t = threadIdx.x;
  for (int i = t; i < 640; i += 256) w2s[i] = W2[i];
  __syncthreads();

  int wave = t >> 6, lane = t & 63;
  int g = lane >> 4, li = lane & 15;
  int d = blockIdx.x * 16 + wave * 4 + g;  // 3125*16 = 50000 exact
  int s0 = start[d];
  int deg = start[d + 1] - s0;

  int dm = deg;
  dm = max(dm, __shfl_xor(dm, 16));
  dm = max(dm, __shfl_xor(dm, 32));

  float4 av0 = *(const float4*)(ad1 + d * 8);
  float4 av1 = *(const float4*)(ad1 + d * 8 + 4);
  float ad_[8] = {av0.x, av0.y, av0.z, av0.w, av1.x, av1.y, av1.z, av1.w};
  float c_[8];
#pragma unroll
  for (int h = 0; h < 8; h++) {
    float e = fmax1[h] + ad_[h];
    c_[h] = e > 0.f ? e : 0.2f * e;
  }

  float den = 0.f;
  float accf[8];
#pragma unroll
  for (int k = 0; k < 8; k++) accf[k] = 0.f;

  int hsel = li >> 1;
  const char* h1l = (const char*)(h1 + li * 8);  // lane's 16B channel chunk

  for (int be = 0; be < dm; be += 16) {
    int cnt = deg - be;  // may be <= 0
    bool act = li < cnt;
    int s = 0;
    if (act) s = esrc[s0 + be + li];
    s_off[wave][g][li] = act ? (s << 8) : 0;
    float4 p0 = {0.f, 0.f, 0.f, 0.f}, p1 = {0.f, 0.f, 0.f, 0.f};
    if (act) {
      p0 = *(const float4*)(as1 + (size_t)s * 8);
      p1 = *(const float4*)(as1 + (size_t)s * 8 + 4);
    }
    float ev[8] = {p0.x, p0.y, p0.z, p0.w, p1.x, p1.y, p1.z, p1.w};
#pragma unroll
    for (int h = 0; h < 8; h++) {
      float v = ev[h] + ad_[h];
      v = v > 0.f ? v : 0.2f * v;
      float pv = act ? __expf(v - c_[h]) : 0.f;
      __half hp = __float2half(pv);
      p_t[wave][g][h][li] = __half2{hp, hp};
    }
    asm volatile("s_waitcnt lgkmcnt(0)" ::: "memory");

    int cm = min(dm - be, 16);
    const __half2* pt = &p_t[wave][g][hsel][0];
    const int* so = &s_off[wave][g][0];
    __half2 a0 = __floats2half2_rn(0.f, 0.f);
    __half2 a1 = __floats2half2_rn(0.f, 0.f);
    __half2 a2 = __floats2half2_rn(0.f, 0.f);
    __half2 a3 = __floats2half2_rn(0.f, 0.f);
    for (int e = 0; e < cm; e += 4) {
      int4 s4 = *(const int4*)&so[e];
      uint4 pw = *(const uint4*)&pt[e];
      const __half2* pp = (const __half2*)&pw;
      uint4 hA = *(const uint4*)(h1l + (unsigned)s4.x);
      uint4 hB = *(const uint4*)(h1l + (unsigned)s4.y);
      uint4 hC = *(const uint4*)(h1l + (unsigned)s4.z);
      uint4 hD = *(const uint4*)(h1l + (unsigned)s4.w);
      const __half2* vA = (const __half2*)&hA;
      const __half2* vB = (const __half2*)&hB;
      const __half2* vC = (const __half2*)&hC;
      const __half2* vD = (const __half2*)&hD;
      a0 = __hfma2(vA[0], pp[0], a0); a1 = __hfma2(vA[1], pp[0], a1);
      a2 = __hfma2(vA[2], pp[0], a2); a3 = __hfma2(vA[3], pp[0], a3);
      a0 = __hfma2(vB[0], pp[1], a0); a1 = __hfma2(vB[1], pp[1], a1);
      a2 = __hfma2(vB[2], pp[1], a2); a3 = __hfma2(vB[3], pp[1], a3);
      a0 = __hfma2(vC[0], pp[2], a0); a1 = __hfma2(vC[1], pp[2], a1);
      a2 = __hfma2(vC[2], pp[2], a2); a3 = __hfma2(vC[3], pp[2], a3);
      a0 = __hfma2(vD[0], pp[3], a0); a1 = __hfma2(vD[1], pp[3], a1);
      a2 = __hfma2(vD[2], pp[3], a2); a3 = __hfma2(vD[3], pp[3], a3);
      den += __low2float(pp[0]) + __low2float(pp[1]) +
             __low2float(pp[2]) + __low2float(pp[3]);
    }
    // promote chunk accumulators to fp32
    float2 f0 = __half22float2(a0), f1 = __half22float2(a1);
    float2 f2 = __half22float2(a2), f3 = __half22float2(a3);
    accf[0] += f0.x; accf[1] += f0.y; accf[2] += f1.x; accf[3] += f1.y;
    accf[4] += f2.x; accf[5] += f2.y; accf[6] += f3.x; accf[7] += f3.y;
    asm volatile("s_waitcnt lgkmcnt(0)" ::: "memory");
  }

  // normalize by own head's den, fold in 1/8 head-mean
  float sc = 0.125f / den;
#pragma unroll
  for (int k = 0; k < 8; k++) accf[k] *= sc;
  // sum over heads: xor 2,4,8 within the 16-lane group
#pragma unroll
  for (int off = 2; off <= 8; off <<= 1) {
#pragma unroll
    for (int k = 0; k < 8; k++) accf[k] += __shfl_xor(accf[k], off);
  }
  // lane holds mean for ch (li&1)*8 + k
  int jb = (li & 1) * 8;
  float4 b1a = *(const float4*)(b1 + jb);
  float4 b1b = *(const float4*)(b1 + jb + 4);
  float bv[8] = {b1a.x, b1a.y, b1a.z, b1a.w, b1b.x, b1b.y, b1b.z, b1b.w};
  float r[8];
#pragma unroll
  for (int k = 0; k < 8; k++) {
    float v = accf[k] + bv[k];
    r[k] = v > 0.f ? v : __expf(v) - 1.f;
  }
  float ro[8];
#pragma unroll
  for (int k = 0; k < 8; k++) ro[k] = __shfl_xor(r[k], 1);

  // conv2 transform: outputs j = li, li+16, li+32(li<8)
  float o0 = 0.f, o1 = 0.f, o2 = 0.f;
  bool has2 = li < 8;
#pragma unroll
  for (int k = 0; k < 16; k++) {
    float rk;
    if (k < 8) rk = (li & 1) ? ro[k] : r[k];
    else       rk = (li & 1) ? r[k - 8] : ro[k - 8];
    o0 = fmaf(rk, w2s[k * 40 + li], o0);
    o1 = fmaf(rk, w2s[k * 40 + li + 16], o1);
    if (has2) o2 = fmaf(rk, w2s[k * 40 + li + 32], o2);
  }
  __half* h2r = h2 + d * 40;
  h2r[li] = __float2half(o0);
  h2r[li + 16] = __float2half(o1);
  if (has2) h2r[li + 32] = __float2half(o2);

  float sv = o0 * att_s2[li] + o1 * att_s2[li + 16];
  float dv = o0 * att_d2[li] + o1 * att_d2[li + 16];
  if (has2) {
    sv = fmaf(o2, att_s2[li + 32], sv);
    dv = fmaf(o2, att_d2[li + 32], dv);
  }
#pragma unroll
  for (int off = 1; off <= 8; off <<= 1) {
    sv += __shfl_xor(sv, off);
    dv += __shfl_xor(dv, off);
  }
  if (li == 0) { as2[d] = sv; ad2[d] = dv; }
}

// ---------------- global max of as2 ----------------

__global__ __launch_bounds__(256) void k_maxas2(const float* __restrict__ as2,
                                                unsigned* __restrict__ enc) {
  int t = blockIdx.x * 256 + threadIdx.x;  // 64 blocks -> 16384 threads
  float mx = -1e30f;
  for (int r = t; r < N_NODES; r += 16384) mx = fmaxf(mx, as2[r]);
#pragma unroll
  for (int off = 32; off; off >>= 1) mx = fmaxf(mx, __shfl_xor(mx, off));
  if ((threadIdx.x & 63) == 0) atomicMax(enc, encf(mx));
}

// ---------------- conv2 aggregation + bias + log_softmax ----------------
// 60 lanes = 20 channel-pairs x 3 edge-slots; 2 slot-groups in flight.

__global__ __launch_bounds__(256) void k_agg2(
    const __half* __restrict__ h2, const float* __restrict__ as2,
    const float* __restrict__ ad2, const int* __restrict__ start,
    const int* __restrict__ esrc, const float* __restrict__ b2,
    const unsigned* __restrict__ as2maxEnc, float* __restrict__ out) {
  __shared__ __align__(16) float p_l[4][64];
  __shared__ __align__(16) int s_l[4][64];  // byte offsets (s*80)
  int wave = threadIdx.x >> 6, lane = threadIdx.x & 63;
  int d = blockIdx.x * 4 + wave;
  if (d >= N_NODES) return;
  int s0 = start[d];
  int deg = start[d + 1] - s0;
  float adv = ad2[d];
  float cm = decf(as2maxEnc[0]) + adv;
  cm = cm > 0.f ? cm : 0.2f * cm;

  int cp = lane % 20;        // channel pair (ch 2cp, 2cp+1)
  int es = lane / 20;        // edge slot 0..2 (lanes >= 60 idle in serial)
  const char* h2b = (const char*)h2 + cp * 4;

  float den = 0.f, acc0 = 0.f, acc1 = 0.f;
  for (int be = 0; be < deg; be += 64) {
    int cnt = min(64, deg - be);
    if (lane < cnt) {
      int s = esrc[s0 + be + lane];
      s_l[wave][lane] = s * 80;  // byte offset into h2 (40 halves)
      float e = as2[s] + adv;
      e = e > 0.f ? e : 0.2f * e;
      float p = __expf(e - cm);
      den += p;
      p_l[wave][lane] = p;
    }
    asm volatile("s_waitcnt lgkmcnt(0)" ::: "memory");
    if (es < 3) {
      int i = 0;
      for (; i + 5 < cnt; i += 6) {
        int eA = i + es, eB = i + 3 + es;
        int sbA = s_l[wave][eA], sbB = s_l[wave][eB];
        float pA = p_l[wave][eA], pB = p_l[wave][eB];
        __half2 hvA = *(const __half2*)(h2b + (unsigned)sbA);
        __half2 hvB = *(const __half2*)(h2b + (unsigned)sbB);
        acc0 = fmaf(__half2float(hvA.x), pA, acc0);
        acc1 = fmaf(__half2float(hvA.y), pA, acc1);
        acc0 = fmaf(__half2float(hvB.x), pB, acc0);
        acc1 = fmaf(__half2float(hvB.y), pB, acc1);
      }
      for (; i < cnt; i += 3) {
        int e = i + es;
        if (e < cnt) {
          int sb = s_l[wave][e];
          float p = p_l[wave][e];
          __half2 hv = *(const __half2*)(h2b + (unsigned)sb);
          acc0 = fmaf(__half2float(hv.x), p, acc0);
          acc1 = fmaf(__half2float(hv.y), p, acc1);
        }
      }
    }
    asm volatile("s_waitcnt lgkmcnt(0)" ::: "memory");
  }
#pragma unroll
  for (int off = 32; off; off >>= 1) den += __shfl_xor(den, off);
  float iv = 1.f / den;

  // combine 3 edge-slots: lanes 0..19 gather from +20, +40
  acc0 += __shfl(acc0, lane + 20) + __shfl(acc0, lane + 40);
  acc1 += __shfl(acc1, lane + 20) + __shfl(acc1, lane + 40);
  // distribute pairs to 40-lane layout: channel j from lane j>>1, comp j&1
  float va = __shfl(acc0, lane >> 1);
  float vb = __shfl(acc1, lane >> 1);
  float v = (lane & 1) ? vb : va;
  v = (lane < N_CLS) ? v * iv + b2[lane] : -1e30f;

  float mx = v;
#pragma unroll
  for (int off = 32; off; off >>= 1) mx = fmaxf(mx, __shfl_xor(mx, off));
  float ex = (lane < N_CLS) ? __expf(v - mx) : 0.f;
  float sm = ex;
#pragma unroll
  for (int off = 32; off; off >>= 1) sm += __shfl_xor(sm, off);
  float lse = logf(sm);
  if (lane < N_CLS) out[d * N_CLS + lane] = (v - mx) - lse;
}

// ---------------- host launcher ----------------

extern "C" void kernel_launch(void* const* d_in, const int* in_sizes, int n_in,
                              void* d_out, int out_size, void* d_ws, size_t ws_size,
                              hipStream_t stream) {
  const float* x    = (const float*)d_in[0];
  const int*   ei   = (const int*)d_in[1];
  const float* W1   = (const float*)d_in[2];
  const float* as1w = (const float*)d_in[3];
  const float* ad1w = (const float*)d_in[4];
  const float* b1   = (const float*)d_in[5];
  const float* W2   = (const float*)d_in[6];
  const float* as2w = (const float*)d_in[7];
  const float* ad2w = (const float*)d_in[8];
  const float* b2   = (const float*)d_in[9];
  float* out = (float*)d_out;

  char* ws = (char*)d_ws;
  size_t off = 0;
  auto alloc = [&](size_t bytes) -> void* {
    void* p = ws + off;
    off += (bytes + 255) & ~(size_t)255;
    return p;
  };
  __half* h1   = (__half*)alloc((size_t)N_NODES * 128 * 2);
  float* as1   = (float*)alloc((size_t)N_NODES * 8 * 4);
  float* ad1   = (float*)alloc((size_t)N_NODES * 8 * 4);
  __half* h2   = (__half*)alloc((size_t)N_NODES * 40 * 2);
  float* as2   = (float*)alloc((size_t)N_NODES * 4);
  float* ad2   = (float*)alloc((size_t)N_NODES * 4);
  // contiguous zero region: deg | cursor | maxenc(16)
  size_t zbytes = (size_t)2 * N_NODES * 4 + 256;
  int* deg     = (int*)alloc(zbytes);
  int* cursor  = deg + N_NODES;
  unsigned* maxenc = (unsigned*)(cursor + N_NODES);  // [0..7]=as1 heads, [8]=as2
  int* start   = (int*)alloc((size_t)(N_NODES + 1) * 4);
  int* esrc    = (int*)alloc((size_t)ET * 4);
  int* bsum    = (int*)alloc((size_t)NSCB * 4);
  int* boff    = (int*)alloc(256 * 4);
  float* fmax1 = (float*)alloc(32);

  (void)hipMemsetAsync(deg, 0, zbytes, stream);

  k_xform1<<<XB + HB, 256, 0, stream>>>(x, W1, as1w, ad1w, ei, deg,
                                        h1, as1, ad1, maxenc);
  k_scanA<<<NSCB, 256, 0, stream>>>(deg, bsum);
  k_scanB<<<1, 256, 0, stream>>>(bsum, boff, start, maxenc, fmax1);
  k_scanC<<<NSCB, 256, 0, stream>>>(deg, boff, start);
  k_scatter<<<HB, 256, 0, stream>>>(ei, start, cursor, esrc);

  k_agg1<<<N_NODES / 16, 256, 0, stream>>>(h1, as1, ad1, start, esrc, b1,
                                           W2, as2w, ad2w, fmax1,
                                           h2, as2, ad2);
  k_maxas2<<<64, 256, 0, stream>>>(as2, maxenc + 8);
  k_agg2<<<(N_NODES + 3) / 4, 256, 0, stream>>>(h2, as2, ad2, start, esrc, b2,
                                                maxenc + 8, out);
}

// Round 11
// 214.784 us; speedup vs baseline: 2.8781x; 1.0154x over previous
//
#include <hip/hip_runtime.h>
#include <hip/hip_fp16.h>
#include <math.h>

#define N_NODES 50000
#define N_EDGES 1000000
#define F_IN 128
#define HID 16
#define N_CLS 40
#define HEADS 8
#define ET (N_EDGES + N_NODES)
#define XB ((N_NODES + 63) / 64)      // 782 xform blocks
#define HB ((ET + 255) / 256)         // 4103 hist blocks
#define NSCB ((N_NODES + 255) / 256)  // 196 scan blocks

__device__ __forceinline__ void fma4(float4& acc, float s, const float4& v) {
  acc.x += s * v.x;
  acc.y += s * v.y;
  acc.z += s * v.z;
  acc.w += s * v.w;
}

__device__ __forceinline__ float dot4(float4 a, float4 b) {
  return a.x * b.x + a.y * b.y + a.z * b.z + a.w * b.w;
}

// monotone float<->uint encoding for atomicMax on floats
__device__ __forceinline__ unsigned encf(float f) {
  unsigned b = __float_as_uint(f);
  return (b & 0x80000000u) ? ~b : (b | 0x80000000u);
}
__device__ __forceinline__ float decf(unsigned k) {
  unsigned b = (k & 0x80000000u) ? (k ^ 0x80000000u) : ~k;
  return __uint_as_float(b);
}

// ---------------- conv1 transform (+ fused hist blocks, + fused as1-max) ----
// Bank-conflict-free tiles: rows padded to 33 float4; thread (tx,ty) owns
// channels [4tx..4tx+3] and [64+4tx..64+4tx+3] -> w-reads at 16B lane stride.

__global__ __launch_bounds__(256) void k_xform1(
    const float* __restrict__ x, const float* __restrict__ W1,
    const float* __restrict__ att_s, const float* __restrict__ att_d,
    const int* __restrict__ ei, int* __restrict__ deg,
    __half* __restrict__ h1, float* __restrict__ as1, float* __restrict__ ad1,
    unsigned* __restrict__ enc1) {
  if (blockIdx.x >= XB) {  // histogram blocks
    int i = (blockIdx.x - XB) * 256 + threadIdx.x;
    if (i < ET) {
      int dd = (i < N_EDGES) ? ei[N_EDGES + i] : (i - N_EDGES);
      atomicAdd(&deg[dd], 1);
    }
    return;
  }
  __shared__ float4 xlds[64 * 33];  // [node][k/4], padded
  __shared__ float4 wlds[64 * 33];  // [k_local][c/4], padded
  __shared__ unsigned encl[8];
  int t = threadIdx.x;
  if (t < 8) encl[t] = 0u;
  int tx = t & 15, ty = t >> 4;
  int base = blockIdx.x * 64;
  const float4* x4 = (const float4*)x;
  const float4* W4 = (const float4*)W1;

  for (int i = t; i < 64 * 32; i += 256) {
    int n = i >> 5;
    int gn = base + n;
    float4 v = {0.f, 0.f, 0.f, 0.f};
    if (gn < N_NODES) v = x4[(size_t)gn * 32 + (i & 31)];
    xlds[n * 33 + (i & 31)] = v;
  }

  float4 accA[4], accB[4];
#pragma unroll
  for (int n = 0; n < 4; n++) {
    accA[n] = {0.f, 0.f, 0.f, 0.f};
    accB[n] = {0.f, 0.f, 0.f, 0.f};
  }
  int n0 = ty * 4;

  for (int half = 0; half < 2; half++) {
    __syncthreads();
    for (int i = t; i < 64 * 32; i += 256)
      wlds[(i >> 5) * 33 + (i & 31)] =
          W4[(size_t)(half * 64 + (i >> 5)) * 32 + (i & 31)];
    __syncthreads();
#pragma unroll
    for (int kk = 0; kk < 64; kk += 4) {
      int kq = half * 16 + (kk >> 2);
      float4 xv0 = xlds[(n0 + 0) * 33 + kq];
      float4 xv1 = xlds[(n0 + 1) * 33 + kq];
      float4 xv2 = xlds[(n0 + 2) * 33 + kq];
      float4 xv3 = xlds[(n0 + 3) * 33 + kq];
#pragma unroll
      for (int j = 0; j < 4; j++) {
        float4 wA = wlds[(kk + j) * 33 + tx];
        float4 wB = wlds[(kk + j) * 33 + tx + 16];
        float s0 = (j == 0) ? xv0.x : (j == 1) ? xv0.y : (j == 2) ? xv0.z : xv0.w;
        float s1 = (j == 0) ? xv1.x : (j == 1) ? xv1.y : (j == 2) ? xv1.z : xv1.w;
        float s2 = (j == 0) ? xv2.x : (j == 1) ? xv2.y : (j == 2) ? xv2.z : xv2.w;
        float s3 = (j == 0) ? xv3.x : (j == 1) ? xv3.y : (j == 2) ? xv3.z : xv3.w;
        fma4(accA[0], s0, wA); fma4(accB[0], s0, wB);
        fma4(accA[1], s1, wA); fma4(accB[1], s1, wB);
        fma4(accA[2], s2, wA); fma4(accB[2], s2, wB);
        fma4(accA[3], s3, wA); fma4(accB[3], s3, wB);
      }
    }
  }

  // epilogue: channels 4tx..4tx+3 (head tx>>2) and 64+4tx.. (head 4+(tx>>2))
  int c4 = tx * 4;
  float4 asA = *(const float4*)(att_s + c4);
  float4 asB = *(const float4*)(att_s + 64 + c4);
  float4 adA = *(const float4*)(att_d + c4);
  float4 adB = *(const float4*)(att_d + 64 + c4);
  float mxA = -1e30f, mxB = -1e30f;
#pragma unroll
  for (int n = 0; n < 4; n++) {
    int gn = base + n0 + n;
    float psA = dot4(accA[n], asA);
    float psB = dot4(accB[n], asB);
    float pdA = dot4(accA[n], adA);
    float pdB = dot4(accB[n], adB);
    psA += __shfl_xor(psA, 1); psA += __shfl_xor(psA, 2);
    psB += __shfl_xor(psB, 1); psB += __shfl_xor(psB, 2);
    pdA += __shfl_xor(pdA, 1); pdA += __shfl_xor(pdA, 2);
    pdB += __shfl_xor(pdB, 1); pdB += __shfl_xor(pdB, 2);
    if (gn < N_NODES) {
      uint2 pkA, pkB;
      __half2* phA = (__half2*)&pkA;
      __half2* phB = (__half2*)&pkB;
      phA[0] = __floats2half2_rn(accA[n].x, accA[n].y);
      phA[1] = __floats2half2_rn(accA[n].z, accA[n].w);
      phB[0] = __floats2half2_rn(accB[n].x, accB[n].y);
      phB[1] = __floats2half2_rn(accB[n].z, accB[n].w);
      *(uint2*)(h1 + (size_t)gn * 128 + c4) = pkA;
      *(uint2*)(h1 + (size_t)gn * 128 + 64 + c4) = pkB;
      mxA = fmaxf(mxA, psA);
      mxB = fmaxf(mxB, psB);
      if ((tx & 3) == 0) {
        as1[gn * 8 + (tx >> 2)] = psA;
        as1[gn * 8 + 4 + (tx >> 2)] = psB;
        ad1[gn * 8 + (tx >> 2)] = pdA;
        ad1[gn * 8 + 4 + (tx >> 2)] = pdB;
      }
    }
  }
  if ((tx & 3) == 0) {
    atomicMax(&encl[tx >> 2], encf(mxA));
    atomicMax(&encl[4 + (tx >> 2)], encf(mxB));
  }
  __syncthreads();
  if (t < 8) atomicMax(&enc1[t], encl[t]);
}

// ---------------- 3-kernel coalesced exclusive scan of deg -> start ----------

__global__ __launch_bounds__(256) void k_scanA(const int* __restrict__ deg,
                                               int* __restrict__ bsum) {
  int i = blockIdx.x * 256 + threadIdx.x;
  int v = (i < N_NODES) ? deg[i] : 0;
#pragma unroll
  for (int off = 32; off; off >>= 1) v += __shfl_xor(v, off);
  __shared__ int ws[4];
  if ((threadIdx.x & 63) == 0) ws[threadIdx.x >> 6] = v;
  __syncthreads();
  if (threadIdx.x == 0) bsum[blockIdx.x] = ws[0] + ws[1] + ws[2] + ws[3];
}

__global__ __launch_bounds__(256) void k_scanB(const int* __restrict__ bsum,
                                               int* __restrict__ boff,
                                               int* __restrict__ start,
                                               const unsigned* __restrict__ enc1,
                                               float* __restrict__ fmax1) {
  __shared__ int s[256];
  int t = threadIdx.x;
  int v0 = (t < NSCB) ? bsum[t] : 0;
  s[t] = v0;
  __syncthreads();
  for (int off = 1; off < 256; off <<= 1) {
    int v = (t >= off) ? s[t - off] : 0;
    __syncthreads();
    s[t] += v;
    __syncthreads();
  }
  boff[t] = s[t] - v0;  // exclusive
  if (t == 0) start[N_NODES] = ET;
  if (t < 8) fmax1[t] = decf(enc1[t]);  // pre-decode as1 per-head max
}

__global__ __launch_bounds__(256) void k_scanC(const int* __restrict__ deg,
                                               const int* __restrict__ boff,
                                               int* __restrict__ start) {
  __shared__ int s[256];
  int t = threadIdx.x;
  int i = blockIdx.x * 256 + t;
  int v0 = (i < N_NODES) ? deg[i] : 0;
  s[t] = v0;
  __syncthreads();
  for (int off = 1; off < 256; off <<= 1) {
    int v = (t >= off) ? s[t - off] : 0;
    __syncthreads();
    s[t] += v;
    __syncthreads();
  }
  if (i < N_NODES) start[i] = boff[blockIdx.x] + s[t] - v0;
}

__global__ void k_scatter(const int* __restrict__ ei, const int* __restrict__ start,
                          int* __restrict__ cursor, int* __restrict__ esrc) {
  int i = blockIdx.x * blockDim.x + threadIdx.x;
  if (i >= ET) return;
  int s, d;
  if (i < N_EDGES) { s = ei[i]; d = ei[N_EDGES + i]; }
  else { s = i - N_EDGES; d = s; }
  int pos = atomicAdd(&cursor[d], 1);
  esrc[start[d] + pos] = s;
}

// ---------------- conv1 aggregation + fused conv2 transform ----------------
// 16-lane groups: wave = 4 dst; lane = 8 channels (16B dwordx4 gathers).

__global__ __launch_bounds__(256) void k_agg1(
    const __half* __restrict__ h1, const float* __restrict__ as1,
    const float* __restrict__ ad1, const int* __restrict__ start,
    const int* __restrict__ esrc, const float* __restrict__ b1,
    const float* __restrict__ W2, const float* __restrict__ att_s2,
    const float* __restrict__ att_d2, const float* __restrict__ fmax1,
    __half* __restrict__ h2, float* __restrict__ as2, float* __restrict__ ad2) {
  __shared__ __align__(16) __half2 p_t[4][4][8][20];  // [wave][g][head][16e+pad]
  __shared__ __align__(16) int s_off[4][4][20];       // [wave][g][16e+pad]
  __shared__ float w2s[16 * 40];
  int t = threadIdx.x;
  for (int i = t; i < 640; i += 256) w2s[i] = W2[i];
  __syncthreads();

  int wave = t >> 6, lane = t & 63;
  int g = lane >> 4, li = lane & 15;
  int d = blockIdx.x * 16 + wave * 4 + g;  // 3125*16 = 50000 exact
  int s0 = start[d];
  int deg = start[d + 1] - s0;

  int dm = deg;
  dm = max(dm, __shfl_xor(dm, 16));
  dm = max(dm, __shfl_xor(dm, 32));

  float4 av0 = *(const float4*)(ad1 + d * 8);
  float4 av1 = *(const float4*)(ad1 + d * 8 + 4);
  float ad_[8] = {av0.x, av0.y, av0.z, av0.w, av1.x, av1.y, av1.z, av1.w};
  float c_[8];
#pragma unroll
  for (int h = 0; h < 8; h++) {
    float e = fmax1[h] + ad_[h];
    c_[h] = e > 0.f ? e : 0.2f * e;
  }

  float den = 0.f;
  float accf[8];
#pragma unroll
  for (int k = 0; k < 8; k++) accf[k] = 0.f;

  int hsel = li >> 1;
  const char* h1l = (const char*)(h1 + li * 8);  // lane's 16B channel chunk

  for (int be = 0; be < dm; be += 16) {
    int cnt = deg - be;  // may be <= 0
    bool act = li < cnt;
    int s = 0;
    if (act) s = esrc[s0 + be + li];
    s_off[wave][g][li] = act ? (s << 8) : 0;
    float4 p0 = {0.f, 0.f, 0.f, 0.f}, p1 = {0.f, 0.f, 0.f, 0.f};
    if (act) {
      p0 = *(const float4*)(as1 + (size_t)s * 8);
      p1 = *(const float4*)(as1 + (size_t)s * 8 + 4);
    }
    float ev[8] = {p0.x, p0.y, p0.z, p0.w, p1.x, p1.y, p1.z, p1.w};
#pragma unroll
    for (int h = 0; h < 8; h++) {
      float v = ev[h] + ad_[h];
      v = v > 0.f ? v : 0.2f * v;
      float pv = act ? __expf(v - c_[h]) : 0.f;
      __half hp = __float2half(pv);
      p_t[wave][g][h][li] = __half2{hp, hp};
    }
    asm volatile("s_waitcnt lgkmcnt(0)" ::: "memory");

    int cm = min(dm - be, 16);
    const __half2* pt = &p_t[wave][g][hsel][0];
    const int* so = &s_off[wave][g][0];
    __half2 a0 = __floats2half2_rn(0.f, 0.f);
    __half2 a1 = __floats2half2_rn(0.f, 0.f);
    __half2 a2 = __floats2half2_rn(0.f, 0.f);
    __half2 a3 = __floats2half2_rn(0.f, 0.f);
    for (int e = 0; e < cm; e += 4) {
      int4 s4 = *(const int4*)&so[e];
      uint4 pw = *(const uint4*)&pt[e];
      const __half2* pp = (const __half2*)&pw;
      uint4 hA = *(const uint4*)(h1l + (unsigned)s4.x);
      uint4 hB = *(const uint4*)(h1l + (unsigned)s4.y);
      uint4 hC = *(const uint4*)(h1l + (unsigned)s4.z);
      uint4 hD = *(const uint4*)(h1l + (unsigned)s4.w);
      const __half2* vA = (const __half2*)&hA;
      const __half2* vB = (const __half2*)&hB;
      const __half2* vC = (const __half2*)&hC;
      const __half2* vD = (const __half2*)&hD;
      a0 = __hfma2(vA[0], pp[0], a0); a1 = __hfma2(vA[1], pp[0], a1);
      a2 = __hfma2(vA[2], pp[0], a2); a3 = __hfma2(vA[3], pp[0], a3);
      a0 = __hfma2(vB[0], pp[1], a0); a1 = __hfma2(vB[1], pp[1], a1);
      a2 = __hfma2(vB[2], pp[1], a2); a3 = __hfma2(vB[3], pp[1], a3);
      a0 = __hfma2(vC[0], pp[2], a0); a1 = __hfma2(vC[1], pp[2], a1);
      a2 = __hfma2(vC[2], pp[2], a2); a3 = __hfma2(vC[3], pp[2], a3);
      a0 = __hfma2(vD[0], pp[3], a0); a1 = __hfma2(vD[1], pp[3], a1);
      a2 = __hfma2(vD[2], pp[3], a2); a3 = __hfma2(vD[3], pp[3], a3);
      den += __low2float(pp[0]) + __low2float(pp[1]) +
             __low2float(pp[2]) + __low2float(pp[3]);
    }
    // promote chunk accumulators to fp32
    float2 f0 = __half22float2(a0), f1 = __half22float2(a1);
    float2 f2 = __half22float2(a2), f3 = __half22float2(a3);
    accf[0] += f0.x; accf[1] += f0.y; accf[2] += f1.x; accf[3] += f1.y;
    accf[4] += f2.x; accf[5] += f2.y; accf[6] += f3.x; accf[7] += f3.y;
    asm volatile("s_waitcnt lgkmcnt(0)" ::: "memory");
  }

  // normalize by own head's den, fold in 1/8 head-mean
  float sc = 0.125f / den;
#pragma unroll
  for (int k = 0; k < 8; k++) accf[k] *= sc;
  // sum over heads: xor 2,4,8 within the 16-lane group
#pragma unroll
  for (int off = 2; off <= 8; off <<= 1) {
#pragma unroll
    for (int k = 0; k < 8; k++) accf[k] += __shfl_xor(accf[k], off);
  }
  // lane holds mean for ch (li&1)*8 + k
  int jb = (li & 1) * 8;
  float4 b1a = *(const float4*)(b1 + jb);
  float4 b1b = *(const float4*)(b1 + jb + 4);
  float bv[8] = {b1a.x, b1a.y, b1a.z, b1a.w, b1b.x, b1b.y, b1b.z, b1b.w};
  float r[8];
#pragma unroll
  for (int k = 0; k < 8; k++) {
    float v = accf[k] + bv[k];
    r[k] = v > 0.f ? v : __expf(v) - 1.f;
  }
  float ro[8];
#pragma unroll
  for (int k = 0; k < 8; k++) ro[k] = __shfl_xor(r[k], 1);

  // conv2 transform: outputs j = li, li+16, li+32(li<8)
  float o0 = 0.f, o1 = 0.f, o2 = 0.f;
  bool has2 = li < 8;
#pragma unroll
  for (int k = 0; k < 16; k++) {
    float rk;
    if (k < 8) rk = (li & 1) ? ro[k] : r[k];
    else       rk = (li & 1) ? r[k - 8] : ro[k - 8];
    o0 = fmaf(rk, w2s[k * 40 + li], o0);
    o1 = fmaf(rk, w2s[k * 40 + li + 16], o1);
    if (has2) o2 = fmaf(rk, w2s[k * 40 + li + 32], o2);
  }
  __half* h2r = h2 + d * 40;
  h2r[li] = __float2half(o0);
  h2r[li + 16] = __float2half(o1);
  if (has2) h2r[li + 32] = __float2half(o2);

  float sv = o0 * att_s2[li] + o1 * att_s2[li + 16];
  float dv = o0 * att_d2[li] + o1 * att_d2[li + 16];
  if (has2) {
    sv = fmaf(o2, att_s2[li + 32], sv);
    dv = fmaf(o2, att_d2[li + 32], dv);
  }
#pragma unroll
  for (int off = 1; off <= 8; off <<= 1) {
    sv += __shfl_xor(sv, off);
    dv += __shfl_xor(dv, off);
  }
  if (li == 0) { as2[d] = sv; ad2[d] = dv; }
}

// ---------------- global max of as2 ----------------

__global__ __launch_bounds__(256) void k_maxas2(const float* __restrict__ as2,
                                                unsigned* __restrict__ enc) {
  int t = blockIdx.x * 256 + threadIdx.x;  // 64 blocks -> 16384 threads
  float mx = -1e30f;
  for (int r = t; r < N_NODES; r += 16384) mx = fmaxf(mx, as2[r]);
#pragma unroll
  for (int off = 32; off; off >>= 1) mx = fmaxf(mx, __shfl_xor(mx, off));
  if ((threadIdx.x & 63) == 0) atomicMax(enc, encf(mx));
}

// ---------------- conv2 aggregation + bias + log_softmax ----------------
// 60 lanes = 20 channel-pairs x 3 edge-slots; 2 slot-groups in flight.

__global__ __launch_bounds__(256) void k_agg2(
    const __half* __restrict__ h2, const float* __restrict__ as2,
    const float* __restrict__ ad2, const int* __restrict__ start,
    const int* __restrict__ esrc, const float* __restrict__ b2,
    const unsigned* __restrict__ as2maxEnc, float* __restrict__ out) {
  __shared__ __align__(16) float p_l[4][64];
  __shared__ __align__(16) int s_l[4][64];  // byte offsets (s*80)
  int wave = threadIdx.x >> 6, lane = threadIdx.x & 63;
  int d = blockIdx.x * 4 + wave;
  if (d >= N_NODES) return;
  int s0 = start[d];
  int deg = start[d + 1] - s0;
  float adv = ad2[d];
  float cm = decf(as2maxEnc[0]) + adv;
  cm = cm > 0.f ? cm : 0.2f * cm;

  int cp = lane % 20;        // channel pair (ch 2cp, 2cp+1)
  int es = lane / 20;        // edge slot 0..2 (lanes >= 60 idle in serial)
  const char* h2b = (const char*)h2 + cp * 4;

  float den = 0.f, acc0 = 0.f, acc1 = 0.f;
  for (int be = 0; be < deg; be += 64) {
    int cnt = min(64, deg - be);
    if (lane < cnt) {
      int s = esrc[s0 + be + lane];
      s_l[wave][lane] = s * 80;  // byte offset into h2 (40 halves)
      float e = as2[s] + adv;
      e = e > 0.f ? e : 0.2f * e;
      float p = __expf(e - cm);
      den += p;
      p_l[wave][lane] = p;
    }
    asm volatile("s_waitcnt lgkmcnt(0)" ::: "memory");
    if (es < 3) {
      int i = 0;
      for (; i + 5 < cnt; i += 6) {
        int eA = i + es, eB = i + 3 + es;
        int sbA = s_l[wave][eA], sbB = s_l[wave][eB];
        float pA = p_l[wave][eA], pB = p_l[wave][eB];
        __half2 hvA = *(const __half2*)(h2b + (unsigned)sbA);
        __half2 hvB = *(const __half2*)(h2b + (unsigned)sbB);
        acc0 = fmaf(__half2float(hvA.x), pA, acc0);
        acc1 = fmaf(__half2float(hvA.y), pA, acc1);
        acc0 = fmaf(__half2float(hvB.x), pB, acc0);
        acc1 = fmaf(__half2float(hvB.y), pB, acc1);
      }
      for (; i < cnt; i += 3) {
        int e = i + es;
        if (e < cnt) {
          int sb = s_l[wave][e];
          float p = p_l[wave][e];
          __half2 hv = *(const __half2*)(h2b + (unsigned)sb);
          acc0 = fmaf(__half2float(hv.x), p, acc0);
          acc1 = fmaf(__half2float(hv.y), p, acc1);
        }
      }
    }
    asm volatile("s_waitcnt lgkmcnt(0)" ::: "memory");
  }
#pragma unroll
  for (int off = 32; off; off >>= 1) den += __shfl_xor(den, off);
  float iv = 1.f / den;

  // combine 3 edge-slots: lanes 0..19 gather from +20, +40
  acc0 += __shfl(acc0, lane + 20) + __shfl(acc0, lane + 40);
  acc1 += __shfl(acc1, lane + 20) + __shfl(acc1, lane + 40);
  // distribute pairs to 40-lane layout: channel j from lane j>>1, comp j&1
  float va = __shfl(acc0, lane >> 1);
  float vb = __shfl(acc1, lane >> 1);
  float v = (lane & 1) ? vb : va;
  v = (lane < N_CLS) ? v * iv + b2[lane] : -1e30f;

  float mx = v;
#pragma unroll
  for (int off = 32; off; off >>= 1) mx = fmaxf(mx, __shfl_xor(mx, off));
  float ex = (lane < N_CLS) ? __expf(v - mx) : 0.f;
  float sm = ex;
#pragma unroll
  for (int off = 32; off; off >>= 1) sm += __shfl_xor(sm, off);
  float lse = logf(sm);
  if (lane < N_CLS) out[d * N_CLS + lane] = (v - mx) - lse;
}

// ---------------- host launcher ----------------

extern "C" void kernel_launch(void* const* d_in, const int* in_sizes, int n_in,
                              void* d_out, int out_size, void* d_ws, size_t ws_size,
                              hipStream_t stream) {
  const float* x    = (const float*)d_in[0];
  const int*   ei   = (const int*)d_in[1];
  const float* W1   = (const float*)d_in[2];
  const float* as1w = (const float*)d_in[3];
  const float* ad1w = (const float*)d_in[4];
  const float* b1   = (const float*)d_in[5];
  const float* W2   = (const float*)d_in[6];
  const float* as2w = (const float*)d_in[7];
  const float* ad2w = (const float*)d_in[8];
  const float* b2   = (const float*)d_in[9];
  float* out = (float*)d_out;

  char* ws = (char*)d_ws;
  size_t off = 0;
  auto alloc = [&](size_t bytes) -> void* {
    void* p = ws + off;
    off += (bytes + 255) & ~(size_t)255;
    return p;
  };
  __half* h1   = (__half*)alloc((size_t)N_NODES * 128 * 2);
  float* as1   = (float*)alloc((size_t)N_NODES * 8 * 4);
  float* ad1   = (float*)alloc((size_t)N_NODES * 8 * 4);
  __half* h2   = (__half*)alloc((size_t)N_NODES * 40 * 2);
  float* as2   = (float*)alloc((size_t)N_NODES * 4);
  float* ad2   = (float*)alloc((size_t)N_NODES * 4);
  // contiguous zero region: deg | cursor | maxenc(16)
  size_t zbytes = (size_t)2 * N_NODES * 4 + 256;
  int* deg     = (int*)alloc(zbytes);
  int* cursor  = deg + N_NODES;
  unsigned* maxenc = (unsigned*)(cursor + N_NODES);  // [0..7]=as1 heads, [8]=as2
  int* start   = (int*)alloc((size_t)(N_NODES + 1) * 4);
  int* esrc    = (int*)alloc((size_t)ET * 4);
  int* bsum    = (int*)alloc((size_t)NSCB * 4);
  int* boff    = (int*)alloc(256 * 4);
  float* fmax1 = (float*)alloc(32);

  (void)hipMemsetAsync(deg, 0, zbytes, stream);

  k_xform1<<<XB + HB, 256, 0, stream>>>(x, W1, as1w, ad1w, ei, deg,
                                        h1, as1, ad1, maxenc);
  k_scanA<<<NSCB, 256, 0, stream>>>(deg, bsum);
  k_scanB<<<1, 256, 0, stream>>>(bsum, boff, start, maxenc, fmax1);
  k_scanC<<<NSCB, 256, 0, stream>>>(deg, boff, start);
  k_scatter<<<HB, 256, 0, stream>>>(ei, start, cursor, esrc);

  k_agg1<<<N_NODES / 16, 256, 0, stream>>>(h1, as1, ad1, start, esrc, b1,
                                           W2, as2w, ad2w, fmax1,
                                           h2, as2, ad2);
  k_maxas2<<<64, 256, 0, stream>>>(as2, maxenc + 8);
  k_agg2<<<(N_NODES + 3) / 4, 256, 0, stream>>>(h2, as2, ad2, start, esrc, b2,
                                                maxenc + 8, out);
}

// Round 12
// 206.028 us; speedup vs baseline: 3.0004x; 1.0425x over previous
//
#include <hip/hip_runtime.h>
#include <hip/hip_fp16.h>
#include <math.h>

#define N_NODES 50000
#define N_EDGES 1000000
#define F_IN 128
#define HID 16
#define N_CLS 40
#define HEADS 8
#define ET (N_EDGES + N_NODES)
#define XB ((N_NODES + 63) / 64)      // 782 xform blocks
#define HB ((ET + 255) / 256)         // 4103 hist blocks
#define NSCB ((N_NODES + 255) / 256)  // 196 scan blocks

__device__ __forceinline__ void fma4(float4& acc, float s, const float4& v) {
  acc.x += s * v.x;
  acc.y += s * v.y;
  acc.z += s * v.z;
  acc.w += s * v.w;
}

__device__ __forceinline__ float dot4(float4 a, float4 b) {
  return a.x * b.x + a.y * b.y + a.z * b.z + a.w * b.w;
}

// monotone float<->uint encoding for atomicMax on floats
__device__ __forceinline__ unsigned encf(float f) {
  unsigned b = __float_as_uint(f);
  return (b & 0x80000000u) ? ~b : (b | 0x80000000u);
}
__device__ __forceinline__ float decf(unsigned k) {
  unsigned b = (k & 0x80000000u) ? (k ^ 0x80000000u) : ~k;
  return __uint_as_float(b);
}

// ---------------- conv1 transform (+ fused hist blocks, + fused as1-max) ----
// k-blocked staging (BK=32): LDS 25.6KB -> 4 blocks/CU (was 66.5KB -> 2).
// Conflict-free padded tiles; thread (tx,ty) owns channels [4tx..4tx+3] and
// [64+4tx..64+4tx+3] for nodes 4ty..4ty+3.

__global__ __launch_bounds__(256, 4) void k_xform1(
    const float* __restrict__ x, const float* __restrict__ W1,
    const float* __restrict__ att_s, const float* __restrict__ att_d,
    const int* __restrict__ ei, int* __restrict__ deg,
    __half* __restrict__ h1, float* __restrict__ as1, float* __restrict__ ad1,
    unsigned* __restrict__ enc1) {
  if (blockIdx.x >= XB) {  // histogram blocks
    int i = (blockIdx.x - XB) * 256 + threadIdx.x;
    if (i < ET) {
      int dd = (i < N_EDGES) ? ei[N_EDGES + i] : (i - N_EDGES);
      atomicAdd(&deg[dd], 1);
    }
    return;
  }
  __shared__ float4 xlds[64 * 9];   // [node][k-quad within phase], padded
  __shared__ float4 wlds[32 * 33];  // [k within phase][c-quad], padded
  __shared__ unsigned encl[8];
  int t = threadIdx.x;
  if (t < 8) encl[t] = 0u;
  int tx = t & 15, ty = t >> 4;
  int base = blockIdx.x * 64;
  const float4* x4 = (const float4*)x;
  const float4* W4 = (const float4*)W1;

  float4 accA[4], accB[4];
#pragma unroll
  for (int n = 0; n < 4; n++) {
    accA[n] = {0.f, 0.f, 0.f, 0.f};
    accB[n] = {0.f, 0.f, 0.f, 0.f};
  }
  int n0 = ty * 4;

  for (int kb = 0; kb < 4; kb++) {
    __syncthreads();  // previous compute done / encl init visible
    // stage x slice: 64 nodes x 8 k-quads
    {
      int i = t;
      int n = i >> 3, q = i & 7;
      int gn = base + n;
      float4 v = {0.f, 0.f, 0.f, 0.f};
      if (gn < N_NODES) v = x4[(size_t)gn * 32 + kb * 8 + q];
      xlds[n * 9 + q] = v;
      i += 256;
      n = i >> 3; q = i & 7;
      gn = base + n;
      float4 v2 = {0.f, 0.f, 0.f, 0.f};
      if (gn < N_NODES) v2 = x4[(size_t)gn * 32 + kb * 8 + q];
      xlds[n * 9 + q] = v2;
    }
    // stage W slice: 32 k-rows x 32 c-quads
#pragma unroll
    for (int u = 0; u < 4; u++) {
      int i = t + u * 256;
      int r = i >> 5, q = i & 31;
      wlds[r * 33 + q] = W4[(size_t)(kb * 32 + r) * 32 + q];
    }
    __syncthreads();
#pragma unroll
    for (int kk = 0; kk < 8; kk++) {
      float4 xv0 = xlds[(n0 + 0) * 9 + kk];
      float4 xv1 = xlds[(n0 + 1) * 9 + kk];
      float4 xv2 = xlds[(n0 + 2) * 9 + kk];
      float4 xv3 = xlds[(n0 + 3) * 9 + kk];
#pragma unroll
      for (int j = 0; j < 4; j++) {
        float4 wA = wlds[(kk * 4 + j) * 33 + tx];
        float4 wB = wlds[(kk * 4 + j) * 33 + tx + 16];
        float s0 = (j == 0) ? xv0.x : (j == 1) ? xv0.y : (j == 2) ? xv0.z : xv0.w;
        float s1 = (j == 0) ? xv1.x : (j == 1) ? xv1.y : (j == 2) ? xv1.z : xv1.w;
        float s2 = (j == 0) ? xv2.x : (j == 1) ? xv2.y : (j == 2) ? xv2.z : xv2.w;
        float s3 = (j == 0) ? xv3.x : (j == 1) ? xv3.y : (j == 2) ? xv3.z : xv3.w;
        fma4(accA[0], s0, wA); fma4(accB[0], s0, wB);
        fma4(accA[1], s1, wA); fma4(accB[1], s1, wB);
        fma4(accA[2], s2, wA); fma4(accB[2], s2, wB);
        fma4(accA[3], s3, wA); fma4(accB[3], s3, wB);
      }
    }
  }

  // epilogue: channels 4tx..4tx+3 (head tx>>2) and 64+4tx.. (head 4+(tx>>2))
  int c4 = tx * 4;
  float4 asA = *(const float4*)(att_s + c4);
  float4 asB = *(const float4*)(att_s + 64 + c4);
  float4 adA = *(const float4*)(att_d + c4);
  float4 adB = *(const float4*)(att_d + 64 + c4);
  float mxA = -1e30f, mxB = -1e30f;
#pragma unroll
  for (int n = 0; n < 4; n++) {
    int gn = base + n0 + n;
    float psA = dot4(accA[n], asA);
    float psB = dot4(accB[n], asB);
    float pdA = dot4(accA[n], adA);
    float pdB = dot4(accB[n], adB);
    psA += __shfl_xor(psA, 1); psA += __shfl_xor(psA, 2);
    psB += __shfl_xor(psB, 1); psB += __shfl_xor(psB, 2);
    pdA += __shfl_xor(pdA, 1); pdA += __shfl_xor(pdA, 2);
    pdB += __shfl_xor(pdB, 1); pdB += __shfl_xor(pdB, 2);
    if (gn < N_NODES) {
      uint2 pkA, pkB;
      __half2* phA = (__half2*)&pkA;
      __half2* phB = (__half2*)&pkB;
      phA[0] = __floats2half2_rn(accA[n].x, accA[n].y);
      phA[1] = __floats2half2_rn(accA[n].z, accA[n].w);
      phB[0] = __floats2half2_rn(accB[n].x, accB[n].y);
      phB[1] = __floats2half2_rn(accB[n].z, accB[n].w);
      *(uint2*)(h1 + (size_t)gn * 128 + c4) = pkA;
      *(uint2*)(h1 + (size_t)gn * 128 + 64 + c4) = pkB;
      mxA = fmaxf(mxA, psA);
      mxB = fmaxf(mxB, psB);
      if ((tx & 3) == 0) {
        as1[gn * 8 + (tx >> 2)] = psA;
        as1[gn * 8 + 4 + (tx >> 2)] = psB;
        ad1[gn * 8 + (tx >> 2)] = pdA;
        ad1[gn * 8 + 4 + (tx >> 2)] = pdB;
      }
    }
  }
  if ((tx & 3) == 0) {
    atomicMax(&encl[tx >> 2], encf(mxA));
    atomicMax(&encl[4 + (tx >> 2)], encf(mxB));
  }
  __syncthreads();
  if (t < 8) atomicMax(&enc1[t], encl[t]);
}

// ---------------- 3-kernel coalesced exclusive scan of deg -> start ----------

__global__ __launch_bounds__(256) void k_scanA(const int* __restrict__ deg,
                                               int* __restrict__ bsum) {
  int i = blockIdx.x * 256 + threadIdx.x;
  int v = (i < N_NODES) ? deg[i] : 0;
#pragma unroll
  for (int off = 32; off; off >>= 1) v += __shfl_xor(v, off);
  __shared__ int ws[4];
  if ((threadIdx.x & 63) == 0) ws[threadIdx.x >> 6] = v;
  __syncthreads();
  if (threadIdx.x == 0) bsum[blockIdx.x] = ws[0] + ws[1] + ws[2] + ws[3];
}

__global__ __launch_bounds__(256) void k_scanB(const int* __restrict__ bsum,
                                               int* __restrict__ boff,
                                               int* __restrict__ start,
                                               const unsigned* __restrict__ enc1,
                                               float* __restrict__ fmax1) {
  __shared__ int s[256];
  int t = threadIdx.x;
  int v0 = (t < NSCB) ? bsum[t] : 0;
  s[t] = v0;
  __syncthreads();
  for (int off = 1; off < 256; off <<= 1) {
    int v = (t >= off) ? s[t - off] : 0;
    __syncthreads();
    s[t] += v;
    __syncthreads();
  }
  boff[t] = s[t] - v0;  // exclusive
  if (t == 0) start[N_NODES] = ET;
  if (t < 8) fmax1[t] = decf(enc1[t]);  // pre-decode as1 per-head max
}

__global__ __launch_bounds__(256) void k_scanC(const int* __restrict__ deg,
                                               const int* __restrict__ boff,
                                               int* __restrict__ start) {
  __shared__ int s[256];
  int t = threadIdx.x;
  int i = blockIdx.x * 256 + t;
  int v0 = (i < N_NODES) ? deg[i] : 0;
  s[t] = v0;
  __syncthreads();
  for (int off = 1; off < 256; off <<= 1) {
    int v = (t >= off) ? s[t - off] : 0;
    __syncthreads();
    s[t] += v;
    __syncthreads();
  }
  if (i < N_NODES) start[i] = boff[blockIdx.x] + s[t] - v0;
}

__global__ void k_scatter(const int* __restrict__ ei, const int* __restrict__ start,
                          int* __restrict__ cursor, int* __restrict__ esrc) {
  int i = blockIdx.x * blockDim.x + threadIdx.x;
  if (i >= ET) return;
  int s, d;
  if (i < N_EDGES) { s = ei[i]; d = ei[N_EDGES + i]; }
  else { s = i - N_EDGES; d = s; }
  int pos = atomicAdd(&cursor[d], 1);
  esrc[start[d] + pos] = s;
}

// ---------------- conv1 aggregation + fused conv2 transform ----------------
// 16-lane groups: wave = 4 dst; lane = 8 channels (16B dwordx4 gathers).

__global__ __launch_bounds__(256) void k_agg1(
    const __half* __restrict__ h1, const float* __restrict__ as1,
    const float* __restrict__ ad1, const int* __restrict__ start,
    const int* __restrict__ esrc, const float* __restrict__ b1,
    const float* __restrict__ W2, const float* __restrict__ att_s2,
    const float* __restrict__ att_d2, const float* __restrict__ fmax1,
    __half* __restrict__ h2, float* __restrict__ as2, float* __restrict__ ad2) {
  __shared__ __align__(16) __half2 p_t[4][4][8][20];  // [wave][g][head][16e+pad]
  __shared__ __align__(16) int s_off[4][4][20];       // [wave][g][16e+pad]
  __shared__ float w2s[16 * 40];
  int t = threadIdx.x;
  for (int i = t; i < 640; i += 256) w2s[i] = W2[i];
  __syncthreads();

  int wave = t >> 6, lane = t & 63;
  int g = lane >> 4, li = lane & 15;
  int d = blockIdx.x * 16 + wave * 4 + g;  // 3125*16 = 50000 exact
  int s0 = start[d];
  int deg = start[d + 1] - s0;

  int dm = deg;
  dm = max(dm, __shfl_xor(dm, 16));
  dm = max(dm, __shfl_xor(dm, 32));

  float4 av0 = *(const float4*)(ad1 + d * 8);
  float4 av1 = *(const float4*)(ad1 + d * 8 + 4);
  float ad_[8] = {av0.x, av0.y, av0.z, av0.w, av1.x, av1.y, av1.z, av1.w};
  float c_[8];
#pragma unroll
  for (int h = 0; h < 8; h++) {
    float e = fmax1[h] + ad_[h];
    c_[h] = e > 0.f ? e : 0.2f * e;
  }

  float den = 0.f;
  float accf[8];
#pragma unroll
  for (int k = 0; k < 8; k++) accf[k] = 0.f;

  int hsel = li >> 1;
  const char* h1l = (const char*)(h1 + li * 8);  // lane's 16B channel chunk

  for (int be = 0; be < dm; be += 16) {
    int cnt = deg - be;  // may be <= 0
    bool act = li < cnt;
    int s = 0;
    if (act) s = esrc[s0 + be + li];
    s_off[wave][g][li] = act ? (s << 8) : 0;
    float4 p0 = {0.f, 0.f, 0.f, 0.f}, p1 = {0.f, 0.f, 0.f, 0.f};
    if (act) {
      p0 = *(const float4*)(as1 + (size_t)s * 8);
      p1 = *(const float4*)(as1 + (size_t)s * 8 + 4);
    }
    float ev[8] = {p0.x, p0.y, p0.z, p0.w, p1.x, p1.y, p1.z, p1.w};
#pragma unroll
    for (int h = 0; h < 8; h++) {
      float v = ev[h] + ad_[h];
      v = v > 0.f ? v : 0.2f * v;
      float pv = act ? __expf(v - c_[h]) : 0.f;
      __half hp = __float2half(pv);
      p_t[wave][g][h][li] = __half2{hp, hp};
    }
    asm volatile("s_waitcnt lgkmcnt(0)" ::: "memory");

    int cm = min(dm - be, 16);
    const __half2* pt = &p_t[wave][g][hsel][0];
    const int* so = &s_off[wave][g][0];
    __half2 a0 = __floats2half2_rn(0.f, 0.f);
    __half2 a1 = __floats2half2_rn(0.f, 0.f);
    __half2 a2 = __floats2half2_rn(0.f, 0.f);
    __half2 a3 = __floats2half2_rn(0.f, 0.f);
    for (int e = 0; e < cm; e += 4) {
      int4 s4 = *(const int4*)&so[e];
      uint4 pw = *(const uint4*)&pt[e];
      const __half2* pp = (const __half2*)&pw;
      uint4 hA = *(const uint4*)(h1l + (unsigned)s4.x);
      uint4 hB = *(const uint4*)(h1l + (unsigned)s4.y);
      uint4 hC = *(const uint4*)(h1l + (unsigned)s4.z);
      uint4 hD = *(const uint4*)(h1l + (unsigned)s4.w);
      const __half2* vA = (const __half2*)&hA;
      const __half2* vB = (const __half2*)&hB;
      const __half2* vC = (const __half2*)&hC;
      const __half2* vD = (const __half2*)&hD;
      a0 = __hfma2(vA[0], pp[0], a0); a1 = __hfma2(vA[1], pp[0], a1);
      a2 = __hfma2(vA[2], pp[0], a2); a3 = __hfma2(vA[3], pp[0], a3);
      a0 = __hfma2(vB[0], pp[1], a0); a1 = __hfma2(vB[1], pp[1], a1);
      a2 = __hfma2(vB[2], pp[1], a2); a3 = __hfma2(vB[3], pp[1], a3);
      a0 = __hfma2(vC[0], pp[2], a0); a1 = __hfma2(vC[1], pp[2], a1);
      a2 = __hfma2(vC[2], pp[2], a2); a3 = __hfma2(vC[3], pp[2], a3);
      a0 = __hfma2(vD[0], pp[3], a0); a1 = __hfma2(vD[1], pp[3], a1);
      a2 = __hfma2(vD[2], pp[3], a2); a3 = __hfma2(vD[3], pp[3], a3);
      den += __low2float(pp[0]) + __low2float(pp[1]) +
             __low2float(pp[2]) + __low2float(pp[3]);
    }
    // promote chunk accumulators to fp32
    float2 f0 = __half22float2(a0), f1 = __half22float2(a1);
    float2 f2 = __half22float2(a2), f3 = __half22float2(a3);
    accf[0] += f0.x; accf[1] += f0.y; accf[2] += f1.x; accf[3] += f1.y;
    accf[4] += f2.x; accf[5] += f2.y; accf[6] += f3.x; accf[7] += f3.y;
    asm volatile("s_waitcnt lgkmcnt(0)" ::: "memory");
  }

  // normalize by own head's den, fold in 1/8 head-mean
  float sc = 0.125f / den;
#pragma unroll
  for (int k = 0; k < 8; k++) accf[k] *= sc;
  // sum over heads: xor 2,4,8 within the 16-lane group
#pragma unroll
  for (int off = 2; off <= 8; off <<= 1) {
#pragma unroll
    for (int k = 0; k < 8; k++) accf[k] += __shfl_xor(accf[k], off);
  }
  // lane holds mean for ch (li&1)*8 + k
  int jb = (li & 1) * 8;
  float4 b1a = *(const float4*)(b1 + jb);
  float4 b1b = *(const float4*)(b1 + jb + 4);
  float bv[8] = {b1a.x, b1a.y, b1a.z, b1a.w, b1b.x, b1b.y, b1b.z, b1b.w};
  float r[8];
#pragma unroll
  for (int k = 0; k < 8; k++) {
    float v = accf[k] + bv[k];
    r[k] = v > 0.f ? v : __expf(v) - 1.f;
  }
  float ro[8];
#pragma unroll
  for (int k = 0; k < 8; k++) ro[k] = __shfl_xor(r[k], 1);

  // conv2 transform: outputs j = li, li+16, li+32(li<8)
  float o0 = 0.f, o1 = 0.f, o2 = 0.f;
  bool has2 = li < 8;
#pragma unroll
  for (int k = 0; k < 16; k++) {
    float rk;
    if (k < 8) rk = (li & 1) ? ro[k] : r[k];
    else       rk = (li & 1) ? r[k - 8] : ro[k - 8];
    o0 = fmaf(rk, w2s[k * 40 + li], o0);
    o1 = fmaf(rk, w2s[k * 40 + li + 16], o1);
    if (has2) o2 = fmaf(rk, w2s[k * 40 + li + 32], o2);
  }
  __half* h2r = h2 + d * 40;
  h2r[li] = __float2half(o0);
  h2r[li + 16] = __float2half(o1);
  if (has2) h2r[li + 32] = __float2half(o2);

  float sv = o0 * att_s2[li] + o1 * att_s2[li + 16];
  float dv = o0 * att_d2[li] + o1 * att_d2[li + 16];
  if (has2) {
    sv = fmaf(o2, att_s2[li + 32], sv);
    dv = fmaf(o2, att_d2[li + 32], dv);
  }
#pragma unroll
  for (int off = 1; off <= 8; off <<= 1) {
    sv += __shfl_xor(sv, off);
    dv += __shfl_xor(dv, off);
  }
  if (li == 0) { as2[d] = sv; ad2[d] = dv; }
}

// ---------------- global max of as2 ----------------

__global__ __launch_bounds__(256) void k_maxas2(const float* __restrict__ as2,
                                                unsigned* __restrict__ enc) {
  int t = blockIdx.x * 256 + threadIdx.x;  // 64 blocks -> 16384 threads
  float mx = -1e30f;
  for (int r = t; r < N_NODES; r += 16384) mx = fmaxf(mx, as2[r]);
#pragma unroll
  for (int off = 32; off; off >>= 1) mx = fmaxf(mx, __shfl_xor(mx, off));
  if ((threadIdx.x & 63) == 0) atomicMax(enc, encf(mx));
}

// ---------------- conv2 aggregation + bias + log_softmax ----------------
// 60 lanes = 20 channel-pairs x 3 edge-slots; 2 slot-groups in flight.

__global__ __launch_bounds__(256) void k_agg2(
    const __half* __restrict__ h2, const float* __restrict__ as2,
    const float* __restrict__ ad2, const int* __restrict__ start,
    const int* __restrict__ esrc, const float* __restrict__ b2,
    const unsigned* __restrict__ as2maxEnc, float* __restrict__ out) {
  __shared__ __align__(16) float p_l[4][64];
  __shared__ __align__(16) int s_l[4][64];  // byte offsets (s*80)
  int wave = threadIdx.x >> 6, lane = threadIdx.x & 63;
  int d = blockIdx.x * 4 + wave;
  if (d >= N_NODES) return;
  int s0 = start[d];
  int deg = start[d + 1] - s0;
  float adv = ad2[d];
  float cm = decf(as2maxEnc[0]) + adv;
  cm = cm > 0.f ? cm : 0.2f * cm;

  int cp = lane % 20;        // channel pair (ch 2cp, 2cp+1)
  int es = lane / 20;        // edge slot 0..2 (lanes >= 60 idle in serial)
  const char* h2b = (const char*)h2 + cp * 4;

  float den = 0.f, acc0 = 0.f, acc1 = 0.f;
  for (int be = 0; be < deg; be += 64) {
    int cnt = min(64, deg - be);
    if (lane < cnt) {
      int s = esrc[s0 + be + lane];
      s_l[wave][lane] = s * 80;  // byte offset into h2 (40 halves)
      float e = as2[s] + adv;
      e = e > 0.f ? e : 0.2f * e;
      float p = __expf(e - cm);
      den += p;
      p_l[wave][lane] = p;
    }
    asm volatile("s_waitcnt lgkmcnt(0)" ::: "memory");
    if (es < 3) {
      int i = 0;
      for (; i + 5 < cnt; i += 6) {
        int eA = i + es, eB = i + 3 + es;
        int sbA = s_l[wave][eA], sbB = s_l[wave][eB];
        float pA = p_l[wave][eA], pB = p_l[wave][eB];
        __half2 hvA = *(const __half2*)(h2b + (unsigned)sbA);
        __half2 hvB = *(const __half2*)(h2b + (unsigned)sbB);
        acc0 = fmaf(__half2float(hvA.x), pA, acc0);
        acc1 = fmaf(__half2float(hvA.y), pA, acc1);
        acc0 = fmaf(__half2float(hvB.x), pB, acc0);
        acc1 = fmaf(__half2float(hvB.y), pB, acc1);
      }
      for (; i < cnt; i += 3) {
        int e = i + es;
        if (e < cnt) {
          int sb = s_l[wave][e];
          float p = p_l[wave][e];
          __half2 hv = *(const __half2*)(h2b + (unsigned)sb);
          acc0 = fmaf(__half2float(hv.x), p, acc0);
          acc1 = fmaf(__half2float(hv.y), p, acc1);
        }
      }
    }
    asm volatile("s_waitcnt lgkmcnt(0)" ::: "memory");
  }
#pragma unroll
  for (int off = 32; off; off >>= 1) den += __shfl_xor(den, off);
  float iv = 1.f / den;

  // combine 3 edge-slots: lanes 0..19 gather from +20, +40
  acc0 += __shfl(acc0, lane + 20) + __shfl(acc0, lane + 40);
  acc1 += __shfl(acc1, lane + 20) + __shfl(acc1, lane + 40);
  // distribute pairs to 40-lane layout: channel j from lane j>>1, comp j&1
  float va = __shfl(acc0, lane >> 1);
  float vb = __shfl(acc1, lane >> 1);
  float v = (lane & 1) ? vb : va;
  v = (lane < N_CLS) ? v * iv + b2[lane] : -1e30f;

  float mx = v;
#pragma unroll
  for (int off = 32; off; off >>= 1) mx = fmaxf(mx, __shfl_xor(mx, off));
  float ex = (lane < N_CLS) ? __expf(v - mx) : 0.f;
  float sm = ex;
#pragma unroll
  for (int off = 32; off; off >>= 1) sm += __shfl_xor(sm, off);
  float lse = logf(sm);
  if (lane < N_CLS) out[d * N_CLS + lane] = (v - mx) - lse;
}

// ---------------- host launcher ----------------

extern "C" void kernel_launch(void* const* d_in, const int* in_sizes, int n_in,
                              void* d_out, int out_size, void* d_ws, size_t ws_size,
                              hipStream_t stream) {
  const float* x    = (const float*)d_in[0];
  const int*   ei   = (const int*)d_in[1];
  const float* W1   = (const float*)d_in[2];
  const float* as1w = (const float*)d_in[3];
  const float* ad1w = (const float*)d_in[4];
  const float* b1   = (const float*)d_in[5];
  const float* W2   = (const float*)d_in[6];
  const float* as2w = (const float*)d_in[7];
  const float* ad2w = (const float*)d_in[8];
  const float* b2   = (const float*)d_in[9];
  float* out = (float*)d_out;

  char* ws = (char*)d_ws;
  size_t off = 0;
  auto alloc = [&](size_t bytes) -> void* {
    void* p = ws + off;
    off += (bytes + 255) & ~(size_t)255;
    return p;
  };
  __half* h1   = (__half*)alloc((size_t)N_NODES * 128 * 2);
  float* as1   = (float*)alloc((size_t)N_NODES * 8 * 4);
  float* ad1   = (float*)alloc((size_t)N_NODES * 8 * 4);
  __half* h2   = (__half*)alloc((size_t)N_NODES * 40 * 2);
  float* as2   = (float*)alloc((size_t)N_NODES * 4);
  float* ad2   = (float*)alloc((size_t)N_NODES * 4);
  // contiguous zero region: deg | cursor | maxenc(16)
  size_t zbytes = (size_t)2 * N_NODES * 4 + 256;
  int* deg     = (int*)alloc(zbytes);
  int* cursor  = deg + N_NODES;
  unsigned* maxenc = (unsigned*)(cursor + N_NODES);  // [0..7]=as1 heads, [8]=as2
  int* start   = (int*)alloc((size_t)(N_NODES + 1) * 4);
  int* esrc    = (int*)alloc((size_t)ET * 4);
  int* bsum    = (int*)alloc((size_t)NSCB * 4);
  int* boff    = (int*)alloc(256 * 4);
  float* fmax1 = (float*)alloc(32);

  (void)hipMemsetAsync(deg, 0, zbytes, stream);

  k_xform1<<<XB + HB, 256, 0, stream>>>(x, W1, as1w, ad1w, ei, deg,
                                        h1, as1, ad1, maxenc);
  k_scanA<<<NSCB, 256, 0, stream>>>(deg, bsum);
  k_scanB<<<1, 256, 0, stream>>>(bsum, boff, start, maxenc, fmax1);
  k_scanC<<<NSCB, 256, 0, stream>>>(deg, boff, start);
  k_scatter<<<HB, 256, 0, stream>>>(ei, start, cursor, esrc);

  k_agg1<<<N_NODES / 16, 256, 0, stream>>>(h1, as1, ad1, start, esrc, b1,
                                           W2, as2w, ad2w, fmax1,
                                           h2, as2, ad2);
  k_maxas2<<<64, 256, 0, stream>>>(as2, maxenc + 8);
  k_agg2<<<(N_NODES + 3) / 4, 256, 0, stream>>>(h2, as2, ad2, start, esrc, b2,
                                                maxenc + 8, out);
}

// Round 13
// 190.590 us; speedup vs baseline: 3.2434x; 1.0810x over previous
//
#include <hip/hip_runtime.h>
#include <hip/hip_fp16.h>
#include <math.h>

#define N_NODES 50000
#define N_EDGES 1000000
#define F_IN 128
#define HID 16
#define N_CLS 40
#define HEADS 8
#define ET (N_EDGES + N_NODES)
#define XB ((N_NODES + 63) / 64)      // 782 xform blocks
#define HB ((ET + 255) / 256)         // 4103 hist blocks
#define NSCB ((N_NODES + 255) / 256)  // 196 scan blocks

__device__ __forceinline__ void fma4(float4& acc, float s, const float4& v) {
  acc.x += s * v.x;
  acc.y += s * v.y;
  acc.z += s * v.z;
  acc.w += s * v.w;
}

__device__ __forceinline__ float dot4(float4 a, float4 b) {
  return a.x * b.x + a.y * b.y + a.z * b.z + a.w * b.w;
}

// monotone float<->uint encoding for atomicMax on floats
__device__ __forceinline__ unsigned encf(float f) {
  unsigned b = __float_as_uint(f);
  return (b & 0x80000000u) ? ~b : (b | 0x80000000u);
}
__device__ __forceinline__ float decf(unsigned k) {
  unsigned b = (k & 0x80000000u) ? (k ^ 0x80000000u) : ~k;
  return __uint_as_float(b);
}

// ---------------- conv1 transform (+ fused hist blocks, + fused as1-max) ----
// Hist blocks also record each edge's intra-bucket position (epos) so the
// scatter needs no atomic.

__global__ __launch_bounds__(256, 4) void k_xform1(
    const float* __restrict__ x, const float* __restrict__ W1,
    const float* __restrict__ att_s, const float* __restrict__ att_d,
    const int* __restrict__ ei, int* __restrict__ deg, int* __restrict__ epos,
    __half* __restrict__ h1, float* __restrict__ as1, float* __restrict__ ad1,
    unsigned* __restrict__ enc1) {
  if (blockIdx.x >= XB) {  // histogram blocks
    int i = (blockIdx.x - XB) * 256 + threadIdx.x;
    if (i < ET) {
      int dd = (i < N_EDGES) ? ei[N_EDGES + i] : (i - N_EDGES);
      epos[i] = atomicAdd(&deg[dd], 1);
    }
    return;
  }
  __shared__ float4 xlds[64 * 9];   // [node][k-quad within phase], padded
  __shared__ float4 wlds[32 * 33];  // [k within phase][c-quad], padded
  __shared__ unsigned encl[8];
  int t = threadIdx.x;
  if (t < 8) encl[t] = 0u;
  int tx = t & 15, ty = t >> 4;
  int base = blockIdx.x * 64;
  const float4* x4 = (const float4*)x;
  const float4* W4 = (const float4*)W1;

  float4 accA[4], accB[4];
#pragma unroll
  for (int n = 0; n < 4; n++) {
    accA[n] = {0.f, 0.f, 0.f, 0.f};
    accB[n] = {0.f, 0.f, 0.f, 0.f};
  }
  int n0 = ty * 4;

  for (int kb = 0; kb < 4; kb++) {
    __syncthreads();  // previous compute done / encl init visible
    // stage x slice: 64 nodes x 8 k-quads
    {
      int i = t;
      int n = i >> 3, q = i & 7;
      int gn = base + n;
      float4 v = {0.f, 0.f, 0.f, 0.f};
      if (gn < N_NODES) v = x4[(size_t)gn * 32 + kb * 8 + q];
      xlds[n * 9 + q] = v;
      i += 256;
      n = i >> 3; q = i & 7;
      gn = base + n;
      float4 v2 = {0.f, 0.f, 0.f, 0.f};
      if (gn < N_NODES) v2 = x4[(size_t)gn * 32 + kb * 8 + q];
      xlds[n * 9 + q] = v2;
    }
    // stage W slice: 32 k-rows x 32 c-quads
#pragma unroll
    for (int u = 0; u < 4; u++) {
      int i = t + u * 256;
      int r = i >> 5, q = i & 31;
      wlds[r * 33 + q] = W4[(size_t)(kb * 32 + r) * 32 + q];
    }
    __syncthreads();
#pragma unroll
    for (int kk = 0; kk < 8; kk++) {
      float4 xv0 = xlds[(n0 + 0) * 9 + kk];
      float4 xv1 = xlds[(n0 + 1) * 9 + kk];
      float4 xv2 = xlds[(n0 + 2) * 9 + kk];
      float4 xv3 = xlds[(n0 + 3) * 9 + kk];
#pragma unroll
      for (int j = 0; j < 4; j++) {
        float4 wA = wlds[(kk * 4 + j) * 33 + tx];
        float4 wB = wlds[(kk * 4 + j) * 33 + tx + 16];
        float s0 = (j == 0) ? xv0.x : (j == 1) ? xv0.y : (j == 2) ? xv0.z : xv0.w;
        float s1 = (j == 0) ? xv1.x : (j == 1) ? xv1.y : (j == 2) ? xv1.z : xv1.w;
        float s2 = (j == 0) ? xv2.x : (j == 1) ? xv2.y : (j == 2) ? xv2.z : xv2.w;
        float s3 = (j == 0) ? xv3.x : (j == 1) ? xv3.y : (j == 2) ? xv3.z : xv3.w;
        fma4(accA[0], s0, wA); fma4(accB[0], s0, wB);
        fma4(accA[1], s1, wA); fma4(accB[1], s1, wB);
        fma4(accA[2], s2, wA); fma4(accB[2], s2, wB);
        fma4(accA[3], s3, wA); fma4(accB[3], s3, wB);
      }
    }
  }

  // epilogue: channels 4tx..4tx+3 (head tx>>2) and 64+4tx.. (head 4+(tx>>2))
  int c4 = tx * 4;
  float4 asA = *(const float4*)(att_s + c4);
  float4 asB = *(const float4*)(att_s + 64 + c4);
  float4 adA = *(const float4*)(att_d + c4);
  float4 adB = *(const float4*)(att_d + 64 + c4);
  float mxA = -1e30f, mxB = -1e30f;
#pragma unroll
  for (int n = 0; n < 4; n++) {
    int gn = base + n0 + n;
    float psA = dot4(accA[n], asA);
    float psB = dot4(accB[n], asB);
    float pdA = dot4(accA[n], adA);
    float pdB = dot4(accB[n], adB);
    psA += __shfl_xor(psA, 1); psA += __shfl_xor(psA, 2);
    psB += __shfl_xor(psB, 1); psB += __shfl_xor(psB, 2);
    pdA += __shfl_xor(pdA, 1); pdA += __shfl_xor(pdA, 2);
    pdB += __shfl_xor(pdB, 1); pdB += __shfl_xor(pdB, 2);
    if (gn < N_NODES) {
      uint2 pkA, pkB;
      __half2* phA = (__half2*)&pkA;
      __half2* phB = (__half2*)&pkB;
      phA[0] = __floats2half2_rn(accA[n].x, accA[n].y);
      phA[1] = __floats2half2_rn(accA[n].z, accA[n].w);
      phB[0] = __floats2half2_rn(accB[n].x, accB[n].y);
      phB[1] = __floats2half2_rn(accB[n].z, accB[n].w);
      *(uint2*)(h1 + (size_t)gn * 128 + c4) = pkA;
      *(uint2*)(h1 + (size_t)gn * 128 + 64 + c4) = pkB;
      mxA = fmaxf(mxA, psA);
      mxB = fmaxf(mxB, psB);
      if ((tx & 3) == 0) {
        as1[gn * 8 + (tx >> 2)] = psA;
        as1[gn * 8 + 4 + (tx >> 2)] = psB;
        ad1[gn * 8 + (tx >> 2)] = pdA;
        ad1[gn * 8 + 4 + (tx >> 2)] = pdB;
      }
    }
  }
  if ((tx & 3) == 0) {
    atomicMax(&encl[tx >> 2], encf(mxA));
    atomicMax(&encl[4 + (tx >> 2)], encf(mxB));
  }
  __syncthreads();
  if (t < 8) atomicMax(&enc1[t], encl[t]);
}

// ---------------- 3-kernel coalesced exclusive scan of deg -> start ----------

__global__ __launch_bounds__(256) void k_scanA(const int* __restrict__ deg,
                                               int* __restrict__ bsum) {
  int i = blockIdx.x * 256 + threadIdx.x;
  int v = (i < N_NODES) ? deg[i] : 0;
#pragma unroll
  for (int off = 32; off; off >>= 1) v += __shfl_xor(v, off);
  __shared__ int ws[4];
  if ((threadIdx.x & 63) == 0) ws[threadIdx.x >> 6] = v;
  __syncthreads();
  if (threadIdx.x == 0) bsum[blockIdx.x] = ws[0] + ws[1] + ws[2] + ws[3];
}

__global__ __launch_bounds__(256) void k_scanB(const int* __restrict__ bsum,
                                               int* __restrict__ boff,
                                               int* __restrict__ start,
                                               const unsigned* __restrict__ enc1,
                                               float* __restrict__ fmax1) {
  __shared__ int s[256];
  int t = threadIdx.x;
  int v0 = (t < NSCB) ? bsum[t] : 0;
  s[t] = v0;
  __syncthreads();
  for (int off = 1; off < 256; off <<= 1) {
    int v = (t >= off) ? s[t - off] : 0;
    __syncthreads();
    s[t] += v;
    __syncthreads();
  }
  boff[t] = s[t] - v0;  // exclusive
  if (t == 0) start[N_NODES] = ET;
  if (t < 8) fmax1[t] = decf(enc1[t]);  // pre-decode as1 per-head max
}

__global__ __launch_bounds__(256) void k_scanC(const int* __restrict__ deg,
                                               const int* __restrict__ boff,
                                               int* __restrict__ start) {
  __shared__ int s[256];
  int t = threadIdx.x;
  int i = blockIdx.x * 256 + t;
  int v0 = (i < N_NODES) ? deg[i] : 0;
  s[t] = v0;
  __syncthreads();
  for (int off = 1; off < 256; off <<= 1) {
    int v = (t >= off) ? s[t - off] : 0;
    __syncthreads();
    s[t] += v;
    __syncthreads();
  }
  if (i < N_NODES) start[i] = boff[blockIdx.x] + s[t] - v0;
}

// atomic-free scatter: position precomputed by hist
__global__ void k_scatter(const int* __restrict__ ei, const int* __restrict__ start,
                          const int* __restrict__ epos, int* __restrict__ esrc) {
  int i = blockIdx.x * blockDim.x + threadIdx.x;
  if (i >= ET) return;
  int s, d;
  if (i < N_EDGES) { s = ei[i]; d = ei[N_EDGES + i]; }
  else { s = i - N_EDGES; d = s; }
  esrc[start[d] + epos[i]] = s;
}

// ---------------- conv1 aggregation + fused conv2 transform (+ as2 max) -----
// 16-lane groups: wave = 4 dst; lane = 8 channels (16B dwordx4 gathers).

__global__ __launch_bounds__(256) void k_agg1(
    const __half* __restrict__ h1, const float* __restrict__ as1,
    const float* __restrict__ ad1, const int* __restrict__ start,
    const int* __restrict__ esrc, const float* __restrict__ b1,
    const float* __restrict__ W2, const float* __restrict__ att_s2,
    const float* __restrict__ att_d2, const float* __restrict__ fmax1,
    __half* __restrict__ h2, float* __restrict__ as2, float* __restrict__ ad2,
    unsigned* __restrict__ enc2) {
  __shared__ __align__(16) __half2 p_t[4][4][8][20];  // [wave][g][head][16e+pad]
  __shared__ __align__(16) int s_off[4][4][20];       // [wave][g][16e+pad]
  __shared__ float w2s[16 * 40];
  __shared__ unsigned encb;
  int t = threadIdx.x;
  if (t == 0) encb = 0u;
  for (int i = t; i < 640; i += 256) w2s[i] = W2[i];
  __syncthreads();

  int wave = t >> 6, lane = t & 63;
  int g = lane >> 4, li = lane & 15;
  int d = blockIdx.x * 16 + wave * 4 + g;  // 3125*16 = 50000 exact
  int s0 = start[d];
  int deg = start[d + 1] - s0;

  int dm = deg;
  dm = max(dm, __shfl_xor(dm, 16));
  dm = max(dm, __shfl_xor(dm, 32));

  float4 av0 = *(const float4*)(ad1 + d * 8);
  float4 av1 = *(const float4*)(ad1 + d * 8 + 4);
  float ad_[8] = {av0.x, av0.y, av0.z, av0.w, av1.x, av1.y, av1.z, av1.w};
  float c_[8];
#pragma unroll
  for (int h = 0; h < 8; h++) {
    float e = fmax1[h] + ad_[h];
    c_[h] = e > 0.f ? e : 0.2f * e;
  }

  float den = 0.f;
  float accf[8];
#pragma unroll
  for (int k = 0; k < 8; k++) accf[k] = 0.f;

  int hsel = li >> 1;
  const char* h1l = (const char*)(h1 + li * 8);  // lane's 16B channel chunk

  for (int be = 0; be < dm; be += 16) {
    int cnt = deg - be;  // may be <= 0
    bool act = li < cnt;
    int s = 0;
    if (act) s = esrc[s0 + be + li];
    s_off[wave][g][li] = act ? (s << 8) : 0;
    float4 p0 = {0.f, 0.f, 0.f, 0.f}, p1 = {0.f, 0.f, 0.f, 0.f};
    if (act) {
      p0 = *(const float4*)(as1 + (size_t)s * 8);
      p1 = *(const float4*)(as1 + (size_t)s * 8 + 4);
    }
    float ev[8] = {p0.x, p0.y, p0.z, p0.w, p1.x, p1.y, p1.z, p1.w};
#pragma unroll
    for (int h = 0; h < 8; h++) {
      float v = ev[h] + ad_[h];
      v = v > 0.f ? v : 0.2f * v;
      float pv = act ? __expf(v - c_[h]) : 0.f;
      __half hp = __float2half(pv);
      p_t[wave][g][h][li] = __half2{hp, hp};
    }
    asm volatile("s_waitcnt lgkmcnt(0)" ::: "memory");

    int cm = min(dm - be, 16);
    const __half2* pt = &p_t[wave][g][hsel][0];
    const int* so = &s_off[wave][g][0];
    __half2 a0 = __floats2half2_rn(0.f, 0.f);
    __half2 a1 = __floats2half2_rn(0.f, 0.f);
    __half2 a2 = __floats2half2_rn(0.f, 0.f);
    __half2 a3 = __floats2half2_rn(0.f, 0.f);
    for (int e = 0; e < cm; e += 4) {
      int4 s4 = *(const int4*)&so[e];
      uint4 pw = *(const uint4*)&pt[e];
      const __half2* pp = (const __half2*)&pw;
      uint4 hA = *(const uint4*)(h1l + (unsigned)s4.x);
      uint4 hB = *(const uint4*)(h1l + (unsigned)s4.y);
      uint4 hC = *(const uint4*)(h1l + (unsigned)s4.z);
      uint4 hD = *(const uint4*)(h1l + (unsigned)s4.w);
      const __half2* vA = (const __half2*)&hA;
      const __half2* vB = (const __half2*)&hB;
      const __half2* vC = (const __half2*)&hC;
      const __half2* vD = (const __half2*)&hD;
      a0 = __hfma2(vA[0], pp[0], a0); a1 = __hfma2(vA[1], pp[0], a1);
      a2 = __hfma2(vA[2], pp[0], a2); a3 = __hfma2(vA[3], pp[0], a3);
      a0 = __hfma2(vB[0], pp[1], a0); a1 = __hfma2(vB[1], pp[1], a1);
      a2 = __hfma2(vB[2], pp[1], a2); a3 = __hfma2(vB[3], pp[1], a3);
      a0 = __hfma2(vC[0], pp[2], a0); a1 = __hfma2(vC[1], pp[2], a1);
      a2 = __hfma2(vC[2], pp[2], a2); a3 = __hfma2(vC[3], pp[2], a3);
      a0 = __hfma2(vD[0], pp[3], a0); a1 = __hfma2(vD[1], pp[3], a1);
      a2 = __hfma2(vD[2], pp[3], a2); a3 = __hfma2(vD[3], pp[3], a3);
      den += __low2float(pp[0]) + __low2float(pp[1]) +
             __low2float(pp[2]) + __low2float(pp[3]);
    }
    // promote chunk accumulators to fp32
    float2 f0 = __half22float2(a0), f1 = __half22float2(a1);
    float2 f2 = __half22float2(a2), f3 = __half22float2(a3);
    accf[0] += f0.x; accf[1] += f0.y; accf[2] += f1.x; accf[3] += f1.y;
    accf[4] += f2.x; accf[5] += f2.y; accf[6] += f3.x; accf[7] += f3.y;
    asm volatile("s_waitcnt lgkmcnt(0)" ::: "memory");
  }

  // normalize by own head's den, fold in 1/8 head-mean
  float sc = 0.125f / den;
#pragma unroll
  for (int k = 0; k < 8; k++) accf[k] *= sc;
  // sum over heads: xor 2,4,8 within the 16-lane group
#pragma unroll
  for (int off = 2; off <= 8; off <<= 1) {
#pragma unroll
    for (int k = 0; k < 8; k++) accf[k] += __shfl_xor(accf[k], off);
  }
  // lane holds mean for ch (li&1)*8 + k
  int jb = (li & 1) * 8;
  float4 b1a = *(const float4*)(b1 + jb);
  float4 b1b = *(const float4*)(b1 + jb + 4);
  float bv[8] = {b1a.x, b1a.y, b1a.z, b1a.w, b1b.x, b1b.y, b1b.z, b1b.w};
  float r[8];
#pragma unroll
  for (int k = 0; k < 8; k++) {
    float v = accf[k] + bv[k];
    r[k] = v > 0.f ? v : __expf(v) - 1.f;
  }
  float ro[8];
#pragma unroll
  for (int k = 0; k < 8; k++) ro[k] = __shfl_xor(r[k], 1);

  // conv2 transform: outputs j = li, li+16, li+32(li<8)
  float o0 = 0.f, o1 = 0.f, o2 = 0.f;
  bool has2 = li < 8;
#pragma unroll
  for (int k = 0; k < 16; k++) {
    float rk;
    if (k < 8) rk = (li & 1) ? ro[k] : r[k];
    else       rk = (li & 1) ? r[k - 8] : ro[k - 8];
    o0 = fmaf(rk, w2s[k * 40 + li], o0);
    o1 = fmaf(rk, w2s[k * 40 + li + 16], o1);
    if (has2) o2 = fmaf(rk, w2s[k * 40 + li + 32], o2);
  }
  __half* h2r = h2 + d * 40;
  h2r[li] = __float2half(o0);
  h2r[li + 16] = __float2half(o1);
  if (has2) h2r[li + 32] = __float2half(o2);

  float sv = o0 * att_s2[li] + o1 * att_s2[li + 16];
  float dv = o0 * att_d2[li] + o1 * att_d2[li + 16];
  if (has2) {
    sv = fmaf(o2, att_s2[li + 32], sv);
    dv = fmaf(o2, att_d2[li + 32], dv);
  }
#pragma unroll
  for (int off = 1; off <= 8; off <<= 1) {
    sv += __shfl_xor(sv, off);
    dv += __shfl_xor(dv, off);
  }
  if (li == 0) {
    as2[d] = sv;
    ad2[d] = dv;
    atomicMax(&encb, encf(sv));
  }
  __syncthreads();
  if (t == 0) atomicMax(enc2, encb);
}

// ---------------- conv2 aggregation + bias + log_softmax ----------------
// 60 lanes = 20 channel-pairs x 3 edge-slots; 2 slot-groups in flight.

__global__ __launch_bounds__(256) void k_agg2(
    const __half* __restrict__ h2, const float* __restrict__ as2,
    const float* __restrict__ ad2, const int* __restrict__ start,
    const int* __restrict__ esrc, const float* __restrict__ b2,
    const unsigned* __restrict__ as2maxEnc, float* __restrict__ out) {
  __shared__ __align__(16) float p_l[4][64];
  __shared__ __align__(16) int s_l[4][64];  // byte offsets (s*80)
  int wave = threadIdx.x >> 6, lane = threadIdx.x & 63;
  int d = blockIdx.x * 4 + wave;
  if (d >= N_NODES) return;
  int s0 = start[d];
  int deg = start[d + 1] - s0;
  float adv = ad2[d];
  float cm = decf(as2maxEnc[0]) + adv;
  cm = cm > 0.f ? cm : 0.2f * cm;

  int cp = lane % 20;        // channel pair (ch 2cp, 2cp+1)
  int es = lane / 20;        // edge slot 0..2 (lanes >= 60 idle in serial)
  const char* h2b = (const char*)h2 + cp * 4;

  float den = 0.f, acc0 = 0.f, acc1 = 0.f;
  for (int be = 0; be < deg; be += 64) {
    int cnt = min(64, deg - be);
    if (lane < cnt) {
      int s = esrc[s0 + be + lane];
      s_l[wave][lane] = s * 80;  // byte offset into h2 (40 halves)
      float e = as2[s] + adv;
      e = e > 0.f ? e : 0.2f * e;
      float p = __expf(e - cm);
      den += p;
      p_l[wave][lane] = p;
    }
    asm volatile("s_waitcnt lgkmcnt(0)" ::: "memory");
    if (es < 3) {
      int i = 0;
      for (; i + 5 < cnt; i += 6) {
        int eA = i + es, eB = i + 3 + es;
        int sbA = s_l[wave][eA], sbB = s_l[wave][eB];
        float pA = p_l[wave][eA], pB = p_l[wave][eB];
        __half2 hvA = *(const __half2*)(h2b + (unsigned)sbA);
        __half2 hvB = *(const __half2*)(h2b + (unsigned)sbB);
        acc0 = fmaf(__half2float(hvA.x), pA, acc0);
        acc1 = fmaf(__half2float(hvA.y), pA, acc1);
        acc0 = fmaf(__half2float(hvB.x), pB, acc0);
        acc1 = fmaf(__half2float(hvB.y), pB, acc1);
      }
      for (; i < cnt; i += 3) {
        int e = i + es;
        if (e < cnt) {
          int sb = s_l[wave][e];
          float p = p_l[wave][e];
          __half2 hv = *(const __half2*)(h2b + (unsigned)sb);
          acc0 = fmaf(__half2float(hv.x), p, acc0);
          acc1 = fmaf(__half2float(hv.y), p, acc1);
        }
      }
    }
    asm volatile("s_waitcnt lgkmcnt(0)" ::: "memory");
  }
#pragma unroll
  for (int off = 32; off; off >>= 1) den += __shfl_xor(den, off);
  float iv = 1.f / den;

  // combine 3 edge-slots: lanes 0..19 gather from +20, +40
  acc0 += __shfl(acc0, lane + 20) + __shfl(acc0, lane + 40);
  acc1 += __shfl(acc1, lane + 20) + __shfl(acc1, lane + 40);
  // distribute pairs to 40-lane layout: channel j from lane j>>1, comp j&1
  float va = __shfl(acc0, lane >> 1);
  float vb = __shfl(acc1, lane >> 1);
  float v = (lane & 1) ? vb : va;
  v = (lane < N_CLS) ? v * iv + b2[lane] : -1e30f;

  float mx = v;
#pragma unroll
  for (int off = 32; off; off >>= 1) mx = fmaxf(mx, __shfl_xor(mx, off));
  float ex = (lane < N_CLS) ? __expf(v - mx) : 0.f;
  float sm = ex;
#pragma unroll
  for (int off = 32; off; off >>= 1) sm += __shfl_xor(sm, off);
  float lse = logf(sm);
  if (lane < N_CLS) out[d * N_CLS + lane] = (v - mx) - lse;
}

// ---------------- host launcher ----------------

extern "C" void kernel_launch(void* const* d_in, const int* in_sizes, int n_in,
                              void* d_out, int out_size, void* d_ws, size_t ws_size,
                              hipStream_t stream) {
  const float* x    = (const float*)d_in[0];
  const int*   ei   = (const int*)d_in[1];
  const float* W1   = (const float*)d_in[2];
  const float* as1w = (const float*)d_in[3];
  const float* ad1w = (const float*)d_in[4];
  const float* b1   = (const float*)d_in[5];
  const float* W2   = (const float*)d_in[6];
  const float* as2w = (const float*)d_in[7];
  const float* ad2w = (const float*)d_in[8];
  const float* b2   = (const float*)d_in[9];
  float* out = (float*)d_out;

  char* ws = (char*)d_ws;
  size_t off = 0;
  auto alloc = [&](size_t bytes) -> void* {
    void* p = ws + off;
    off += (bytes + 255) & ~(size_t)255;
    return p;
  };
  __half* h1   = (__half*)alloc((size_t)N_NODES * 128 * 2);
  float* as1   = (float*)alloc((size_t)N_NODES * 8 * 4);
  float* ad1   = (float*)alloc((size_t)N_NODES * 8 * 4);
  __half* h2   = (__half*)alloc((size_t)N_NODES * 40 * 2);
  float* as2   = (float*)alloc((size_t)N_NODES * 4);
  float* ad2   = (float*)alloc((size_t)N_NODES * 4);
  // contiguous zero region: deg | maxenc(16)
  size_t zbytes = (size_t)N_NODES * 4 + 256;
  int* deg     = (int*)alloc(zbytes);
  unsigned* maxenc = (unsigned*)(deg + N_NODES);  // [0..7]=as1 heads, [8]=as2
  int* start   = (int*)alloc((size_t)(N_NODES + 1) * 4);
  int* esrc    = (int*)alloc((size_t)ET * 4);
  int* epos    = (int*)alloc((size_t)ET * 4);
  int* bsum    = (int*)alloc((size_t)NSCB * 4);
  int* boff    = (int*)alloc(256 * 4);
  float* fmax1 = (float*)alloc(32);

  (void)hipMemsetAsync(deg, 0, zbytes, stream);

  k_xform1<<<XB + HB, 256, 0, stream>>>(x, W1, as1w, ad1w, ei, deg, epos,
                                        h1, as1, ad1, maxenc);
  k_scanA<<<NSCB, 256, 0, stream>>>(deg, bsum);
  k_scanB<<<1, 256, 0, stream>>>(bsum, boff, start, maxenc, fmax1);
  k_scanC<<<NSCB, 256, 0, stream>>>(deg, boff, start);
  k_scatter<<<HB, 256, 0, stream>>>(ei, start, epos, esrc);

  k_agg1<<<N_NODES / 16, 256, 0, stream>>>(h1, as1, ad1, start, esrc, b1,
                                           W2, as2w, ad2w, fmax1,
                                           h2, as2, ad2, maxenc + 8);
  k_agg2<<<(N_NODES + 3) / 4, 256, 0, stream>>>(h2, as2, ad2, start, esrc, b2,
                                                maxenc + 8, out);
}

// Round 14
// 172.007 us; speedup vs baseline: 3.5939x; 1.1080x over previous
//
#include <hip/hip_runtime.h>
#include <hip/hip_fp16.h>
#include <math.h>

#define N_NODES 50000
#define N_EDGES 1000000
#define F_IN 128
#define HID 16
#define N_CLS 40
#define HEADS 8
#define ET (N_EDGES + N_NODES)
#define XB ((N_NODES + 63) / 64)      // 782 xform blocks
#define HB ((ET + 255) / 256)         // 4103 hist blocks
#define NSCB ((N_NODES + 255) / 256)  // 196 scan blocks

__device__ __forceinline__ void fma4(float4& acc, float s, const float4& v) {
  acc.x += s * v.x;
  acc.y += s * v.y;
  acc.z += s * v.z;
  acc.w += s * v.w;
}

__device__ __forceinline__ float dot4(float4 a, float4 b) {
  return a.x * b.x + a.y * b.y + a.z * b.z + a.w * b.w;
}

// monotone float<->uint encoding for atomicMax on floats
__device__ __forceinline__ unsigned encf(float f) {
  unsigned b = __float_as_uint(f);
  return (b & 0x80000000u) ? ~b : (b | 0x80000000u);
}
__device__ __forceinline__ float decf(unsigned k) {
  unsigned b = (k & 0x80000000u) ? (k ^ 0x80000000u) : ~k;
  return __uint_as_float(b);
}

// ---------------- conv1 transform (+ fused hist blocks, + fused as1-max) ----
// Hist blocks also record each edge's intra-bucket position (epos) so the
// scatter needs no atomic.

__global__ __launch_bounds__(256, 4) void k_xform1(
    const float* __restrict__ x, const float* __restrict__ W1,
    const float* __restrict__ att_s, const float* __restrict__ att_d,
    const int* __restrict__ ei, int* __restrict__ deg, int* __restrict__ epos,
    __half* __restrict__ h1, float* __restrict__ as1, float* __restrict__ ad1,
    unsigned* __restrict__ enc1) {
  if (blockIdx.x >= XB) {  // histogram blocks
    int i = (blockIdx.x - XB) * 256 + threadIdx.x;
    if (i < ET) {
      int dd = (i < N_EDGES) ? ei[N_EDGES + i] : (i - N_EDGES);
      epos[i] = atomicAdd(&deg[dd], 1);
    }
    return;
  }
  __shared__ float4 xlds[64 * 9];   // [node][k-quad within phase], padded
  __shared__ float4 wlds[32 * 33];  // [k within phase][c-quad], padded
  __shared__ unsigned encl[8];
  int t = threadIdx.x;
  if (t < 8) encl[t] = 0u;
  int tx = t & 15, ty = t >> 4;
  int base = blockIdx.x * 64;
  const float4* x4 = (const float4*)x;
  const float4* W4 = (const float4*)W1;

  float4 accA[4], accB[4];
#pragma unroll
  for (int n = 0; n < 4; n++) {
    accA[n] = {0.f, 0.f, 0.f, 0.f};
    accB[n] = {0.f, 0.f, 0.f, 0.f};
  }
  int n0 = ty * 4;

  for (int kb = 0; kb < 4; kb++) {
    __syncthreads();  // previous compute done / encl init visible
    // stage x slice: 64 nodes x 8 k-quads
    {
      int i = t;
      int n = i >> 3, q = i & 7;
      int gn = base + n;
      float4 v = {0.f, 0.f, 0.f, 0.f};
      if (gn < N_NODES) v = x4[(size_t)gn * 32 + kb * 8 + q];
      xlds[n * 9 + q] = v;
      i += 256;
      n = i >> 3; q = i & 7;
      gn = base + n;
      float4 v2 = {0.f, 0.f, 0.f, 0.f};
      if (gn < N_NODES) v2 = x4[(size_t)gn * 32 + kb * 8 + q];
      xlds[n * 9 + q] = v2;
    }
    // stage W slice: 32 k-rows x 32 c-quads
#pragma unroll
    for (int u = 0; u < 4; u++) {
      int i = t + u * 256;
      int r = i >> 5, q = i & 31;
      wlds[r * 33 + q] = W4[(size_t)(kb * 32 + r) * 32 + q];
    }
    __syncthreads();
#pragma unroll
    for (int kk = 0; kk < 8; kk++) {
      float4 xv0 = xlds[(n0 + 0) * 9 + kk];
      float4 xv1 = xlds[(n0 + 1) * 9 + kk];
      float4 xv2 = xlds[(n0 + 2) * 9 + kk];
      float4 xv3 = xlds[(n0 + 3) * 9 + kk];
#pragma unroll
      for (int j = 0; j < 4; j++) {
        float4 wA = wlds[(kk * 4 + j) * 33 + tx];
        float4 wB = wlds[(kk * 4 + j) * 33 + tx + 16];
        float s0 = (j == 0) ? xv0.x : (j == 1) ? xv0.y : (j == 2) ? xv0.z : xv0.w;
        float s1 = (j == 0) ? xv1.x : (j == 1) ? xv1.y : (j == 2) ? xv1.z : xv1.w;
        float s2 = (j == 0) ? xv2.x : (j == 1) ? xv2.y : (j == 2) ? xv2.z : xv2.w;
        float s3 = (j == 0) ? xv3.x : (j == 1) ? xv3.y : (j == 2) ? xv3.z : xv3.w;
        fma4(accA[0], s0, wA); fma4(accB[0], s0, wB);
        fma4(accA[1], s1, wA); fma4(accB[1], s1, wB);
        fma4(accA[2], s2, wA); fma4(accB[2], s2, wB);
        fma4(accA[3], s3, wA); fma4(accB[3], s3, wB);
      }
    }
  }

  // epilogue: channels 4tx..4tx+3 (head tx>>2) and 64+4tx.. (head 4+(tx>>2))
  int c4 = tx * 4;
  float4 asA = *(const float4*)(att_s + c4);
  float4 asB = *(const float4*)(att_s + 64 + c4);
  float4 adA = *(const float4*)(att_d + c4);
  float4 adB = *(const float4*)(att_d + 64 + c4);
  float mxA = -1e30f, mxB = -1e30f;
#pragma unroll
  for (int n = 0; n < 4; n++) {
    int gn = base + n0 + n;
    float psA = dot4(accA[n], asA);
    float psB = dot4(accB[n], asB);
    float pdA = dot4(accA[n], adA);
    float pdB = dot4(accB[n], adB);
    psA += __shfl_xor(psA, 1); psA += __shfl_xor(psA, 2);
    psB += __shfl_xor(psB, 1); psB += __shfl_xor(psB, 2);
    pdA += __shfl_xor(pdA, 1); pdA += __shfl_xor(pdA, 2);
    pdB += __shfl_xor(pdB, 1); pdB += __shfl_xor(pdB, 2);
    if (gn < N_NODES) {
      uint2 pkA, pkB;
      __half2* phA = (__half2*)&pkA;
      __half2* phB = (__half2*)&pkB;
      phA[0] = __floats2half2_rn(accA[n].x, accA[n].y);
      phA[1] = __floats2half2_rn(accA[n].z, accA[n].w);
      phB[0] = __floats2half2_rn(accB[n].x, accB[n].y);
      phB[1] = __floats2half2_rn(accB[n].z, accB[n].w);
      *(uint2*)(h1 + (size_t)gn * 128 + c4) = pkA;
      *(uint2*)(h1 + (size_t)gn * 128 + 64 + c4) = pkB;
      mxA = fmaxf(mxA, psA);
      mxB = fmaxf(mxB, psB);
      if ((tx & 3) == 0) {
        as1[gn * 8 + (tx >> 2)] = psA;
        as1[gn * 8 + 4 + (tx >> 2)] = psB;
        ad1[gn * 8 + (tx >> 2)] = pdA;
        ad1[gn * 8 + 4 + (tx >> 2)] = pdB;
      }
    }
  }
  if ((tx & 3) == 0) {
    atomicMax(&encl[tx >> 2], encf(mxA));
    atomicMax(&encl[4 + (tx >> 2)], encf(mxB));
  }
  __syncthreads();
  if (t < 8) atomicMax(&enc1[t], encl[t]);
}

// ---------------- 3-kernel coalesced exclusive scan of deg -> start ----------

__global__ __launch_bounds__(256) void k_scanA(const int* __restrict__ deg,
                                               int* __restrict__ bsum) {
  int i = blockIdx.x * 256 + threadIdx.x;
  int v = (i < N_NODES) ? deg[i] : 0;
#pragma unroll
  for (int off = 32; off; off >>= 1) v += __shfl_xor(v, off);
  __shared__ int ws[4];
  if ((threadIdx.x & 63) == 0) ws[threadIdx.x >> 6] = v;
  __syncthreads();
  if (threadIdx.x == 0) bsum[blockIdx.x] = ws[0] + ws[1] + ws[2] + ws[3];
}

__global__ __launch_bounds__(256) void k_scanB(const int* __restrict__ bsum,
                                               int* __restrict__ boff,
                                               int* __restrict__ start,
                                               const unsigned* __restrict__ enc1,
                                               float* __restrict__ fmax1) {
  __shared__ int s[256];
  int t = threadIdx.x;
  int v0 = (t < NSCB) ? bsum[t] : 0;
  s[t] = v0;
  __syncthreads();
  for (int off = 1; off < 256; off <<= 1) {
    int v = (t >= off) ? s[t - off] : 0;
    __syncthreads();
    s[t] += v;
    __syncthreads();
  }
  boff[t] = s[t] - v0;  // exclusive
  if (t == 0) start[N_NODES] = ET;
  if (t < 8) fmax1[t] = decf(enc1[t]);  // pre-decode as1 per-head max
}

__global__ __launch_bounds__(256) void k_scanC(const int* __restrict__ deg,
                                               const int* __restrict__ boff,
                                               int* __restrict__ start) {
  __shared__ int s[256];
  int t = threadIdx.x;
  int i = blockIdx.x * 256 + t;
  int v0 = (i < N_NODES) ? deg[i] : 0;
  s[t] = v0;
  __syncthreads();
  for (int off = 1; off < 256; off <<= 1) {
    int v = (t >= off) ? s[t - off] : 0;
    __syncthreads();
    s[t] += v;
    __syncthreads();
  }
  if (i < N_NODES) start[i] = boff[blockIdx.x] + s[t] - v0;
}

// atomic-free scatter: position precomputed by hist
__global__ void k_scatter(const int* __restrict__ ei, const int* __restrict__ start,
                          const int* __restrict__ epos, int* __restrict__ esrc) {
  int i = blockIdx.x * blockDim.x + threadIdx.x;
  if (i >= ET) return;
  int s, d;
  if (i < N_EDGES) { s = ei[i]; d = ei[N_EDGES + i]; }
  else { s = i - N_EDGES; d = s; }
  esrc[start[d] + epos[i]] = s;
}

// ---------------- conv1 aggregation + fused conv2 transform ----------------
// 16-lane groups: wave = 4 dst; lane = 8 channels (16B dwordx4 gathers).
// 8-deep gather unroll; de-aligned p_t group stride (656B) to stagger banks.

__global__ __launch_bounds__(256) void k_agg1(
    const __half* __restrict__ h1, const float* __restrict__ as1,
    const float* __restrict__ ad1, const int* __restrict__ start,
    const int* __restrict__ esrc, const float* __restrict__ b1,
    const float* __restrict__ W2, const float* __restrict__ att_s2,
    const float* __restrict__ att_d2, const float* __restrict__ fmax1,
    __half* __restrict__ h2, float* __restrict__ as2, float* __restrict__ ad2) {
  __shared__ __align__(16) __half2 p_t[4][4 * 164];  // [wave][g*164 + head*20 + e]
  __shared__ __align__(16) int s_off[4][4][20];      // [wave][g][16e+pad]
  __shared__ float w2s[16 * 40];
  int t = threadIdx.x;
  for (int i = t; i < 640; i += 256) w2s[i] = W2[i];
  __syncthreads();

  int wave = t >> 6, lane = t & 63;
  int g = lane >> 4, li = lane & 15;
  int d = blockIdx.x * 16 + wave * 4 + g;  // 3125*16 = 50000 exact
  int s0 = start[d];
  int deg = start[d + 1] - s0;

  int dm = deg;
  dm = max(dm, __shfl_xor(dm, 16));
  dm = max(dm, __shfl_xor(dm, 32));

  float4 av0 = *(const float4*)(ad1 + d * 8);
  float4 av1 = *(const float4*)(ad1 + d * 8 + 4);
  float ad_[8] = {av0.x, av0.y, av0.z, av0.w, av1.x, av1.y, av1.z, av1.w};
  float c_[8];
#pragma unroll
  for (int h = 0; h < 8; h++) {
    float e = fmax1[h] + ad_[h];
    c_[h] = e > 0.f ? e : 0.2f * e;
  }

  float den = 0.f;
  float accf[8];
#pragma unroll
  for (int k = 0; k < 8; k++) accf[k] = 0.f;

  int hsel = li >> 1;
  const char* h1l = (const char*)(h1 + li * 8);  // lane's 16B channel chunk
  __half2* ptw = &p_t[wave][g * 164];
  const int* so = &s_off[wave][g][0];

  for (int be = 0; be < dm; be += 16) {
    int cnt = deg - be;  // may be <= 0
    bool act = li < cnt;
    int s = 0;
    if (act) s = esrc[s0 + be + li];
    s_off[wave][g][li] = act ? (s << 8) : 0;
    float4 p0 = {0.f, 0.f, 0.f, 0.f}, p1 = {0.f, 0.f, 0.f, 0.f};
    if (act) {
      p0 = *(const float4*)(as1 + (size_t)s * 8);
      p1 = *(const float4*)(as1 + (size_t)s * 8 + 4);
    }
    float ev[8] = {p0.x, p0.y, p0.z, p0.w, p1.x, p1.y, p1.z, p1.w};
#pragma unroll
    for (int h = 0; h < 8; h++) {
      float v = ev[h] + ad_[h];
      v = v > 0.f ? v : 0.2f * v;
      float pv = act ? __expf(v - c_[h]) : 0.f;
      __half hp = __float2half(pv);
      ptw[h * 20 + li] = __half2{hp, hp};
    }
    asm volatile("s_waitcnt lgkmcnt(0)" ::: "memory");

    int cm = min(dm - be, 16);
    const __half2* pt = ptw + hsel * 20;
    __half2 a0 = __floats2half2_rn(0.f, 0.f);
    __half2 a1 = __floats2half2_rn(0.f, 0.f);
    __half2 a2 = __floats2half2_rn(0.f, 0.f);
    __half2 a3 = __floats2half2_rn(0.f, 0.f);
    for (int e = 0; e < cm; e += 8) {  // pad entries are (p=0, off=0): safe
      int4 s4 = *(const int4*)&so[e];
      int4 s8 = *(const int4*)&so[e + 4];
      uint4 pwA = *(const uint4*)&pt[e];
      uint4 pwB = *(const uint4*)&pt[e + 4];
      const __half2* ppA = (const __half2*)&pwA;
      const __half2* ppB = (const __half2*)&pwB;
      uint4 hA = *(const uint4*)(h1l + (unsigned)s4.x);
      uint4 hB = *(const uint4*)(h1l + (unsigned)s4.y);
      uint4 hC = *(const uint4*)(h1l + (unsigned)s4.z);
      uint4 hD = *(const uint4*)(h1l + (unsigned)s4.w);
      uint4 hE = *(const uint4*)(h1l + (unsigned)s8.x);
      uint4 hF = *(const uint4*)(h1l + (unsigned)s8.y);
      uint4 hG = *(const uint4*)(h1l + (unsigned)s8.z);
      uint4 hH = *(const uint4*)(h1l + (unsigned)s8.w);
      const __half2* vA = (const __half2*)&hA;
      const __half2* vB = (const __half2*)&hB;
      const __half2* vC = (const __half2*)&hC;
      const __half2* vD = (const __half2*)&hD;
      const __half2* vE = (const __half2*)&hE;
      const __half2* vF = (const __half2*)&hF;
      const __half2* vG = (const __half2*)&hG;
      const __half2* vH = (const __half2*)&hH;
      a0 = __hfma2(vA[0], ppA[0], a0); a1 = __hfma2(vA[1], ppA[0], a1);
      a2 = __hfma2(vA[2], ppA[0], a2); a3 = __hfma2(vA[3], ppA[0], a3);
      a0 = __hfma2(vB[0], ppA[1], a0); a1 = __hfma2(vB[1], ppA[1], a1);
      a2 = __hfma2(vB[2], ppA[1], a2); a3 = __hfma2(vB[3], ppA[1], a3);
      a0 = __hfma2(vC[0], ppA[2], a0); a1 = __hfma2(vC[1], ppA[2], a1);
      a2 = __hfma2(vC[2], ppA[2], a2); a3 = __hfma2(vC[3], ppA[2], a3);
      a0 = __hfma2(vD[0], ppA[3], a0); a1 = __hfma2(vD[1], ppA[3], a1);
      a2 = __hfma2(vD[2], ppA[3], a2); a3 = __hfma2(vD[3], ppA[3], a3);
      a0 = __hfma2(vE[0], ppB[0], a0); a1 = __hfma2(vE[1], ppB[0], a1);
      a2 = __hfma2(vE[2], ppB[0], a2); a3 = __hfma2(vE[3], ppB[0], a3);
      a0 = __hfma2(vF[0], ppB[1], a0); a1 = __hfma2(vF[1], ppB[1], a1);
      a2 = __hfma2(vF[2], ppB[1], a2); a3 = __hfma2(vF[3], ppB[1], a3);
      a0 = __hfma2(vG[0], ppB[2], a0); a1 = __hfma2(vG[1], ppB[2], a1);
      a2 = __hfma2(vG[2], ppB[2], a2); a3 = __hfma2(vG[3], ppB[2], a3);
      a0 = __hfma2(vH[0], ppB[3], a0); a1 = __hfma2(vH[1], ppB[3], a1);
      a2 = __hfma2(vH[2], ppB[3], a2); a3 = __hfma2(vH[3], ppB[3], a3);
      den += __low2float(ppA[0]) + __low2float(ppA[1]) +
             __low2float(ppA[2]) + __low2float(ppA[3]) +
             __low2float(ppB[0]) + __low2float(ppB[1]) +
             __low2float(ppB[2]) + __low2float(ppB[3]);
    }
    // promote chunk accumulators to fp32
    float2 f0 = __half22float2(a0), f1 = __half22float2(a1);
    float2 f2 = __half22float2(a2), f3 = __half22float2(a3);
    accf[0] += f0.x; accf[1] += f0.y; accf[2] += f1.x; accf[3] += f1.y;
    accf[4] += f2.x; accf[5] += f2.y; accf[6] += f3.x; accf[7] += f3.y;
    asm volatile("s_waitcnt lgkmcnt(0)" ::: "memory");
  }

  // normalize by own head's den, fold in 1/8 head-mean
  float sc = 0.125f / den;
#pragma unroll
  for (int k = 0; k < 8; k++) accf[k] *= sc;
  // sum over heads: xor 2,4,8 within the 16-lane group
#pragma unroll
  for (int off = 2; off <= 8; off <<= 1) {
#pragma unroll
    for (int k = 0; k < 8; k++) accf[k] += __shfl_xor(accf[k], off);
  }
  // lane holds mean for ch (li&1)*8 + k
  int jb = (li & 1) * 8;
  float4 b1a = *(const float4*)(b1 + jb);
  float4 b1b = *(const float4*)(b1 + jb + 4);
  float bv[8] = {b1a.x, b1a.y, b1a.z, b1a.w, b1b.x, b1b.y, b1b.z, b1b.w};
  float r[8];
#pragma unroll
  for (int k = 0; k < 8; k++) {
    float v = accf[k] + bv[k];
    r[k] = v > 0.f ? v : __expf(v) - 1.f;
  }
  float ro[8];
#pragma unroll
  for (int k = 0; k < 8; k++) ro[k] = __shfl_xor(r[k], 1);

  // conv2 transform: outputs j = li, li+16, li+32(li<8)
  float o0 = 0.f, o1 = 0.f, o2 = 0.f;
  bool has2 = li < 8;
#pragma unroll
  for (int k = 0; k < 16; k++) {
    float rk;
    if (k < 8) rk = (li & 1) ? ro[k] : r[k];
    else       rk = (li & 1) ? r[k - 8] : ro[k - 8];
    o0 = fmaf(rk, w2s[k * 40 + li], o0);
    o1 = fmaf(rk, w2s[k * 40 + li + 16], o1);
    if (has2) o2 = fmaf(rk, w2s[k * 40 + li + 32], o2);
  }
  __half* h2r = h2 + d * 40;
  h2r[li] = __float2half(o0);
  h2r[li + 16] = __float2half(o1);
  if (has2) h2r[li + 32] = __float2half(o2);

  float sv = o0 * att_s2[li] + o1 * att_s2[li + 16];
  float dv = o0 * att_d2[li] + o1 * att_d2[li + 16];
  if (has2) {
    sv = fmaf(o2, att_s2[li + 32], sv);
    dv = fmaf(o2, att_d2[li + 32], dv);
  }
#pragma unroll
  for (int off = 1; off <= 8; off <<= 1) {
    sv += __shfl_xor(sv, off);
    dv += __shfl_xor(dv, off);
  }
  if (li == 0) { as2[d] = sv; ad2[d] = dv; }
}

// ---------------- global max of as2 ----------------

__global__ __launch_bounds__(256) void k_maxas2(const float* __restrict__ as2,
                                                unsigned* __restrict__ enc) {
  int t = blockIdx.x * 256 + threadIdx.x;  // 64 blocks -> 16384 threads
  float mx = -1e30f;
  for (int r = t; r < N_NODES; r += 16384) mx = fmaxf(mx, as2[r]);
#pragma unroll
  for (int off = 32; off; off >>= 1) mx = fmaxf(mx, __shfl_xor(mx, off));
  if ((threadIdx.x & 63) == 0) atomicMax(enc, encf(mx));
}

// ---------------- conv2 aggregation + bias + log_softmax ----------------
// 60 lanes = 20 channel-pairs x 3 edge-slots; 2 slot-groups in flight.

__global__ __launch_bounds__(256) void k_agg2(
    const __half* __restrict__ h2, const float* __restrict__ as2,
    const float* __restrict__ ad2, const int* __restrict__ start,
    const int* __restrict__ esrc, const float* __restrict__ b2,
    const unsigned* __restrict__ as2maxEnc, float* __restrict__ out) {
  __shared__ __align__(16) float p_l[4][64];
  __shared__ __align__(16) int s_l[4][64];  // byte offsets (s*80)
  int wave = threadIdx.x >> 6, lane = threadIdx.x & 63;
  int d = blockIdx.x * 4 + wave;
  if (d >= N_NODES) return;
  int s0 = start[d];
  int deg = start[d + 1] - s0;
  float adv = ad2[d];
  float cm = decf(as2maxEnc[0]) + adv;
  cm = cm > 0.f ? cm : 0.2f * cm;

  int cp = lane % 20;        // channel pair (ch 2cp, 2cp+1)
  int es = lane / 20;        // edge slot 0..2 (lanes >= 60 idle in serial)
  const char* h2b = (const char*)h2 + cp * 4;

  float den = 0.f, acc0 = 0.f, acc1 = 0.f;
  for (int be = 0; be < deg; be += 64) {
    int cnt = min(64, deg - be);
    if (lane < cnt) {
      int s = esrc[s0 + be + lane];
      s_l[wave][lane] = s * 80;  // byte offset into h2 (40 halves)
      float e = as2[s] + adv;
      e = e > 0.f ? e : 0.2f * e;
      float p = __expf(e - cm);
      den += p;
      p_l[wave][lane] = p;
    }
    asm volatile("s_waitcnt lgkmcnt(0)" ::: "memory");
    if (es < 3) {
      int i = 0;
      for (; i + 5 < cnt; i += 6) {
        int eA = i + es, eB = i + 3 + es;
        int sbA = s_l[wave][eA], sbB = s_l[wave][eB];
        float pA = p_l[wave][eA], pB = p_l[wave][eB];
        __half2 hvA = *(const __half2*)(h2b + (unsigned)sbA);
        __half2 hvB = *(const __half2*)(h2b + (unsigned)sbB);
        acc0 = fmaf(__half2float(hvA.x), pA, acc0);
        acc1 = fmaf(__half2float(hvA.y), pA, acc1);
        acc0 = fmaf(__half2float(hvB.x), pB, acc0);
        acc1 = fmaf(__half2float(hvB.y), pB, acc1);
      }
      for (; i < cnt; i += 3) {
        int e = i + es;
        if (e < cnt) {
          int sb = s_l[wave][e];
          float p = p_l[wave][e];
          __half2 hv = *(const __half2*)(h2b + (unsigned)sb);
          acc0 = fmaf(__half2float(hv.x), p, acc0);
          acc1 = fmaf(__half2float(hv.y), p, acc1);
        }
      }
    }
    asm volatile("s_waitcnt lgkmcnt(0)" ::: "memory");
  }
#pragma unroll
  for (int off = 32; off; off >>= 1) den += __shfl_xor(den, off);
  float iv = 1.f / den;

  // combine 3 edge-slots: lanes 0..19 gather from +20, +40
  acc0 += __shfl(acc0, lane + 20) + __shfl(acc0, lane + 40);
  acc1 += __shfl(acc1, lane + 20) + __shfl(acc1, lane + 40);
  // distribute pairs to 40-lane layout: channel j from lane j>>1, comp j&1
  float va = __shfl(acc0, lane >> 1);
  float vb = __shfl(acc1, lane >> 1);
  float v = (lane & 1) ? vb : va;
  v = (lane < N_CLS) ? v * iv + b2[lane] : -1e30f;

  float mx = v;
#pragma unroll
  for (int off = 32; off; off >>= 1) mx = fmaxf(mx, __shfl_xor(mx, off));
  float ex = (lane < N_CLS) ? __expf(v - mx) : 0.f;
  float sm = ex;
#pragma unroll
  for (int off = 32; off; off >>= 1) sm += __shfl_xor(sm, off);
  float lse = logf(sm);
  if (lane < N_CLS) out[d * N_CLS + lane] = (v - mx) - lse;
}

// ---------------- host launcher ----------------

extern "C" void kernel_launch(void* const* d_in, const int* in_sizes, int n_in,
                              void* d_out, int out_size, void* d_ws, size_t ws_size,
                              hipStream_t stream) {
  const float* x    = (const float*)d_in[0];
  const int*   ei   = (const int*)d_in[1];
  const float* W1   = (const float*)d_in[2];
  const float* as1w = (const float*)d_in[3];
  const float* ad1w = (const float*)d_in[4];
  const float* b1   = (const float*)d_in[5];
  const float* W2   = (const float*)d_in[6];
  const float* as2w = (const float*)d_in[7];
  const float* ad2w = (const float*)d_in[8];
  const float* b2   = (const float*)d_in[9];
  float* out = (float*)d_out;

  char* ws = (char*)d_ws;
  size_t off = 0;
  auto alloc = [&](size_t bytes) -> void* {
    void* p = ws + off;
    off += (bytes + 255) & ~(size_t)255;
    return p;
  };
  __half* h1   = (__half*)alloc((size_t)N_NODES * 128 * 2);
  float* as1   = (float*)alloc((size_t)N_NODES * 8 * 4);
  float* ad1   = (float*)alloc((size_t)N_NODES * 8 * 4);
  __half* h2   = (__half*)alloc((size_t)N_NODES * 40 * 2);
  float* as2   = (float*)alloc((size_t)N_NODES * 4);
  float* ad2   = (float*)alloc((size_t)N_NODES * 4);
  // contiguous zero region: deg | maxenc(16)
  size_t zbytes = (size_t)N_NODES * 4 + 256;
  int* deg     = (int*)alloc(zbytes);
  unsigned* maxenc = (unsigned*)(deg + N_NODES);  // [0..7]=as1 heads, [8]=as2
  int* start   = (int*)alloc((size_t)(N_NODES + 1) * 4);
  int* esrc    = (int*)alloc((size_t)ET * 4);
  int* epos    = (int*)alloc((size_t)ET * 4);
  int* bsum    = (int*)alloc((size_t)NSCB * 4);
  int* boff    = (int*)alloc(256 * 4);
  float* fmax1 = (float*)alloc(32);

  (void)hipMemsetAsync(deg, 0, zbytes, stream);

  k_xform1<<<XB + HB, 256, 0, stream>>>(x, W1, as1w, ad1w, ei, deg, epos,
                                        h1, as1, ad1, maxenc);
  k_scanA<<<NSCB, 256, 0, stream>>>(deg, bsum);
  k_scanB<<<1, 256, 0, stream>>>(bsum, boff, start, maxenc, fmax1);
  k_scanC<<<NSCB, 256, 0, stream>>>(deg, boff, start);
  k_scatter<<<HB, 256, 0, stream>>>(ei, start, epos, esrc);

  k_agg1<<<N_NODES / 16, 256, 0, stream>>>(h1, as1, ad1, start, esrc, b1,
                                           W2, as2w, ad2w, fmax1,
                                           h2, as2, ad2);
  k_maxas2<<<64, 256, 0, stream>>>(as2, maxenc + 8);
  k_agg2<<<(N_NODES + 3) / 4, 256, 0, stream>>>(h2, as2, ad2, start, esrc, b2,
                                                maxenc + 8, out);
}